// Round 7
// baseline (2258.730 us; speedup 1.0000x reference)
//
#include <hip/hip_runtime.h>
#include <math.h>

#define N_NODES 50000
#define N_EDGES 500000

using bf16x8 = __attribute__((ext_vector_type(8))) short;
using f32x4  = __attribute__((ext_vector_type(4))) float;

// ---------- bf16 helpers ----------
__device__ inline float b2f(unsigned short u) {
  union { unsigned int i; float f; } v; v.i = ((unsigned int)u) << 16; return v.f;
}
__device__ inline unsigned short f2b(float f) {
  union { float f; unsigned int i; } v; v.f = f;
  unsigned int x = v.i;
  return (unsigned short)((x + 0x7fffu + ((x >> 16) & 1u)) >> 16);
}
__device__ inline void stv(unsigned short* p, float v) { *p = f2b(v); }
__device__ inline void stv(float* p, float v) { *p = v; }
__device__ inline float ldf(unsigned short u) { return b2f(u); }
__device__ inline float ldf(float f) { return f; }

// ---------------- degree / CSR ----------------
__global__ void k_count(const int* __restrict__ src, const int* __restrict__ dst,
                        int* __restrict__ cnt, int* __restrict__ degall) {
  int e = blockIdx.x * blockDim.x + threadIdx.x;
  if (e < N_EDGES) {
    atomicAdd(&cnt[dst[e]], 1);
    atomicAdd(&degall[src[e]], 1);
    atomicAdd(&degall[dst[e]], 1);
  }
}

__global__ __launch_bounds__(1024) void k_scan(const int* __restrict__ cnt, int* __restrict__ ptr) {
  __shared__ int buf[1024];
  __shared__ int carry;
  if (threadIdx.x == 0) carry = 0;
  __syncthreads();
  for (int base = 0; base < N_NODES; base += 1024) {
    int i = base + threadIdx.x;
    int v = (i < N_NODES) ? cnt[i] : 0;
    buf[threadIdx.x] = v;
    __syncthreads();
    for (int off = 1; off < 1024; off <<= 1) {
      int tv = (threadIdx.x >= off) ? buf[threadIdx.x - off] : 0;
      __syncthreads();
      buf[threadIdx.x] += tv;
      __syncthreads();
    }
    if (i < N_NODES) ptr[i] = carry + buf[threadIdx.x] - v;
    int total = buf[1023];
    __syncthreads();
    if (threadIdx.x == 0) carry += total;
    __syncthreads();
  }
  if (threadIdx.x == 0) ptr[N_NODES] = carry;
}

__global__ void k_fill(const int* __restrict__ src, const int* __restrict__ dst,
                       const int* __restrict__ ptr, int* __restrict__ cnt, int* __restrict__ col) {
  int e = blockIdx.x * blockDim.x + threadIdx.x;
  if (e < N_EDGES) {
    int d = dst[e];
    int pos = atomicAdd(&cnt[d], 1);
    col[ptr[d] + pos] = src[e];
  }
}

__global__ void k_avglog(const int* __restrict__ degall, float* __restrict__ scal) {
  __shared__ float L[256];
  float s = 0.f;
  for (int n = blockIdx.x * blockDim.x + threadIdx.x; n < N_NODES; n += gridDim.x * blockDim.x)
    s += logf((float)degall[n] + 1.0f);
  L[threadIdx.x] = s;
  __syncthreads();
  for (int o = 128; o > 0; o >>= 1) {
    if (threadIdx.x < o) L[threadIdx.x] += L[threadIdx.x + o];
    __syncthreads();
  }
  if (threadIdx.x == 0) atomicAdd(&scal[0], L[0]);
}

__global__ void k_avg_fin(float* scal) {
  float avg = scal[0] / (float)N_NODES;
  scal[1] = avg;
  scal[2] = 1.0f / avg;
}

__global__ void k_scalars(const int* __restrict__ ptr, const float* __restrict__ scal,
                          float* __restrict__ a_arr, float* __restrict__ c_arr) {
  int n = blockIdx.x * blockDim.x + threadIdx.x;
  if (n < N_NODES) {
    int d = ptr[n + 1] - ptr[n];
    float degc = fmaxf((float)d, 1.f);
    float logd = logf(degc + 1.f);
    a_arr[n] = logd * scal[2];
    c_arr[n] = scal[1] / logd;
  }
}

__global__ void k_cast(const float* __restrict__ x, unsigned short* __restrict__ xb, int total) {
  int i = blockIdx.x * blockDim.x + threadIdx.x;
  if (i < total) xb[i] = f2b(x[i]);
}

// pre-weights: BT_pre[j][k] = j<F ? Wpre[k][j] : Wpre[F+k][j-F]   (j<2F, k<F)
__global__ void k_tcast_pre(const float* __restrict__ Wpre, unsigned short* __restrict__ out, int F) {
  int i = blockIdx.x * blockDim.x + threadIdx.x;
  if (i < 2 * F * F) {
    int j = i / F, k = i % F;
    float v = (j < F) ? Wpre[(size_t)k * F + j] : Wpre[(size_t)(F + k) * F + (j - F)];
    out[i] = f2b(v);
  }
}

__global__ void k_biaspre(const float* __restrict__ bpre, float* __restrict__ biasPre, int F) {
  int j = threadIdx.x;
  if (j < 2 * F) biasPre[j] = (j < F) ? bpre[j] : 0.f;
}

// permuted zero-padded post weight: wP[j][k], j<3FO, k<5F.
// j -> wave w=j/96, slot=j%96, slice s=slot/32, col cc=w*32+slot%32.
// s=0: wcomb[k][cc] (rows 0..5F = [x-part; agg-part]); s=1: k<F?0:wcomb[4F+k][cc]; s=2: k<F?0:wcomb[8F+k][cc]
__global__ void k_build_wP(const float* __restrict__ wcomb, unsigned short* __restrict__ wP,
                           int F, int FO) {
  int K5 = 5 * F;
  int i = blockIdx.x * blockDim.x + threadIdx.x;
  if (i < 3 * FO * K5) {
    int j = i / K5, k = i % K5;
    int w = j / 96, slot = j % 96;
    int s = slot / 32, cc = w * 32 + slot % 32;
    float v;
    if (s == 0) v = wcomb[(size_t)k * FO + cc];
    else if (k < F) v = 0.f;
    else v = wcomb[(size_t)((4 * s * F) + k) * FO + cc];  // s=1 -> 4F+k, s=2 -> 8F+k
    wP[i] = f2b(v);
  }
}

// ---------------- fp32 GEMM (tiny, weights-only): C[M,Ncol] = A@B ----------------
__global__ __launch_bounds__(256) void k_gemm_f32(const float* __restrict__ A, const float* __restrict__ B,
                                                  float* __restrict__ C, int M, int Ncol, int K) {
  __shared__ float As[16][136];
  __shared__ float Bs[16][128];
  int tid = threadIdx.x;
  int row0 = blockIdx.y * 128, col0 = blockIdx.x * 128;
  int am = tid >> 1, ah = (tid & 1) * 8;
  int ty = tid >> 4, tx = tid & 15;
  float acc[8][8];
#pragma unroll
  for (int i = 0; i < 8; i++)
#pragma unroll
    for (int j = 0; j < 8; j++) acc[i][j] = 0.f;
  int arow = row0 + am;
  bool av = arow < M;
  const float* Ar = A + (size_t)arow * K;
  for (int k0 = 0; k0 < K; k0 += 16) {
    float4 a0 = make_float4(0, 0, 0, 0), a1 = make_float4(0, 0, 0, 0);
    if (av) {
      a0 = *(const float4*)(Ar + k0 + ah);
      a1 = *(const float4*)(Ar + k0 + ah + 4);
    }
    As[ah + 0][am] = a0.x; As[ah + 1][am] = a0.y; As[ah + 2][am] = a0.z; As[ah + 3][am] = a0.w;
    As[ah + 4][am] = a1.x; As[ah + 5][am] = a1.y; As[ah + 6][am] = a1.z; As[ah + 7][am] = a1.w;
#pragma unroll
    for (int i = 0; i < 2; i++) {
      int q = tid * 2 + i;
      int kk = q >> 5, j4 = (q & 31) * 4;
      int bc = col0 + j4;
      float4 b = make_float4(0, 0, 0, 0);
      if (bc < Ncol) b = *(const float4*)(B + (size_t)(k0 + kk) * Ncol + bc);
      *(float4*)(&Bs[kk][j4]) = b;
    }
    __syncthreads();
#pragma unroll
    for (int kk = 0; kk < 16; kk++) {
      float av8[8], bv8[8];
#pragma unroll
      for (int i = 0; i < 8; i++) av8[i] = As[kk][ty * 8 + i];
#pragma unroll
      for (int j = 0; j < 8; j++) bv8[j] = Bs[kk][tx * 8 + j];
#pragma unroll
      for (int i = 0; i < 8; i++)
#pragma unroll
        for (int j = 0; j < 8; j++) acc[i][j] = fmaf(av8[i], bv8[j], acc[i][j]);
    }
    __syncthreads();
  }
#pragma unroll
  for (int i = 0; i < 8; i++) {
    int r = row0 + ty * 8 + i;
    if (r < M) {
#pragma unroll
      for (int j = 0; j < 8; j++) {
        int c = col0 + tx * 8 + j;
        if (c < Ncol) C[(size_t)r * Ncol + c] = acc[i][j];
      }
    }
  }
}

// ---------------- plain single-phase MFMA bf16 GEMM (pre-GEMM) ----------------
template <int NTILE, typename To>
__global__ __launch_bounds__(256) void k_tile(
    const unsigned short* __restrict__ A, int lda, int K,
    const unsigned short* __restrict__ BT,
    const float* __restrict__ bias,
    To* __restrict__ C, int n0, int M, int Ncol) {
  constexpr int WN = NTILE / 64;
  constexpr int WM = 4 / WN;
  constexpr int MTILE = WM * 32;
  constexpr int PK = 40;
  constexpr int CA = MTILE / 64;
  constexpr int CB = NTILE / 64;
  __shared__ unsigned short As[MTILE][PK];
  __shared__ unsigned short Bs[NTILE][PK];
  const int tid = threadIdx.x;
  const int lane = tid & 63;
  const int wid = tid >> 6;
  const int wr = wid / WN;
  const int wc = wid % WN;
  const int row0 = blockIdx.y * MTILE;
  const int col0 = blockIdx.x * NTILE;
  const int l15 = lane & 15, lq = lane >> 4;
  uint4 apf[CA], bpf[CB];
  f32x4 acc[2][4];
#pragma unroll
  for (int m = 0; m < 2; m++)
#pragma unroll
    for (int n = 0; n < 4; n++) acc[m][n] = (f32x4){0.f, 0.f, 0.f, 0.f};

  auto load = [&](int k0) {
#pragma unroll
    for (int i = 0; i < CA; i++) {
      int idx = tid + 256 * i;
      int r = idx >> 2, c8 = (idx & 3) * 8;
      int gr = row0 + r;
      uint4 v = make_uint4(0u, 0u, 0u, 0u);
      if (gr < M) v = *(const uint4*)(A + (size_t)gr * lda + k0 + c8);
      apf[i] = v;
    }
#pragma unroll
    for (int i = 0; i < CB; i++) {
      int idx = tid + 256 * i;
      int r = idx >> 2, c8 = (idx & 3) * 8;
      bpf[i] = *(const uint4*)(BT + (size_t)(col0 + r) * K + k0 + c8);
    }
  };

  load(0);
  for (int k0 = 0; k0 < K; k0 += 32) {
#pragma unroll
    for (int i = 0; i < CA; i++) {
      int idx = tid + 256 * i;
      *(uint4*)&As[idx >> 2][(idx & 3) * 8] = apf[i];
    }
#pragma unroll
    for (int i = 0; i < CB; i++) {
      int idx = tid + 256 * i;
      *(uint4*)&Bs[idx >> 2][(idx & 3) * 8] = bpf[i];
    }
    __syncthreads();
    if (k0 + 32 < K) load(k0 + 32);
    bf16x8 af0 = *(const bf16x8*)&As[wr * 32 + l15][lq * 8];
    bf16x8 af1 = *(const bf16x8*)&As[wr * 32 + 16 + l15][lq * 8];
#pragma unroll
    for (int n = 0; n < 4; n++) {
      bf16x8 bf = *(const bf16x8*)&Bs[wc * 64 + n * 16 + l15][lq * 8];
      acc[0][n] = __builtin_amdgcn_mfma_f32_16x16x32_bf16(af0, bf, acc[0][n], 0, 0, 0);
      acc[1][n] = __builtin_amdgcn_mfma_f32_16x16x32_bf16(af1, bf, acc[1][n], 0, 0, 0);
    }
    __syncthreads();
  }
#pragma unroll
  for (int n = 0; n < 4; n++) {
    int col = col0 + wc * 64 + n * 16 + l15;
    float bv = bias ? bias[col] : 0.f;
#pragma unroll
    for (int m = 0; m < 2; m++) {
#pragma unroll
      for (int j = 0; j < 4; j++) {
        int r = row0 + wr * 32 + m * 16 + lq * 4 + j;
        if (r < M) stv(&C[(size_t)(n0 + r) * Ncol + col], acc[m][n][j] + bv);
      }
    }
  }
}

// ---------------- post GEMM with in-register combine ----------------
// A = aggx chunk [M][5F] ([x | mean|min|max|std]); BP = wP [3FO][5F] (permuted, zero-padded).
// One block spans ALL 3FO U-columns (grid.x==1) -> A fetched once.
// Wave wc owns output cols wc*32..wc*32+31; its 6 acc frag-pairs are the (U0,U1,U2) triple.
// Epilogue: o = U0 + an*U1 + cn*U2 + bias, per-row an/cn.
template <int WROW, int WCOL, int F, typename To>
__global__ __launch_bounds__(WROW* WCOL * 64) void k_gemm_u(
    const unsigned short* __restrict__ A,
    const unsigned short* __restrict__ BP,
    const float* __restrict__ a_arr, const float* __restrict__ c_arr,
    const float* __restrict__ bias,
    To* __restrict__ C, int n0, int M) {
  constexpr int K = 5 * F;
  constexpr int T = WROW * WCOL * 64;
  constexpr int MROWS = WROW * 32;
  constexpr int NU = WCOL * 96;
  constexpr int FO = WCOL * 32;
  constexpr int PK = 40;
  constexpr int CB = (NU * 4) / T;
  __shared__ unsigned short As[MROWS][PK];
  __shared__ unsigned short Bs[NU][PK];
  const int tid = threadIdx.x;
  const int lane = tid & 63;
  const int wid = tid >> 6;
  const int wr = wid / WCOL;
  const int wc = wid % WCOL;
  const int row0 = blockIdx.y * MROWS;
  const int l15 = lane & 15, lq = lane >> 4;
  uint4 apf, bpf[CB];
  f32x4 acc[2][6];
#pragma unroll
  for (int m = 0; m < 2; m++)
#pragma unroll
    for (int n = 0; n < 6; n++) acc[m][n] = (f32x4){0.f, 0.f, 0.f, 0.f};

  auto load = [&](int k0) {
    if (tid < MROWS * 4) {
      int r = tid >> 2, c8 = (tid & 3) * 8;
      int gr = row0 + r;
      uint4 v = make_uint4(0u, 0u, 0u, 0u);
      if (gr < M) v = *(const uint4*)(A + (size_t)gr * K + k0 + c8);
      apf = v;
    }
#pragma unroll
    for (int i = 0; i < CB; i++) {
      int idx = tid + T * i;
      int r = idx >> 2, c8 = (idx & 3) * 8;
      bpf[i] = *(const uint4*)(BP + (size_t)r * K + k0 + c8);
    }
  };

  load(0);
  for (int k0 = 0; k0 < K; k0 += 32) {
    if (tid < MROWS * 4) *(uint4*)&As[tid >> 2][(tid & 3) * 8] = apf;
#pragma unroll
    for (int i = 0; i < CB; i++) {
      int idx = tid + T * i;
      *(uint4*)&Bs[idx >> 2][(idx & 3) * 8] = bpf[i];
    }
    __syncthreads();
    if (k0 + 32 < K) load(k0 + 32);  // prefetch hidden under MFMA
    bf16x8 af0 = *(const bf16x8*)&As[wr * 32 + l15][lq * 8];
    bf16x8 af1 = *(const bf16x8*)&As[wr * 32 + 16 + l15][lq * 8];
#pragma unroll
    for (int n = 0; n < 6; n++) {
      bf16x8 bf = *(const bf16x8*)&Bs[wc * 96 + n * 16 + l15][lq * 8];
      acc[0][n] = __builtin_amdgcn_mfma_f32_16x16x32_bf16(af0, bf, acc[0][n], 0, 0, 0);
      acc[1][n] = __builtin_amdgcn_mfma_f32_16x16x32_bf16(af1, bf, acc[1][n], 0, 0, 0);
    }
    __syncthreads();
  }
  // epilogue: combine U0 + an*U1 + cn*U2 + bias (C/D map: col=lane&15, row=lq*4+j)
#pragma unroll
  for (int m = 0; m < 2; m++) {
    f32x4 anv = (f32x4){0.f, 0.f, 0.f, 0.f}, cnv = anv;
#pragma unroll
    for (int j = 0; j < 4; j++) {
      int r = row0 + wr * 32 + m * 16 + lq * 4 + j;
      if (r < M) { anv[j] = a_arr[n0 + r]; cnv[j] = c_arr[n0 + r]; }
    }
#pragma unroll
    for (int n = 0; n < 2; n++) {
      int ocol = wc * 32 + n * 16 + l15;
      f32x4 v = acc[m][n] + anv * acc[m][n + 2] + cnv * acc[m][n + 4];
      float bv = bias[ocol];
#pragma unroll
      for (int j = 0; j < 4; j++) {
        int r = row0 + wr * 32 + m * 16 + lq * 4 + j;
        if (r < M) stv(&C[(size_t)(n0 + r) * FO + ocol], v[j] + bv);
      }
    }
  }
}

// ---------------- edge aggregation: writes 5F rows [x | mean | min | max | std] ----------------
template <int F>
__global__ __launch_bounds__(256) void k_edge_agg(const unsigned short* __restrict__ ts,
                                                  const unsigned short* __restrict__ xin,
                                                  const int* __restrict__ ptr, const int* __restrict__ col,
                                                  unsigned short* __restrict__ aggx, int n0, int nchunk) {
  constexpr int R = F / 64;
  int idx = (blockIdx.x * blockDim.x + threadIdx.x) >> 6;
  int lane = threadIdx.x & 63;
  if (idx >= nchunk) return;
  int n = n0 + idx;
  if (n >= N_NODES) return;
  size_t obase = (size_t)idx * 5 * F;
#pragma unroll
  for (int r = 0; r < R; r++)
    aggx[obase + lane + 64 * r] = xin[(size_t)n * F + lane + 64 * r];
  float S1[R], S2[R], mn[R], mx[R];
#pragma unroll
  for (int r = 0; r < R; r++) {
    S1[r] = 0.f; S2[r] = 0.f;
    mn[r] = 3.4e38f; mx[r] = -3.4e38f;
  }
  int e0 = ptr[n], e1 = ptr[n + 1];
  for (int e = e0; e < e1; ++e) {
    int sidx = col[e];
    const unsigned short* srow = ts + (size_t)sidx * 2 * F + F;  // s part
#pragma unroll
    for (int r = 0; r < R; r++) {
      float v = b2f(srow[lane + 64 * r]);
      S1[r] += v;
      S2[r] += v * v;
      mn[r] = fminf(mn[r], v);
      mx[r] = fmaxf(mx[r], v);
    }
  }
  int d = e1 - e0;
#pragma unroll
  for (int r = 0; r < R; r++) {
    float mean, sd, lo, hi;
    if (d > 0) {
      float inv = 1.f / (float)d;
      float ms = S1[r] * inv;
      float var = fmaxf(S2[r] * inv - ms * ms, 0.f);
      sd = sqrtf(var + 1e-5f);
      float tv = b2f(ts[(size_t)n * 2 * F + lane + 64 * r]);  // t part
      mean = tv + ms;
      lo = tv + mn[r];
      hi = tv + mx[r];
    } else {
      mean = 0.f; lo = 0.f; hi = 0.f;
      sd = sqrtf(1e-5f);
    }
    size_t b = obase + F + lane + 64 * r;
    aggx[b] = f2b(mean);
    aggx[b + F] = f2b(lo);
    aggx[b + 2 * F] = f2b(hi);
    aggx[b + 3 * F] = f2b(sd);
  }
}

// ---------------- BN ----------------
template <int FO, typename Ti>
__global__ __launch_bounds__(256) void k_bn_stats(const Ti* __restrict__ o, float* __restrict__ gsum,
                                                  float* __restrict__ gsq) {
  constexpr int P = 256 / FO;
  int c = threadIdx.x % FO;
  int p = threadIdx.x / FO;
  float s1 = 0.f, s2 = 0.f;
  for (int n = blockIdx.x * P + p; n < N_NODES; n += gridDim.x * P) {
    float v = ldf(o[(size_t)n * FO + c]);
    s1 += v;
    s2 += v * v;
  }
  __shared__ float L1[256], L2[256];
  L1[threadIdx.x] = s1;
  L2[threadIdx.x] = s2;
  __syncthreads();
  if (p == 0) {
#pragma unroll
    for (int q = 1; q < P; q++) {
      s1 += L1[q * FO + c];
      s2 += L2[q * FO + c];
    }
    atomicAdd(&gsum[c], s1);
    atomicAdd(&gsq[c], s2);
  }
}

__global__ void k_bn_fin(const float* bnsum, const float* bnsq, float* bnmean, float* bnrs, int FO) {
  int c = threadIdx.x;
  if (c < FO) {
    float mean = bnsum[c] / (float)N_NODES;
    float var = bnsq[c] / (float)N_NODES - mean * mean;
    bnmean[c] = mean;
    bnrs[c] = rsqrtf(var + 1e-5f);
  }
}

template <typename Ti>
__global__ void k_bn_elu(const Ti* __restrict__ o, const float* __restrict__ mean,
                         const float* __restrict__ rs, const float* __restrict__ gamma,
                         const float* __restrict__ beta, unsigned short* __restrict__ h,
                         float* __restrict__ bnout, int FO) {
  int idx = blockIdx.x * blockDim.x + threadIdx.x;
  if (idx < N_NODES * FO) {
    int c = idx % FO;
    float y = gamma[c] * (ldf(o[idx]) - mean[c]) * rs[c] + beta[c];
    if (bnout) bnout[idx] = y;
    h[idx] = f2b(y > 0.f ? y : expm1f(y));
  }
}

// ---------------- misc ----------------
__global__ void k_bcomb(const float* __restrict__ bpost, const float* __restrict__ Wlin,
                        const float* __restrict__ blin, float* __restrict__ bcomb, int FO) {
  int j = threadIdx.x;
  if (j < FO) {
    float acc = blin[j];
    for (int k = 0; k < FO; k++) acc += bpost[k] * Wlin[k * FO + j];
    bcomb[j] = acc;
  }
}

__global__ void k_add(const unsigned short* __restrict__ a, const unsigned short* __restrict__ b,
                      unsigned short* __restrict__ c) {
  int idx = blockIdx.x * blockDim.x + threadIdx.x;
  if (idx < N_NODES * 128) c[idx] = f2b(b2f(a[idx]) + b2f(b[idx]));
}

__global__ void k_logits(const unsigned short* __restrict__ h4, const float* __restrict__ Wc,
                         const float* __restrict__ bc, float* __restrict__ out) {
  int n = blockIdx.x * blockDim.x + threadIdx.x;
  if (n < N_NODES) {
    float acc0 = bc[0], acc1 = bc[1];
    const unsigned short* hr = h4 + (size_t)n * 64;
    for (int k = 0; k < 64; k++) {
      float v = b2f(hr[k]);
      acc0 += v * Wc[k * 2 + 0];
      acc1 += v * Wc[k * 2 + 1];
    }
    out[n * 2 + 0] = acc0;
    out[n * 2 + 1] = acc1;
  }
}

// ---------------- driver ----------------
struct WS {
  int *ptr, *col, *cnt, *degall;
  float *scal, *a_arr, *c_arr, *bnsum, *bnsq, *bnmean, *bnrs, *wcomb, *bcomb, *biasPre;
  unsigned short *wP, *wpreT;
  unsigned short *xb, *h1, *h2, *h3, *ts, *aggx;
  size_t agg_elems;
};

template <int F, typename To>
static void run_layer(const unsigned short* xin, To* o_ptr, float* bnout, unsigned short* hout,
                      const float* Wpre, const float* bpre, const float* Wpost, const float* bpost,
                      const float* Wlin, const float* blin, const float* gamma, const float* beta,
                      int FO, const WS& ws, hipStream_t stream) {
  const int N = N_NODES;
  const int K13 = 13 * F;
  const int K5 = 5 * F;
  // weight prep
  {
    dim3 g((FO + 127) / 128, (K13 + 127) / 128);
    k_gemm_f32<<<g, 256, 0, stream>>>(Wpost, Wlin, ws.wcomb, K13, FO, FO);
    k_bcomb<<<1, 256, 0, stream>>>(bpost, Wlin, blin, ws.bcomb, FO);
    k_build_wP<<<(3 * FO * K5 + 255) / 256, 256, 0, stream>>>(ws.wcomb, ws.wP, F, FO);
    k_tcast_pre<<<(2 * F * F + 255) / 256, 256, 0, stream>>>(Wpre, ws.wpreT, F);
    k_biaspre<<<1, 512, 0, stream>>>(bpre, ws.biasPre, F);
  }
  // fused pre-GEMM: ts = xin @ [W1 | W2] + [bpre | 0]
  {
    dim3 g(2 * F / 128, (N + 63) / 64);
    k_tile<128, unsigned short><<<g, 256, 0, stream>>>(
        xin, F, F, ws.wpreT, ws.biasPre, ws.ts, 0, N, 2 * F);
  }
  // chunked: edge aggregation (5F rows) -> post GEMM with in-register combine
  int NB = (int)(ws.agg_elems / (size_t)K5);
  NB &= ~63;
  if (NB > N) NB = N;
  if (NB < 64) NB = 64;
  for (int c0 = 0; c0 < N; c0 += NB) {
    int nc = (N - c0 < NB) ? (N - c0) : NB;
    k_edge_agg<F><<<(nc + 3) / 4, 256, 0, stream>>>(ws.ts, xin, ws.ptr, ws.col, ws.aggx, c0, nc);
    if (FO == 64) {
      dim3 g(1, (nc + 63) / 64);
      k_gemm_u<2, 2, F, To><<<g, 256, 0, stream>>>(
          ws.aggx, ws.wP, ws.a_arr, ws.c_arr, ws.bcomb, o_ptr, c0, nc);
    } else if (FO == 128) {
      dim3 g(1, (nc + 63) / 64);
      k_gemm_u<2, 4, F, To><<<g, 512, 0, stream>>>(
          ws.aggx, ws.wP, ws.a_arr, ws.c_arr, ws.bcomb, o_ptr, c0, nc);
    } else {
      dim3 g(1, (nc + 31) / 32);
      k_gemm_u<1, 8, F, To><<<g, 512, 0, stream>>>(
          ws.aggx, ws.wP, ws.a_arr, ws.c_arr, ws.bcomb, o_ptr, c0, nc);
    }
  }
  // BN + ELU
  hipMemsetAsync(ws.bnsum, 0, 256 * sizeof(float), stream);
  hipMemsetAsync(ws.bnsq, 0, 256 * sizeof(float), stream);
  if (FO == 64)
    k_bn_stats<64, To><<<128, 256, 0, stream>>>(o_ptr, ws.bnsum, ws.bnsq);
  else if (FO == 128)
    k_bn_stats<128, To><<<128, 256, 0, stream>>>(o_ptr, ws.bnsum, ws.bnsq);
  else
    k_bn_stats<256, To><<<128, 256, 0, stream>>>(o_ptr, ws.bnsum, ws.bnsq);
  k_bn_fin<<<1, 256, 0, stream>>>(ws.bnsum, ws.bnsq, ws.bnmean, ws.bnrs, FO);
  int total = N_NODES * FO;
  k_bn_elu<To><<<(total + 255) / 256, 256, 0, stream>>>(o_ptr, ws.bnmean, ws.bnrs, gamma, beta, hout, bnout, FO);
}

extern "C" void kernel_launch(void* const* d_in, const int* in_sizes, int n_in,
                              void* d_out, int out_size, void* d_ws, size_t ws_size,
                              hipStream_t stream) {
  const int N = N_NODES, E = N_EDGES;
  const float* x = (const float*)d_in[0];
  const int* ei = (const int*)d_in[1];
  const int* src = ei;
  const int* dst = ei + E;
  const float *Wpre[4], *bpre[4], *Wpost[4], *bpost[4], *Wlin[4], *blin[4], *gamma[4], *beta[4];
  for (int i = 0; i < 4; i++) {
    const int b = 2 + i * 8;
    Wpre[i] = (const float*)d_in[b + 0];
    bpre[i] = (const float*)d_in[b + 1];
    Wpost[i] = (const float*)d_in[b + 2];
    bpost[i] = (const float*)d_in[b + 3];
    Wlin[i] = (const float*)d_in[b + 4];
    blin[i] = (const float*)d_in[b + 5];
    gamma[i] = (const float*)d_in[b + 6];
    beta[i] = (const float*)d_in[b + 7];
  }
  const float* Wc = (const float*)d_in[34];
  const float* bcv = (const float*)d_in[35];

  // ----- workspace layout (~121 MB fixed + adaptive aggx) -----
  char* w = (char*)d_ws;
  size_t off = 0;
  auto alloc = [&](size_t bytes) -> void* {
    void* p = (void*)(w + off);
    off = (off + bytes + 255) & ~(size_t)255;
    return p;
  };
  WS ws;
  ws.ptr = (int*)alloc((N + 1) * sizeof(int));
  ws.col = (int*)alloc((size_t)E * sizeof(int));
  ws.cnt = (int*)alloc((size_t)N * sizeof(int));
  ws.degall = (int*)alloc((size_t)N * sizeof(int));
  ws.scal = (float*)alloc(16 * sizeof(float));
  ws.a_arr = (float*)alloc((size_t)N * sizeof(float));
  ws.c_arr = (float*)alloc((size_t)N * sizeof(float));
  ws.bnsum = (float*)alloc(256 * sizeof(float));
  ws.bnsq = (float*)alloc(256 * sizeof(float));
  ws.bnmean = (float*)alloc(256 * sizeof(float));
  ws.bnrs = (float*)alloc(256 * sizeof(float));
  ws.wcomb = (float*)alloc((size_t)13 * 256 * 128 * sizeof(float));
  ws.bcomb = (float*)alloc(256 * sizeof(float));
  ws.biasPre = (float*)alloc(512 * sizeof(float));
  ws.wP = (unsigned short*)alloc((size_t)768 * 1280 * sizeof(unsigned short));
  ws.wpreT = (unsigned short*)alloc((size_t)512 * 256 * sizeof(unsigned short));
  ws.xb = (unsigned short*)alloc((size_t)N * 128 * sizeof(unsigned short));
  ws.h1 = (unsigned short*)alloc((size_t)N * 128 * sizeof(unsigned short));
  ws.h2 = (unsigned short*)alloc((size_t)N * 256 * sizeof(unsigned short));
  ws.h3 = (unsigned short*)alloc((size_t)N * 128 * sizeof(unsigned short));
  ws.ts = (unsigned short*)alloc((size_t)N * 512 * sizeof(unsigned short));
  size_t rem = (ws_size > off) ? (ws_size - off) : 0;
  ws.agg_elems = rem / sizeof(unsigned short);
  ws.aggx = (unsigned short*)(w + off);
  unsigned short* h4 = ws.xb;  // alias: x dead after layer 1; h4 is [N,64]

  float* outp = (float*)d_out;
  float* logits = outp;              // [N,2]
  float* p4 = outp + (size_t)N * 2;  // [N,64]
  float* b4 = p4 + (size_t)N * 64;   // [N,64]
  unsigned short* o_scratch = (unsigned short*)p4;  // pre-BN scratch, overwritten by layer 4

  // ----- degree / CSR / scalars -----
  hipMemsetAsync(ws.cnt, 0, N * sizeof(int), stream);
  hipMemsetAsync(ws.degall, 0, N * sizeof(int), stream);
  hipMemsetAsync(ws.scal, 0, 16 * sizeof(float), stream);
  k_count<<<(E + 255) / 256, 256, 0, stream>>>(src, dst, ws.cnt, ws.degall);
  k_scan<<<1, 1024, 0, stream>>>(ws.cnt, ws.ptr);
  hipMemsetAsync(ws.cnt, 0, N * sizeof(int), stream);
  k_fill<<<(E + 255) / 256, 256, 0, stream>>>(src, dst, ws.ptr, ws.cnt, ws.col);
  k_avglog<<<64, 256, 0, stream>>>(ws.degall, ws.scal);
  k_avg_fin<<<1, 1, 0, stream>>>(ws.scal);
  k_scalars<<<(N + 255) / 256, 256, 0, stream>>>(ws.ptr, ws.scal, ws.a_arr, ws.c_arr);
  k_cast<<<(N * 128 + 255) / 256, 256, 0, stream>>>(x, ws.xb, N * 128);

  run_layer<128, unsigned short>(ws.xb, o_scratch, nullptr, ws.h1,
                                 Wpre[0], bpre[0], Wpost[0], bpost[0], Wlin[0], blin[0], gamma[0], beta[0],
                                 128, ws, stream);
  run_layer<128, unsigned short>(ws.h1, o_scratch, nullptr, ws.h2,
                                 Wpre[1], bpre[1], Wpost[1], bpost[1], Wlin[1], blin[1], gamma[1], beta[1],
                                 256, ws, stream);
  run_layer<256, unsigned short>(ws.h2, o_scratch, nullptr, ws.h3,
                                 Wpre[2], bpre[2], Wpost[2], bpost[2], Wlin[2], blin[2], gamma[2], beta[2],
                                 128, ws, stream);
  k_add<<<((N * 128) + 255) / 256, 256, 0, stream>>>(ws.h1, ws.h3, ws.h3);  // x4 = h1 + h3 in place
  run_layer<128, float>(ws.h3, p4, b4, h4,
                        Wpre[3], bpre[3], Wpost[3], bpost[3], Wlin[3], blin[3], gamma[3], beta[3],
                        64, ws, stream);
  k_logits<<<(N + 255) / 256, 256, 0, stream>>>(h4, Wc, bcv, logits);
  (void)in_sizes; (void)n_in; (void)out_size; (void)ws_size;
}

// Round 8
// 1704.050 us; speedup vs baseline: 1.3255x; 1.3255x over previous
//
#include <hip/hip_runtime.h>
#include <math.h>

#define N_NODES 50000
#define N_EDGES 500000

using bf16x8 = __attribute__((ext_vector_type(8))) short;
using f32x4  = __attribute__((ext_vector_type(4))) float;

// ---------- bf16 helpers ----------
__device__ inline float b2f(unsigned short u) {
  union { unsigned int i; float f; } v; v.i = ((unsigned int)u) << 16; return v.f;
}
__device__ inline unsigned short f2b(float f) {
  union { float f; unsigned int i; } v; v.f = f;
  unsigned int x = v.i;
  return (unsigned short)((x + 0x7fffu + ((x >> 16) & 1u)) >> 16);
}
__device__ inline unsigned int pk2(float a, float b) {
  return (unsigned int)f2b(a) | ((unsigned int)f2b(b) << 16);
}
__device__ inline void stv(unsigned short* p, float v) { *p = f2b(v); }
__device__ inline void stv(float* p, float v) { *p = v; }
__device__ inline float ldf(unsigned short u) { return b2f(u); }
__device__ inline float ldf(float f) { return f; }
__device__ inline int imin(int a, int b) { return a < b ? a : b; }

// direct global->LDS DMA, 16B per lane; lds base is wave-uniform
__device__ inline void gload16(const unsigned short* g, unsigned short* l) {
  __builtin_amdgcn_global_load_lds((const __attribute__((address_space(1))) unsigned int*)g,
                                   (__attribute__((address_space(3))) unsigned int*)l, 16, 0, 0);
}

// ---------------- degree / CSR ----------------
__global__ void k_count(const int* __restrict__ src, const int* __restrict__ dst,
                        int* __restrict__ cnt, int* __restrict__ degall) {
  int e = blockIdx.x * blockDim.x + threadIdx.x;
  if (e < N_EDGES) {
    atomicAdd(&cnt[dst[e]], 1);
    atomicAdd(&degall[src[e]], 1);
    atomicAdd(&degall[dst[e]], 1);
  }
}

__global__ __launch_bounds__(1024) void k_scan(const int* __restrict__ cnt, int* __restrict__ ptr) {
  __shared__ int buf[1024];
  __shared__ int carry;
  if (threadIdx.x == 0) carry = 0;
  __syncthreads();
  for (int base = 0; base < N_NODES; base += 1024) {
    int i = base + threadIdx.x;
    int v = (i < N_NODES) ? cnt[i] : 0;
    buf[threadIdx.x] = v;
    __syncthreads();
    for (int off = 1; off < 1024; off <<= 1) {
      int tv = (threadIdx.x >= off) ? buf[threadIdx.x - off] : 0;
      __syncthreads();
      buf[threadIdx.x] += tv;
      __syncthreads();
    }
    if (i < N_NODES) ptr[i] = carry + buf[threadIdx.x] - v;
    int total = buf[1023];
    __syncthreads();
    if (threadIdx.x == 0) carry += total;
    __syncthreads();
  }
  if (threadIdx.x == 0) ptr[N_NODES] = carry;
}

__global__ void k_fill(const int* __restrict__ src, const int* __restrict__ dst,
                       const int* __restrict__ ptr, int* __restrict__ cnt, int* __restrict__ col) {
  int e = blockIdx.x * blockDim.x + threadIdx.x;
  if (e < N_EDGES) {
    int d = dst[e];
    int pos = atomicAdd(&cnt[d], 1);
    col[ptr[d] + pos] = src[e];
  }
}

__global__ void k_avglog(const int* __restrict__ degall, float* __restrict__ scal) {
  __shared__ float L[256];
  float s = 0.f;
  for (int n = blockIdx.x * blockDim.x + threadIdx.x; n < N_NODES; n += gridDim.x * blockDim.x)
    s += logf((float)degall[n] + 1.0f);
  L[threadIdx.x] = s;
  __syncthreads();
  for (int o = 128; o > 0; o >>= 1) {
    if (threadIdx.x < o) L[threadIdx.x] += L[threadIdx.x + o];
    __syncthreads();
  }
  if (threadIdx.x == 0) atomicAdd(&scal[0], L[0]);
}

__global__ void k_avg_fin(float* scal) {
  float avg = scal[0] / (float)N_NODES;
  scal[1] = avg;
  scal[2] = 1.0f / avg;
}

__global__ void k_scalars(const int* __restrict__ ptr, const float* __restrict__ scal,
                          float* __restrict__ a_arr, float* __restrict__ c_arr) {
  int n = blockIdx.x * blockDim.x + threadIdx.x;
  if (n < N_NODES) {
    int d = ptr[n + 1] - ptr[n];
    float degc = fmaxf((float)d, 1.f);
    float logd = logf(degc + 1.f);
    a_arr[n] = logd * scal[2];
    c_arr[n] = scal[1] / logd;
  }
}

__global__ void k_cast(const float* __restrict__ x, unsigned short* __restrict__ xb, int total) {
  int i = blockIdx.x * blockDim.x + threadIdx.x;
  if (i < total) xb[i] = f2b(x[i]);
}

// pre-weights: BT_pre[j][k] = j<F ? Wpre[k][j] : Wpre[F+k][j-F]   (j<2F, k<F)
__global__ void k_tcast_pre(const float* __restrict__ Wpre, unsigned short* __restrict__ out, int F) {
  int i = blockIdx.x * blockDim.x + threadIdx.x;
  if (i < 2 * F * F) {
    int j = i / F, k = i % F;
    float v = (j < F) ? Wpre[(size_t)k * F + j] : Wpre[(size_t)(F + k) * F + (j - F)];
    out[i] = f2b(v);
  }
}

__global__ void k_biaspre(const float* __restrict__ bpre, float* __restrict__ biasPre, int F) {
  int j = threadIdx.x;
  if (j < 2 * F) biasPre[j] = (j < F) ? bpre[j] : 0.f;
}

// ---------------- weight GEMM: CT[c][r] = bf16( (Wpost@Wlin)[r][c] ), M=13F rows, Ncol=FO ----------------
__global__ __launch_bounds__(256) void k_wcombT(const float* __restrict__ A, const float* __restrict__ B,
                                                unsigned short* __restrict__ CT, int M, int Ncol, int K) {
  __shared__ float As[16][136];
  __shared__ float Bs[16][128];
  int tid = threadIdx.x;
  int row0 = blockIdx.y * 128, col0 = blockIdx.x * 128;
  int am = tid >> 1, ah = (tid & 1) * 8;
  int ty = tid >> 4, tx = tid & 15;
  float acc[8][8];
#pragma unroll
  for (int i = 0; i < 8; i++)
#pragma unroll
    for (int j = 0; j < 8; j++) acc[i][j] = 0.f;
  int arow = row0 + am;
  bool av = arow < M;
  const float* Ar = A + (size_t)arow * K;
  for (int k0 = 0; k0 < K; k0 += 16) {
    float4 a0 = make_float4(0, 0, 0, 0), a1 = make_float4(0, 0, 0, 0);
    if (av) {
      a0 = *(const float4*)(Ar + k0 + ah);
      a1 = *(const float4*)(Ar + k0 + ah + 4);
    }
    As[ah + 0][am] = a0.x; As[ah + 1][am] = a0.y; As[ah + 2][am] = a0.z; As[ah + 3][am] = a0.w;
    As[ah + 4][am] = a1.x; As[ah + 5][am] = a1.y; As[ah + 6][am] = a1.z; As[ah + 7][am] = a1.w;
#pragma unroll
    for (int i = 0; i < 2; i++) {
      int q = tid * 2 + i;
      int kk = q >> 5, j4 = (q & 31) * 4;
      int bc = col0 + j4;
      float4 b = make_float4(0, 0, 0, 0);
      if (bc < Ncol && (k0 + kk) < K) b = *(const float4*)(B + (size_t)(k0 + kk) * Ncol + bc);
      *(float4*)(&Bs[kk][j4]) = b;
    }
    __syncthreads();
#pragma unroll
    for (int kk = 0; kk < 16; kk++) {
      float av8[8], bv8[8];
#pragma unroll
      for (int i = 0; i < 8; i++) av8[i] = As[kk][ty * 8 + i];
#pragma unroll
      for (int j = 0; j < 8; j++) bv8[j] = Bs[kk][tx * 8 + j];
#pragma unroll
      for (int i = 0; i < 8; i++)
#pragma unroll
        for (int j = 0; j < 8; j++) acc[i][j] = fmaf(av8[i], bv8[j], acc[i][j]);
    }
    __syncthreads();
  }
#pragma unroll
  for (int i = 0; i < 8; i++) {
    int r = row0 + ty * 8 + i;
    if (r < M) {
#pragma unroll
      for (int j = 0; j < 8; j++) {
        int c = col0 + tx * 8 + j;
        if (c < Ncol) CT[(size_t)c * M + r] = f2b(acc[i][j]);
      }
    }
  }
}

// ---------------- m97-style MFMA GEMM: 128x128 tile, 64x64/wave, gload_lds dbuf ----------------
// C[n0+r, :] = A[r, :K] @ BT^T + bias.  A [M,K] bf16 (rows clamped), BT [Ncol,K] bf16.
// Requires: K % 32 == 0, Ncol % 128 == 0, 16B-aligned rows.
template <typename To>
__global__ __launch_bounds__(256) void k_mm(
    const unsigned short* __restrict__ A, int K,
    const unsigned short* __restrict__ BT,
    const float* __restrict__ bias,
    To* __restrict__ C, int n0, int M, int Ncol) {
  __shared__ unsigned short lds[2][2][4096];  // [buf][A/B][128 rows x 32 cols]
  const int tid = threadIdx.x;
  const int lane = tid & 63;
  const int wid = tid >> 6;
  const int wr = wid >> 1, wc = wid & 1;
  const int row0 = blockIdx.y * 128;
  const int col0 = blockIdx.x * 128;
  const int l15 = lane & 15, lq = lane >> 4;
  // staging geometry: wave wid covers rows [wid*32, wid*32+32), two 16-row chunks
  const int srow = wid * 32 + (lane >> 2);
  const int scol = (lane & 3) * 8;
  const unsigned short* gA0 = A + (size_t)imin(row0 + srow, M - 1) * K + scol;
  const unsigned short* gA1 = A + (size_t)imin(row0 + srow + 16, M - 1) * K + scol;
  const unsigned short* gB0 = BT + (size_t)(col0 + srow) * K + scol;
  const unsigned short* gB1 = BT + (size_t)(col0 + srow + 16) * K + scol;

  f32x4 acc[4][4];
#pragma unroll
  for (int m = 0; m < 4; m++)
#pragma unroll
    for (int n = 0; n < 4; n++) acc[m][n] = (f32x4){0.f, 0.f, 0.f, 0.f};

  auto stage = [&](int buf, int k0) {
    gload16(gA0 + k0, &lds[buf][0][wid * 1024]);
    gload16(gA1 + k0, &lds[buf][0][wid * 1024 + 512]);
    gload16(gB0 + k0, &lds[buf][1][wid * 1024]);
    gload16(gB1 + k0, &lds[buf][1][wid * 1024 + 512]);
  };

  const int nk = K / 32;
  stage(0, 0);
  __syncthreads();
  for (int t = 0; t < nk; ++t) {
    const int cur = t & 1;
    if (t + 1 < nk) stage(cur ^ 1, (t + 1) * 32);  // prefetch next K-tile (drained by barrier)
    bf16x8 a[4], b[4];
#pragma unroll
    for (int m = 0; m < 4; m++)
      a[m] = *(const bf16x8*)&lds[cur][0][(wr * 64 + m * 16 + l15) * 32 + lq * 8];
#pragma unroll
    for (int n = 0; n < 4; n++)
      b[n] = *(const bf16x8*)&lds[cur][1][(wc * 64 + n * 16 + l15) * 32 + lq * 8];
#pragma unroll
    for (int m = 0; m < 4; m++)
#pragma unroll
      for (int n = 0; n < 4; n++)
        acc[m][n] = __builtin_amdgcn_mfma_f32_16x16x32_bf16(a[m], b[n], acc[m][n], 0, 0, 0);
    __syncthreads();
  }
  // epilogue (C/D map: col=lane&15, row=(lane>>4)*4+j)
#pragma unroll
  for (int n = 0; n < 4; n++) {
    int col = col0 + wc * 64 + n * 16 + l15;
    float bv = bias ? bias[col] : 0.f;
#pragma unroll
    for (int m = 0; m < 4; m++) {
#pragma unroll
      for (int j = 0; j < 4; j++) {
        int r = row0 + wr * 64 + m * 16 + lq * 4 + j;
        if (r < M) stv(&C[(size_t)(n0 + r) * Ncol + col], acc[m][n][j] + bv);
      }
    }
  }
}

// ---------------- reg-staged MFMA GEMM for Ncol=64 (layer-4 post) ----------------
template <int NTILE, typename To>
__global__ __launch_bounds__(256) void k_tile(
    const unsigned short* __restrict__ A, int lda, int K,
    const unsigned short* __restrict__ BT,
    const float* __restrict__ bias,
    To* __restrict__ C, int n0, int M, int Ncol) {
  constexpr int WN = NTILE / 64;
  constexpr int WM = 4 / WN;
  constexpr int MTILE = WM * 32;
  constexpr int PK = 40;
  constexpr int CA = MTILE / 64;
  constexpr int CB = NTILE / 64;
  __shared__ unsigned short As[MTILE][PK];
  __shared__ unsigned short Bs[NTILE][PK];
  const int tid = threadIdx.x;
  const int lane = tid & 63;
  const int wid = tid >> 6;
  const int wr = wid / WN;
  const int wc = wid % WN;
  const int row0 = blockIdx.y * MTILE;
  const int col0 = blockIdx.x * NTILE;
  const int l15 = lane & 15, lq = lane >> 4;
  uint4 apf[CA], bpf[CB];
  f32x4 acc[2][4];
#pragma unroll
  for (int m = 0; m < 2; m++)
#pragma unroll
    for (int n = 0; n < 4; n++) acc[m][n] = (f32x4){0.f, 0.f, 0.f, 0.f};

  auto load = [&](int k0) {
#pragma unroll
    for (int i = 0; i < CA; i++) {
      int idx = tid + 256 * i;
      int r = idx >> 2, c8 = (idx & 3) * 8;
      int gr = row0 + r;
      uint4 v = make_uint4(0u, 0u, 0u, 0u);
      if (gr < M) v = *(const uint4*)(A + (size_t)gr * lda + k0 + c8);
      apf[i] = v;
    }
#pragma unroll
    for (int i = 0; i < CB; i++) {
      int idx = tid + 256 * i;
      int r = idx >> 2, c8 = (idx & 3) * 8;
      bpf[i] = *(const uint4*)(BT + (size_t)(col0 + r) * K + k0 + c8);
    }
  };

  load(0);
  for (int k0 = 0; k0 < K; k0 += 32) {
#pragma unroll
    for (int i = 0; i < CA; i++) {
      int idx = tid + 256 * i;
      *(uint4*)&As[idx >> 2][(idx & 3) * 8] = apf[i];
    }
#pragma unroll
    for (int i = 0; i < CB; i++) {
      int idx = tid + 256 * i;
      *(uint4*)&Bs[idx >> 2][(idx & 3) * 8] = bpf[i];
    }
    __syncthreads();
    if (k0 + 32 < K) load(k0 + 32);
    bf16x8 af0 = *(const bf16x8*)&As[wr * 32 + l15][lq * 8];
    bf16x8 af1 = *(const bf16x8*)&As[wr * 32 + 16 + l15][lq * 8];
#pragma unroll
    for (int n = 0; n < 4; n++) {
      bf16x8 bf = *(const bf16x8*)&Bs[wc * 64 + n * 16 + l15][lq * 8];
      acc[0][n] = __builtin_amdgcn_mfma_f32_16x16x32_bf16(af0, bf, acc[0][n], 0, 0, 0);
      acc[1][n] = __builtin_amdgcn_mfma_f32_16x16x32_bf16(af1, bf, acc[1][n], 0, 0, 0);
    }
    __syncthreads();
  }
#pragma unroll
  for (int n = 0; n < 4; n++) {
    int col = col0 + wc * 64 + n * 16 + l15;
    float bv = bias ? bias[col] : 0.f;
#pragma unroll
    for (int m = 0; m < 2; m++) {
#pragma unroll
      for (int j = 0; j < 4; j++) {
        int r = row0 + wr * 32 + m * 16 + lq * 4 + j;
        if (r < M) stv(&C[(size_t)(n0 + r) * Ncol + col], acc[m][n][j] + bv);
      }
    }
  }
}

// ---------------- edge aggregation (vectorized): writes 13F rows [x | agg | an*agg | cn*agg] ----------------
template <int F>
__global__ __launch_bounds__(256) void k_edge_agg(
    const unsigned short* __restrict__ ts, const unsigned short* __restrict__ xin,
    const int* __restrict__ ptr, const int* __restrict__ col,
    const float* __restrict__ a_arr, const float* __restrict__ c_arr,
    unsigned short* __restrict__ aggx, int n0, int nchunk) {
  constexpr int VU = F / 128;  // uints per lane per F-block
  int idx = (blockIdx.x * blockDim.x + threadIdx.x) >> 6;
  int lane = threadIdx.x & 63;
  if (idx >= nchunk) return;
  int n = n0 + idx;
  if (n >= N_NODES) return;
  float S1[2 * VU], S2[2 * VU], mn[2 * VU], mx[2 * VU];
#pragma unroll
  for (int u = 0; u < 2 * VU; u++) {
    S1[u] = 0.f; S2[u] = 0.f; mn[u] = 3.4e38f; mx[u] = -3.4e38f;
  }
  int e0 = ptr[n], e1 = ptr[n + 1];
  for (int e = e0; e < e1; ++e) {
    int sidx = col[e];
    const unsigned int* sr = (const unsigned int*)(ts + (size_t)sidx * 2 * F + F);
#pragma unroll
    for (int u = 0; u < VU; u++) {
      unsigned int v = sr[lane + 64 * u];
      float f0 = b2f((unsigned short)(v & 0xffff));
      float f1 = b2f((unsigned short)(v >> 16));
      S1[2 * u] += f0; S2[2 * u] += f0 * f0;
      mn[2 * u] = fminf(mn[2 * u], f0); mx[2 * u] = fmaxf(mx[2 * u], f0);
      S1[2 * u + 1] += f1; S2[2 * u + 1] += f1 * f1;
      mn[2 * u + 1] = fminf(mn[2 * u + 1], f1); mx[2 * u + 1] = fmaxf(mx[2 * u + 1], f1);
    }
  }
  int d = e1 - e0;
  float an = a_arr[n], cn = c_arr[n];
  const unsigned int* tr = (const unsigned int*)(ts + (size_t)n * 2 * F);
  const unsigned int* xr = (const unsigned int*)(xin + (size_t)n * F);
  unsigned int* ob = (unsigned int*)(aggx + (size_t)idx * 13 * F);
  constexpr int UB = 64 * VU;  // uints per F-block
#pragma unroll
  for (int u = 0; u < VU; u++) {
    int ui = lane + 64 * u;
    ob[ui] = xr[ui];  // x block
    float mean0, mean1, lo0, lo1, hi0, hi1, sd0, sd1;
    if (d > 0) {
      float inv = 1.f / (float)d;
      unsigned int tv = tr[ui];
      float t0 = b2f((unsigned short)(tv & 0xffff));
      float t1 = b2f((unsigned short)(tv >> 16));
      float ms0 = S1[2 * u] * inv, ms1 = S1[2 * u + 1] * inv;
      sd0 = sqrtf(fmaxf(S2[2 * u] * inv - ms0 * ms0, 0.f) + 1e-5f);
      sd1 = sqrtf(fmaxf(S2[2 * u + 1] * inv - ms1 * ms1, 0.f) + 1e-5f);
      mean0 = t0 + ms0; mean1 = t1 + ms1;
      lo0 = t0 + mn[2 * u]; lo1 = t1 + mn[2 * u + 1];
      hi0 = t0 + mx[2 * u]; hi1 = t1 + mx[2 * u + 1];
    } else {
      mean0 = mean1 = lo0 = lo1 = hi0 = hi1 = 0.f;
      sd0 = sd1 = sqrtf(1e-5f);
    }
    unsigned int* o1 = ob + UB + ui;
    o1[0] = pk2(mean0, mean1);
    o1[UB] = pk2(lo0, lo1);
    o1[2 * UB] = pk2(hi0, hi1);
    o1[3 * UB] = pk2(sd0, sd1);
    o1[4 * UB] = pk2(an * mean0, an * mean1);
    o1[5 * UB] = pk2(an * lo0, an * lo1);
    o1[6 * UB] = pk2(an * hi0, an * hi1);
    o1[7 * UB] = pk2(an * sd0, an * sd1);
    o1[8 * UB] = pk2(cn * mean0, cn * mean1);
    o1[9 * UB] = pk2(cn * lo0, cn * lo1);
    o1[10 * UB] = pk2(cn * hi0, cn * hi1);
    o1[11 * UB] = pk2(cn * sd0, cn * sd1);
  }
}

// ---------------- BN ----------------
template <int FO, typename Ti>
__global__ __launch_bounds__(256) void k_bn_stats(const Ti* __restrict__ o, float* __restrict__ gsum,
                                                  float* __restrict__ gsq) {
  constexpr int P = 256 / FO;
  int c = threadIdx.x % FO;
  int p = threadIdx.x / FO;
  float s1 = 0.f, s2 = 0.f;
  for (int n = blockIdx.x * P + p; n < N_NODES; n += gridDim.x * P) {
    float v = ldf(o[(size_t)n * FO + c]);
    s1 += v;
    s2 += v * v;
  }
  __shared__ float L1[256], L2[256];
  L1[threadIdx.x] = s1;
  L2[threadIdx.x] = s2;
  __syncthreads();
  if (p == 0) {
#pragma unroll
    for (int q = 1; q < P; q++) {
      s1 += L1[q * FO + c];
      s2 += L2[q * FO + c];
    }
    atomicAdd(&gsum[c], s1);
    atomicAdd(&gsq[c], s2);
  }
}

__global__ void k_bn_fin(const float* bnsum, const float* bnsq, float* bnmean, float* bnrs, int FO) {
  int c = threadIdx.x;
  if (c < FO) {
    float mean = bnsum[c] / (float)N_NODES;
    float var = bnsq[c] / (float)N_NODES - mean * mean;
    bnmean[c] = mean;
    bnrs[c] = rsqrtf(var + 1e-5f);
  }
}

template <typename Ti>
__global__ void k_bn_elu(const Ti* __restrict__ o, const float* __restrict__ mean,
                         const float* __restrict__ rs, const float* __restrict__ gamma,
                         const float* __restrict__ beta, unsigned short* __restrict__ h,
                         float* __restrict__ bnout, int FO) {
  int idx = blockIdx.x * blockDim.x + threadIdx.x;
  if (idx < N_NODES * FO) {
    int c = idx % FO;
    float y = gamma[c] * (ldf(o[idx]) - mean[c]) * rs[c] + beta[c];
    if (bnout) bnout[idx] = y;
    h[idx] = f2b(y > 0.f ? y : expm1f(y));
  }
}

// ---------------- misc ----------------
__global__ void k_bcomb(const float* __restrict__ bpost, const float* __restrict__ Wlin,
                        const float* __restrict__ blin, float* __restrict__ bcomb, int FO) {
  int j = threadIdx.x;
  if (j < FO) {
    float acc = blin[j];
    for (int k = 0; k < FO; k++) acc += bpost[k] * Wlin[k * FO + j];
    bcomb[j] = acc;
  }
}

__global__ void k_add(const unsigned short* __restrict__ a, const unsigned short* __restrict__ b,
                      unsigned short* __restrict__ c) {
  int idx = blockIdx.x * blockDim.x + threadIdx.x;
  if (idx < N_NODES * 128) c[idx] = f2b(b2f(a[idx]) + b2f(b[idx]));
}

__global__ void k_logits(const unsigned short* __restrict__ h4, const float* __restrict__ Wc,
                         const float* __restrict__ bc, float* __restrict__ out) {
  int n = blockIdx.x * blockDim.x + threadIdx.x;
  if (n < N_NODES) {
    float acc0 = bc[0], acc1 = bc[1];
    const unsigned short* hr = h4 + (size_t)n * 64;
    for (int k = 0; k < 64; k++) {
      float v = b2f(hr[k]);
      acc0 += v * Wc[k * 2 + 0];
      acc1 += v * Wc[k * 2 + 1];
    }
    out[n * 2 + 0] = acc0;
    out[n * 2 + 1] = acc1;
  }
}

// ---------------- driver ----------------
struct WS {
  int *ptr, *col, *cnt, *degall;
  float *scal, *a_arr, *c_arr, *bnsum, *bnsq, *bnmean, *bnrs, *bcomb, *biasPre;
  unsigned short *wcombT, *wpreT;
  unsigned short *xb, *h1, *h2, *h3, *ts, *aggx;
  size_t agg_elems;
};

template <int F, typename To>
static void run_layer(const unsigned short* xin, To* o_ptr, float* bnout, unsigned short* hout,
                      const float* Wpre, const float* bpre, const float* Wpost, const float* bpost,
                      const float* Wlin, const float* blin, const float* gamma, const float* beta,
                      int FO, const WS& ws, hipStream_t stream) {
  const int N = N_NODES;
  const int K13 = 13 * F;
  // weight prep (wcombT written transposed-bf16 directly)
  {
    dim3 g((FO + 127) / 128, (K13 + 127) / 128);
    k_wcombT<<<g, 256, 0, stream>>>(Wpost, Wlin, ws.wcombT, K13, FO, FO);
    k_bcomb<<<1, 256, 0, stream>>>(bpost, Wlin, blin, ws.bcomb, FO);
    k_tcast_pre<<<(2 * F * F + 255) / 256, 256, 0, stream>>>(Wpre, ws.wpreT, F);
    k_biaspre<<<1, 512, 0, stream>>>(bpre, ws.biasPre, F);
  }
  // fused pre-GEMM: ts = xin @ [W1 | W2] + [bpre | 0]
  {
    dim3 g(2 * F / 128, (N + 127) / 128);
    k_mm<unsigned short><<<g, 256, 0, stream>>>(xin, F, ws.wpreT, ws.biasPre, ws.ts, 0, N, 2 * F);
  }
  // chunked: edge aggregation (materializes 13F A) -> m97-style post GEMM
  int NB = (int)(ws.agg_elems / (size_t)K13);
  NB &= ~127;
  if (NB > N) NB = N;
  if (NB < 128) NB = 128;
  for (int c0 = 0; c0 < N; c0 += NB) {
    int nc = (N - c0 < NB) ? (N - c0) : NB;
    k_edge_agg<F><<<(nc + 3) / 4, 256, 0, stream>>>(ws.ts, xin, ws.ptr, ws.col,
                                                    ws.a_arr, ws.c_arr, ws.aggx, c0, nc);
    if (FO == 64) {
      dim3 g(1, (nc + 127) / 128);
      k_tile<64, To><<<g, 256, 0, stream>>>(ws.aggx, K13, K13, ws.wcombT, ws.bcomb, o_ptr, c0, nc, FO);
    } else {
      dim3 g(FO / 128, (nc + 127) / 128);
      k_mm<To><<<g, 256, 0, stream>>>(ws.aggx, K13, ws.wcombT, ws.bcomb, o_ptr, c0, nc, FO);
    }
  }
  // BN + ELU
  hipMemsetAsync(ws.bnsum, 0, 256 * sizeof(float), stream);
  hipMemsetAsync(ws.bnsq, 0, 256 * sizeof(float), stream);
  if (FO == 64)
    k_bn_stats<64, To><<<128, 256, 0, stream>>>(o_ptr, ws.bnsum, ws.bnsq);
  else if (FO == 128)
    k_bn_stats<128, To><<<128, 256, 0, stream>>>(o_ptr, ws.bnsum, ws.bnsq);
  else
    k_bn_stats<256, To><<<128, 256, 0, stream>>>(o_ptr, ws.bnsum, ws.bnsq);
  k_bn_fin<<<1, 256, 0, stream>>>(ws.bnsum, ws.bnsq, ws.bnmean, ws.bnrs, FO);
  int total = N_NODES * FO;
  k_bn_elu<To><<<(total + 255) / 256, 256, 0, stream>>>(o_ptr, ws.bnmean, ws.bnrs, gamma, beta, hout, bnout, FO);
}

extern "C" void kernel_launch(void* const* d_in, const int* in_sizes, int n_in,
                              void* d_out, int out_size, void* d_ws, size_t ws_size,
                              hipStream_t stream) {
  const int N = N_NODES, E = N_EDGES;
  const float* x = (const float*)d_in[0];
  const int* ei = (const int*)d_in[1];
  const int* src = ei;
  const int* dst = ei + E;
  const float *Wpre[4], *bpre[4], *Wpost[4], *bpost[4], *Wlin[4], *blin[4], *gamma[4], *beta[4];
  for (int i = 0; i < 4; i++) {
    const int b = 2 + i * 8;
    Wpre[i] = (const float*)d_in[b + 0];
    bpre[i] = (const float*)d_in[b + 1];
    Wpost[i] = (const float*)d_in[b + 2];
    bpost[i] = (const float*)d_in[b + 3];
    Wlin[i] = (const float*)d_in[b + 4];
    blin[i] = (const float*)d_in[b + 5];
    gamma[i] = (const float*)d_in[b + 6];
    beta[i] = (const float*)d_in[b + 7];
  }
  const float* Wc = (const float*)d_in[34];
  const float* bcv = (const float*)d_in[35];

  // ----- workspace layout (~119 MB fixed + adaptive aggx) -----
  char* w = (char*)d_ws;
  size_t off = 0;
  auto alloc = [&](size_t bytes) -> void* {
    void* p = (void*)(w + off);
    off = (off + bytes + 255) & ~(size_t)255;
    return p;
  };
  WS ws;
  ws.ptr = (int*)alloc((N + 1) * sizeof(int));
  ws.col = (int*)alloc((size_t)E * sizeof(int));
  ws.cnt = (int*)alloc((size_t)N * sizeof(int));
  ws.degall = (int*)alloc((size_t)N * sizeof(int));
  ws.scal = (float*)alloc(16 * sizeof(float));
  ws.a_arr = (float*)alloc((size_t)N * sizeof(float));
  ws.c_arr = (float*)alloc((size_t)N * sizeof(float));
  ws.bnsum = (float*)alloc(256 * sizeof(float));
  ws.bnsq = (float*)alloc(256 * sizeof(float));
  ws.bnmean = (float*)alloc(256 * sizeof(float));
  ws.bnrs = (float*)alloc(256 * sizeof(float));
  ws.bcomb = (float*)alloc(256 * sizeof(float));
  ws.biasPre = (float*)alloc(512 * sizeof(float));
  ws.wcombT = (unsigned short*)alloc((size_t)256 * 3328 * sizeof(unsigned short));
  ws.wpreT = (unsigned short*)alloc((size_t)512 * 256 * sizeof(unsigned short));
  ws.xb = (unsigned short*)alloc((size_t)N * 128 * sizeof(unsigned short));
  ws.h1 = (unsigned short*)alloc((size_t)N * 128 * sizeof(unsigned short));
  ws.h2 = (unsigned short*)alloc((size_t)N * 256 * sizeof(unsigned short));
  ws.h3 = (unsigned short*)alloc((size_t)N * 128 * sizeof(unsigned short));
  ws.ts = (unsigned short*)alloc((size_t)N * 512 * sizeof(unsigned short));
  size_t rem = (ws_size > off) ? (ws_size - off) : 0;
  ws.agg_elems = rem / sizeof(unsigned short);
  ws.aggx = (unsigned short*)(w + off);
  unsigned short* h4 = ws.xb;  // alias: x dead after layer 1; h4 is [N,64]

  float* outp = (float*)d_out;
  float* logits = outp;              // [N,2]
  float* p4 = outp + (size_t)N * 2;  // [N,64]
  float* b4 = p4 + (size_t)N * 64;   // [N,64]
  unsigned short* o_scratch = (unsigned short*)p4;  // pre-BN scratch, overwritten by layer 4

  // ----- degree / CSR / scalars -----
  hipMemsetAsync(ws.cnt, 0, N * sizeof(int), stream);
  hipMemsetAsync(ws.degall, 0, N * sizeof(int), stream);
  hipMemsetAsync(ws.scal, 0, 16 * sizeof(float), stream);
  k_count<<<(E + 255) / 256, 256, 0, stream>>>(src, dst, ws.cnt, ws.degall);
  k_scan<<<1, 1024, 0, stream>>>(ws.cnt, ws.ptr);
  hipMemsetAsync(ws.cnt, 0, N * sizeof(int), stream);
  k_fill<<<(E + 255) / 256, 256, 0, stream>>>(src, dst, ws.ptr, ws.cnt, ws.col);
  k_avglog<<<64, 256, 0, stream>>>(ws.degall, ws.scal);
  k_avg_fin<<<1, 1, 0, stream>>>(ws.scal);
  k_scalars<<<(N + 255) / 256, 256, 0, stream>>>(ws.ptr, ws.scal, ws.a_arr, ws.c_arr);
  k_cast<<<(N * 128 + 255) / 256, 256, 0, stream>>>(x, ws.xb, N * 128);

  run_layer<128, unsigned short>(ws.xb, o_scratch, nullptr, ws.h1,
                                 Wpre[0], bpre[0], Wpost[0], bpost[0], Wlin[0], blin[0], gamma[0], beta[0],
                                 128, ws, stream);
  run_layer<128, unsigned short>(ws.h1, o_scratch, nullptr, ws.h2,
                                 Wpre[1], bpre[1], Wpost[1], bpost[1], Wlin[1], blin[1], gamma[1], beta[1],
                                 256, ws, stream);
  run_layer<256, unsigned short>(ws.h2, o_scratch, nullptr, ws.h3,
                                 Wpre[2], bpre[2], Wpost[2], bpost[2], Wlin[2], blin[2], gamma[2], beta[2],
                                 128, ws, stream);
  k_add<<<((N * 128) + 255) / 256, 256, 0, stream>>>(ws.h1, ws.h3, ws.h3);  // x4 = h1 + h3 in place
  run_layer<128, float>(ws.h3, p4, b4, h4,
                        Wpre[3], bpre[3], Wpost[3], bpost[3], Wlin[3], blin[3], gamma[3], beta[3],
                        64, ws, stream);
  k_logits<<<(N + 255) / 256, 256, 0, stream>>>(h4, Wc, bcv, logits);
  (void)in_sizes; (void)n_in; (void)out_size; (void)ws_size;
}

// Round 10
// 1550.310 us; speedup vs baseline: 1.4570x; 1.0992x over previous
//
#include <hip/hip_runtime.h>
#include <math.h>

#define N_NODES 50000
#define N_EDGES 500000

using bf16x8 = __attribute__((ext_vector_type(8))) short;
using f32x4  = __attribute__((ext_vector_type(4))) float;

// ---------- bf16 helpers ----------
__device__ inline float b2f(unsigned short u) {
  union { unsigned int i; float f; } v; v.i = ((unsigned int)u) << 16; return v.f;
}
__device__ inline unsigned short f2b(float f) {
  union { float f; unsigned int i; } v; v.f = f;
  unsigned int x = v.i;
  return (unsigned short)((x + 0x7fffu + ((x >> 16) & 1u)) >> 16);
}
__device__ inline unsigned int pk2(float a, float b) {
  return (unsigned int)f2b(a) | ((unsigned int)f2b(b) << 16);
}
__device__ inline void stv(unsigned short* p, float v) { *p = f2b(v); }
__device__ inline void stv(float* p, float v) { *p = v; }
__device__ inline float ldf(unsigned short u) { return b2f(u); }
__device__ inline float ldf(float f) { return f; }
__host__ __device__ inline int imin(int a, int b) { return a < b ? a : b; }

// direct global->LDS DMA, 16B per lane; lds base is wave-uniform
__device__ inline void gload16(const unsigned short* g, unsigned short* l) {
  __builtin_amdgcn_global_load_lds((const __attribute__((address_space(1))) unsigned int*)g,
                                   (__attribute__((address_space(3))) unsigned int*)l, 16, 0, 0);
}

// ---------------- degree / CSR ----------------
__global__ void k_count(const int* __restrict__ src, const int* __restrict__ dst,
                        int* __restrict__ cnt, int* __restrict__ degall) {
  int e = blockIdx.x * blockDim.x + threadIdx.x;
  if (e < N_EDGES) {
    atomicAdd(&cnt[dst[e]], 1);
    atomicAdd(&degall[src[e]], 1);
    atomicAdd(&degall[dst[e]], 1);
  }
}

__global__ __launch_bounds__(1024) void k_scan(const int* __restrict__ cnt, int* __restrict__ ptr) {
  __shared__ int buf[1024];
  __shared__ int carry;
  if (threadIdx.x == 0) carry = 0;
  __syncthreads();
  for (int base = 0; base < N_NODES; base += 1024) {
    int i = base + threadIdx.x;
    int v = (i < N_NODES) ? cnt[i] : 0;
    buf[threadIdx.x] = v;
    __syncthreads();
    for (int off = 1; off < 1024; off <<= 1) {
      int tv = (threadIdx.x >= off) ? buf[threadIdx.x - off] : 0;
      __syncthreads();
      buf[threadIdx.x] += tv;
      __syncthreads();
    }
    if (i < N_NODES) ptr[i] = carry + buf[threadIdx.x] - v;
    int total = buf[1023];
    __syncthreads();
    if (threadIdx.x == 0) carry += total;
    __syncthreads();
  }
  if (threadIdx.x == 0) ptr[N_NODES] = carry;
}

__global__ void k_fill(const int* __restrict__ src, const int* __restrict__ dst,
                       const int* __restrict__ ptr, int* __restrict__ cnt, int* __restrict__ col) {
  int e = blockIdx.x * blockDim.x + threadIdx.x;
  if (e < N_EDGES) {
    int d = dst[e];
    int pos = atomicAdd(&cnt[d], 1);
    col[ptr[d] + pos] = src[e];
  }
}

__global__ void k_avglog(const int* __restrict__ degall, float* __restrict__ scal) {
  __shared__ float L[256];
  float s = 0.f;
  for (int n = blockIdx.x * blockDim.x + threadIdx.x; n < N_NODES; n += gridDim.x * blockDim.x)
    s += logf((float)degall[n] + 1.0f);
  L[threadIdx.x] = s;
  __syncthreads();
  for (int o = 128; o > 0; o >>= 1) {
    if (threadIdx.x < o) L[threadIdx.x] += L[threadIdx.x + o];
    __syncthreads();
  }
  if (threadIdx.x == 0) atomicAdd(&scal[0], L[0]);
}

__global__ void k_avg_fin(float* scal) {
  float avg = scal[0] / (float)N_NODES;
  scal[1] = avg;
  scal[2] = 1.0f / avg;
}

__global__ void k_scalars(const int* __restrict__ ptr, const float* __restrict__ scal,
                          float* __restrict__ a_arr, float* __restrict__ c_arr) {
  int n = blockIdx.x * blockDim.x + threadIdx.x;
  if (n < N_NODES) {
    int d = ptr[n + 1] - ptr[n];
    float degc = fmaxf((float)d, 1.f);
    float logd = logf(degc + 1.f);
    a_arr[n] = logd * scal[2];
    c_arr[n] = scal[1] / logd;
  }
}

__global__ void k_cast(const float* __restrict__ x, unsigned short* __restrict__ xb, int total) {
  int i = blockIdx.x * blockDim.x + threadIdx.x;
  if (i < total) xb[i] = f2b(x[i]);
}

// pre-weights: BT_pre[j][k] = j<F ? Wpre[k][j] : Wpre[F+k][j-F]   (j<2F, k<F)
__global__ void k_tcast_pre(const float* __restrict__ Wpre, unsigned short* __restrict__ out, int F) {
  int i = blockIdx.x * blockDim.x + threadIdx.x;
  if (i < 2 * F * F) {
    int j = i / F, k = i % F;
    float v = (j < F) ? Wpre[(size_t)k * F + j] : Wpre[(size_t)(F + k) * F + (j - F)];
    out[i] = f2b(v);
  }
}

__global__ void k_biaspre(const float* __restrict__ bpre, float* __restrict__ biasPre, int F) {
  int j = threadIdx.x;
  if (j < 2 * F) biasPre[j] = (j < F) ? bpre[j] : 0.f;
}

// ---------------- weight GEMM: CT[c][r] = bf16( (Wpost@Wlin)[r][c] ) ----------------
__global__ __launch_bounds__(256) void k_wcombT(const float* __restrict__ A, const float* __restrict__ B,
                                                unsigned short* __restrict__ CT, int M, int Ncol, int K) {
  __shared__ float As[16][136];
  __shared__ float Bs[16][128];
  int tid = threadIdx.x;
  int row0 = blockIdx.y * 128, col0 = blockIdx.x * 128;
  int am = tid >> 1, ah = (tid & 1) * 8;
  int ty = tid >> 4, tx = tid & 15;
  float acc[8][8];
#pragma unroll
  for (int i = 0; i < 8; i++)
#pragma unroll
    for (int j = 0; j < 8; j++) acc[i][j] = 0.f;
  int arow = row0 + am;
  bool av = arow < M;
  const float* Ar = A + (size_t)arow * K;
  for (int k0 = 0; k0 < K; k0 += 16) {
    float4 a0 = make_float4(0, 0, 0, 0), a1 = make_float4(0, 0, 0, 0);
    if (av) {
      a0 = *(const float4*)(Ar + k0 + ah);
      a1 = *(const float4*)(Ar + k0 + ah + 4);
    }
    As[ah + 0][am] = a0.x; As[ah + 1][am] = a0.y; As[ah + 2][am] = a0.z; As[ah + 3][am] = a0.w;
    As[ah + 4][am] = a1.x; As[ah + 5][am] = a1.y; As[ah + 6][am] = a1.z; As[ah + 7][am] = a1.w;
#pragma unroll
    for (int i = 0; i < 2; i++) {
      int q = tid * 2 + i;
      int kk = q >> 5, j4 = (q & 31) * 4;
      int bc = col0 + j4;
      float4 b = make_float4(0, 0, 0, 0);
      if (bc < Ncol && (k0 + kk) < K) b = *(const float4*)(B + (size_t)(k0 + kk) * Ncol + bc);
      *(float4*)(&Bs[kk][j4]) = b;
    }
    __syncthreads();
#pragma unroll
    for (int kk = 0; kk < 16; kk++) {
      float av8[8], bv8[8];
#pragma unroll
      for (int i = 0; i < 8; i++) av8[i] = As[kk][ty * 8 + i];
#pragma unroll
      for (int j = 0; j < 8; j++) bv8[j] = Bs[kk][tx * 8 + j];
#pragma unroll
      for (int i = 0; i < 8; i++)
#pragma unroll
        for (int j = 0; j < 8; j++) acc[i][j] = fmaf(av8[i], bv8[j], acc[i][j]);
    }
    __syncthreads();
  }
#pragma unroll
  for (int i = 0; i < 8; i++) {
    int r = row0 + ty * 8 + i;
    if (r < M) {
#pragma unroll
      for (int j = 0; j < 8; j++) {
        int c = col0 + tx * 8 + j;
        if (c < Ncol) CT[(size_t)c * M + r] = f2b(acc[i][j]);
      }
    }
  }
}

// ---------------- m97-style MFMA GEMM: 128x128 tile, 64x64/wave, gload_lds dbuf ----------------
template <typename To>
__global__ __launch_bounds__(256) void k_mm(
    const unsigned short* __restrict__ A, int K,
    const unsigned short* __restrict__ BT,
    const float* __restrict__ bias,
    To* __restrict__ C, int n0, int M, int Ncol) {
  __shared__ unsigned short lds[2][2][4096];  // [buf][A/B][128 rows x 32 cols]
  const int tid = threadIdx.x;
  const int lane = tid & 63;
  const int wid = tid >> 6;
  const int wr = wid >> 1, wc = wid & 1;
  const int row0 = blockIdx.y * 128;
  const int col0 = blockIdx.x * 128;
  const int l15 = lane & 15, lq = lane >> 4;
  const int srow = wid * 32 + (lane >> 2);
  const int scol = (lane & 3) * 8;
  const unsigned short* gA0 = A + (size_t)imin(row0 + srow, N_NODES - 1) * K + scol;
  const unsigned short* gA1 = A + (size_t)imin(row0 + srow + 16, N_NODES - 1) * K + scol;
  const unsigned short* gB0 = BT + (size_t)(col0 + srow) * K + scol;
  const unsigned short* gB1 = BT + (size_t)(col0 + srow + 16) * K + scol;

  f32x4 acc[4][4];
#pragma unroll
  for (int m = 0; m < 4; m++)
#pragma unroll
    for (int n = 0; n < 4; n++) acc[m][n] = (f32x4){0.f, 0.f, 0.f, 0.f};

  auto stage = [&](int buf, int k0) {
    gload16(gA0 + k0, &lds[buf][0][wid * 1024]);
    gload16(gA1 + k0, &lds[buf][0][wid * 1024 + 512]);
    gload16(gB0 + k0, &lds[buf][1][wid * 1024]);
    gload16(gB1 + k0, &lds[buf][1][wid * 1024 + 512]);
  };

  const int nk = K / 32;
  stage(0, 0);
  __syncthreads();
  for (int t = 0; t < nk; ++t) {
    const int cur = t & 1;
    if (t + 1 < nk) stage(cur ^ 1, (t + 1) * 32);
    bf16x8 a[4], b[4];
#pragma unroll
    for (int m = 0; m < 4; m++)
      a[m] = *(const bf16x8*)&lds[cur][0][(wr * 64 + m * 16 + l15) * 32 + lq * 8];
#pragma unroll
    for (int n = 0; n < 4; n++)
      b[n] = *(const bf16x8*)&lds[cur][1][(wc * 64 + n * 16 + l15) * 32 + lq * 8];
#pragma unroll
    for (int m = 0; m < 4; m++)
#pragma unroll
      for (int n = 0; n < 4; n++)
        acc[m][n] = __builtin_amdgcn_mfma_f32_16x16x32_bf16(a[m], b[n], acc[m][n], 0, 0, 0);
    __syncthreads();
  }
#pragma unroll
  for (int n = 0; n < 4; n++) {
    int col = col0 + wc * 64 + n * 16 + l15;
    float bv = bias ? bias[col] : 0.f;
#pragma unroll
    for (int m = 0; m < 4; m++) {
#pragma unroll
      for (int j = 0; j < 4; j++) {
        int r = row0 + wr * 64 + m * 16 + lq * 4 + j;
        if (r < M) stv(&C[(size_t)(n0 + r) * Ncol + col], acc[m][n][j] + bv);
      }
    }
  }
}

// ---------------- reg-staged MFMA GEMM for Ncol=64 (layer-4 post) ----------------
template <int NTILE, typename To>
__global__ __launch_bounds__(256) void k_tile(
    const unsigned short* __restrict__ A, int lda, int K,
    const unsigned short* __restrict__ BT,
    const float* __restrict__ bias,
    To* __restrict__ C, int n0, int M, int Ncol) {
  constexpr int WN = NTILE / 64;
  constexpr int WM = 4 / WN;
  constexpr int MTILE = WM * 32;
  constexpr int PK = 40;
  constexpr int CA = MTILE / 64;
  constexpr int CB = NTILE / 64;
  __shared__ unsigned short As[MTILE][PK];
  __shared__ unsigned short Bs[NTILE][PK];
  const int tid = threadIdx.x;
  const int lane = tid & 63;
  const int wid = tid >> 6;
  const int wr = wid / WN;
  const int wc = wid % WN;
  const int row0 = blockIdx.y * MTILE;
  const int col0 = blockIdx.x * NTILE;
  const int l15 = lane & 15, lq = lane >> 4;
  uint4 apf[CA], bpf[CB];
  f32x4 acc[2][4];
#pragma unroll
  for (int m = 0; m < 2; m++)
#pragma unroll
    for (int n = 0; n < 4; n++) acc[m][n] = (f32x4){0.f, 0.f, 0.f, 0.f};

  auto load = [&](int k0) {
#pragma unroll
    for (int i = 0; i < CA; i++) {
      int idx = tid + 256 * i;
      int r = idx >> 2, c8 = (idx & 3) * 8;
      int gr = row0 + r;
      uint4 v = make_uint4(0u, 0u, 0u, 0u);
      if (gr < M) v = *(const uint4*)(A + (size_t)gr * lda + k0 + c8);
      apf[i] = v;
    }
#pragma unroll
    for (int i = 0; i < CB; i++) {
      int idx = tid + 256 * i;
      int r = idx >> 2, c8 = (idx & 3) * 8;
      bpf[i] = *(const uint4*)(BT + (size_t)(col0 + r) * K + k0 + c8);
    }
  };

  load(0);
  for (int k0 = 0; k0 < K; k0 += 32) {
#pragma unroll
    for (int i = 0; i < CA; i++) {
      int idx = tid + 256 * i;
      *(uint4*)&As[idx >> 2][(idx & 3) * 8] = apf[i];
    }
#pragma unroll
    for (int i = 0; i < CB; i++) {
      int idx = tid + 256 * i;
      *(uint4*)&Bs[idx >> 2][(idx & 3) * 8] = bpf[i];
    }
    __syncthreads();
    if (k0 + 32 < K) load(k0 + 32);
    bf16x8 af0 = *(const bf16x8*)&As[wr * 32 + l15][lq * 8];
    bf16x8 af1 = *(const bf16x8*)&As[wr * 32 + 16 + l15][lq * 8];
#pragma unroll
    for (int n = 0; n < 4; n++) {
      bf16x8 bf = *(const bf16x8*)&Bs[wc * 64 + n * 16 + l15][lq * 8];
      acc[0][n] = __builtin_amdgcn_mfma_f32_16x16x32_bf16(af0, bf, acc[0][n], 0, 0, 0);
      acc[1][n] = __builtin_amdgcn_mfma_f32_16x16x32_bf16(af1, bf, acc[1][n], 0, 0, 0);
    }
    __syncthreads();
  }
#pragma unroll
  for (int n = 0; n < 4; n++) {
    int col = col0 + wc * 64 + n * 16 + l15;
    float bv = bias ? bias[col] : 0.f;
#pragma unroll
    for (int m = 0; m < 2; m++) {
#pragma unroll
      for (int j = 0; j < 4; j++) {
        int r = row0 + wr * 32 + m * 16 + lq * 4 + j;
        if (r < M) stv(&C[(size_t)(n0 + r) * Ncol + col], acc[m][n][j] + bv);
      }
    }
  }
}

// ---------------- edge aggregation (vectorized): writes 13F rows [x | agg | an*agg | cn*agg] ----------------
template <int F>
__global__ __launch_bounds__(256) void k_edge_agg(
    const unsigned short* __restrict__ ts, const unsigned short* __restrict__ xin,
    const int* __restrict__ ptr, const int* __restrict__ col,
    const float* __restrict__ a_arr, const float* __restrict__ c_arr,
    unsigned short* __restrict__ aggx, int n0, int nchunk) {
  constexpr int VU = F / 128;
  int idx = (blockIdx.x * blockDim.x + threadIdx.x) >> 6;
  int lane = threadIdx.x & 63;
  if (idx >= nchunk) return;
  int n = n0 + idx;
  if (n >= N_NODES) return;
  float S1[2 * VU], S2[2 * VU], mn[2 * VU], mx[2 * VU];
#pragma unroll
  for (int u = 0; u < 2 * VU; u++) {
    S1[u] = 0.f; S2[u] = 0.f; mn[u] = 3.4e38f; mx[u] = -3.4e38f;
  }
  int e0 = ptr[n], e1 = ptr[n + 1];
  for (int e = e0; e < e1; ++e) {
    int sidx = col[e];
    const unsigned int* sr = (const unsigned int*)(ts + (size_t)sidx * 2 * F + F);
#pragma unroll
    for (int u = 0; u < VU; u++) {
      unsigned int v = sr[lane + 64 * u];
      float f0 = b2f((unsigned short)(v & 0xffff));
      float f1 = b2f((unsigned short)(v >> 16));
      S1[2 * u] += f0; S2[2 * u] += f0 * f0;
      mn[2 * u] = fminf(mn[2 * u], f0); mx[2 * u] = fmaxf(mx[2 * u], f0);
      S1[2 * u + 1] += f1; S2[2 * u + 1] += f1 * f1;
      mn[2 * u + 1] = fminf(mn[2 * u + 1], f1); mx[2 * u + 1] = fmaxf(mx[2 * u + 1], f1);
    }
  }
  int d = e1 - e0;
  float an = a_arr[n], cn = c_arr[n];
  const unsigned int* tr = (const unsigned int*)(ts + (size_t)n * 2 * F);
  const unsigned int* xr = (const unsigned int*)(xin + (size_t)n * F);
  unsigned int* ob = (unsigned int*)(aggx + (size_t)idx * 13 * F);
  constexpr int UB = 64 * VU;
#pragma unroll
  for (int u = 0; u < VU; u++) {
    int ui = lane + 64 * u;
    ob[ui] = xr[ui];
    float mean0, mean1, lo0, lo1, hi0, hi1, sd0, sd1;
    if (d > 0) {
      float inv = 1.f / (float)d;
      unsigned int tv = tr[ui];
      float t0 = b2f((unsigned short)(tv & 0xffff));
      float t1 = b2f((unsigned short)(tv >> 16));
      float ms0 = S1[2 * u] * inv, ms1 = S1[2 * u + 1] * inv;
      sd0 = sqrtf(fmaxf(S2[2 * u] * inv - ms0 * ms0, 0.f) + 1e-5f);
      sd1 = sqrtf(fmaxf(S2[2 * u + 1] * inv - ms1 * ms1, 0.f) + 1e-5f);
      mean0 = t0 + ms0; mean1 = t1 + ms1;
      lo0 = t0 + mn[2 * u]; lo1 = t1 + mn[2 * u + 1];
      hi0 = t0 + mx[2 * u]; hi1 = t1 + mx[2 * u + 1];
    } else {
      mean0 = mean1 = lo0 = lo1 = hi0 = hi1 = 0.f;
      sd0 = sd1 = sqrtf(1e-5f);
    }
    unsigned int* o1 = ob + UB + ui;
    o1[0] = pk2(mean0, mean1);
    o1[UB] = pk2(lo0, lo1);
    o1[2 * UB] = pk2(hi0, hi1);
    o1[3 * UB] = pk2(sd0, sd1);
    o1[4 * UB] = pk2(an * mean0, an * mean1);
    o1[5 * UB] = pk2(an * lo0, an * lo1);
    o1[6 * UB] = pk2(an * hi0, an * hi1);
    o1[7 * UB] = pk2(an * sd0, an * sd1);
    o1[8 * UB] = pk2(cn * mean0, cn * mean1);
    o1[9 * UB] = pk2(cn * lo0, cn * lo1);
    o1[10 * UB] = pk2(cn * hi0, cn * hi1);
    o1[11 * UB] = pk2(cn * sd0, cn * sd1);
  }
}

// ---------------- BN stats: vectorized grid-stride + LDS reduce + 1 atomic/col/block ----------------
template <int FO>
__global__ __launch_bounds__(256) void k_bn_stats_bf(const unsigned short* __restrict__ o,
                                                     float* __restrict__ gsum, float* __restrict__ gsq) {
  constexpr int TOTAL = N_NODES * FO;
  float s1[8], s2[8];
#pragma unroll
  for (int j = 0; j < 8; j++) { s1[j] = 0.f; s2[j] = 0.f; }
  const int stride = gridDim.x * 2048;
  for (int base = blockIdx.x * 2048 + threadIdx.x * 8; base < TOTAL; base += stride) {
    uint4 v = *(const uint4*)(o + base);
    const unsigned int* u = (const unsigned int*)&v;
#pragma unroll
    for (int w = 0; w < 4; w++) {
      float f0 = b2f((unsigned short)(u[w] & 0xffff));
      float f1 = b2f((unsigned short)(u[w] >> 16));
      s1[2 * w] += f0; s2[2 * w] += f0 * f0;
      s1[2 * w + 1] += f1; s2[2 * w + 1] += f1 * f1;
    }
  }
  __shared__ float L1[2048], L2[2048];
#pragma unroll
  for (int j = 0; j < 8; j++) {
    L1[threadIdx.x * 8 + j] = s1[j];
    L2[threadIdx.x * 8 + j] = s2[j];
  }
  __syncthreads();
  int c = threadIdx.x;
  if (c < FO) {
    float a1 = 0.f, a2 = 0.f;
    for (int i = c; i < 2048; i += FO) { a1 += L1[i]; a2 += L2[i]; }
    atomicAdd(&gsum[c], a1);
    atomicAdd(&gsq[c], a2);
  }
}

template <int FO>
__global__ __launch_bounds__(256) void k_bn_stats_f32(const float* __restrict__ o,
                                                      float* __restrict__ gsum, float* __restrict__ gsq) {
  constexpr int TOTAL = N_NODES * FO;
  float s1[4], s2[4];
#pragma unroll
  for (int j = 0; j < 4; j++) { s1[j] = 0.f; s2[j] = 0.f; }
  const int stride = gridDim.x * 1024;
  for (int base = blockIdx.x * 1024 + threadIdx.x * 4; base < TOTAL; base += stride) {
    float4 v = *(const float4*)(o + base);
    s1[0] += v.x; s2[0] += v.x * v.x;
    s1[1] += v.y; s2[1] += v.y * v.y;
    s1[2] += v.z; s2[2] += v.z * v.z;
    s1[3] += v.w; s2[3] += v.w * v.w;
  }
  __shared__ float L1[1024], L2[1024];
#pragma unroll
  for (int j = 0; j < 4; j++) {
    L1[threadIdx.x * 4 + j] = s1[j];
    L2[threadIdx.x * 4 + j] = s2[j];
  }
  __syncthreads();
  int c = threadIdx.x;
  if (c < FO) {
    float a1 = 0.f, a2 = 0.f;
    for (int i = c; i < 1024; i += FO) { a1 += L1[i]; a2 += L2[i]; }
    atomicAdd(&gsum[c], a1);
    atomicAdd(&gsq[c], a2);
  }
}

__global__ void k_bn_fin(const float* bnsum, const float* bnsq, float* bnmean, float* bnrs, int FO) {
  int c = threadIdx.x;
  if (c < FO) {
    float mean = bnsum[c] / (float)N_NODES;
    float var = bnsq[c] / (float)N_NODES - mean * mean;
    bnmean[c] = mean;
    bnrs[c] = rsqrtf(var + 1e-5f);
  }
}

// ---------------- BN+ELU (vectorized) ----------------
template <int FO>
__global__ __launch_bounds__(256) void k_bn_elu_bf(const unsigned short* __restrict__ o,
                                                   const float* __restrict__ mean, const float* __restrict__ rs,
                                                   const float* __restrict__ gamma, const float* __restrict__ beta,
                                                   unsigned short* __restrict__ h) {
  constexpr int TOTAL = N_NODES * FO;
  int base = (blockIdx.x * blockDim.x + threadIdx.x) * 8;
  if (base >= TOTAL) return;
  int c0 = base % FO;
  uint4 v = *(const uint4*)(o + base);
  const unsigned int* u = (const unsigned int*)&v;
  unsigned int outw[4];
#pragma unroll
  for (int w = 0; w < 4; w++) {
    int c = c0 + 2 * w;
    float f0 = b2f((unsigned short)(u[w] & 0xffff));
    float f1 = b2f((unsigned short)(u[w] >> 16));
    float y0 = gamma[c] * (f0 - mean[c]) * rs[c] + beta[c];
    float y1 = gamma[c + 1] * (f1 - mean[c + 1]) * rs[c + 1] + beta[c + 1];
    y0 = y0 > 0.f ? y0 : expm1f(y0);
    y1 = y1 > 0.f ? y1 : expm1f(y1);
    outw[w] = pk2(y0, y1);
  }
  *(uint4*)(h + base) = *(uint4*)outw;
}

template <int FO>
__global__ __launch_bounds__(256) void k_bn_elu_f32(const float* __restrict__ o,
                                                    const float* __restrict__ mean, const float* __restrict__ rs,
                                                    const float* __restrict__ gamma, const float* __restrict__ beta,
                                                    unsigned short* __restrict__ h, float* __restrict__ bnout) {
  constexpr int TOTAL = N_NODES * FO;
  int base = (blockIdx.x * blockDim.x + threadIdx.x) * 4;
  if (base >= TOTAL) return;
  int c = base % FO;
  float4 v = *(const float4*)(o + base);
  float y0 = gamma[c] * (v.x - mean[c]) * rs[c] + beta[c];
  float y1 = gamma[c + 1] * (v.y - mean[c + 1]) * rs[c + 1] + beta[c + 1];
  float y2 = gamma[c + 2] * (v.z - mean[c + 2]) * rs[c + 2] + beta[c + 2];
  float y3 = gamma[c + 3] * (v.w - mean[c + 3]) * rs[c + 3] + beta[c + 3];
  if (bnout) *(float4*)(bnout + base) = make_float4(y0, y1, y2, y3);
  unsigned int o0 = pk2(y0 > 0.f ? y0 : expm1f(y0), y1 > 0.f ? y1 : expm1f(y1));
  unsigned int o1 = pk2(y2 > 0.f ? y2 : expm1f(y2), y3 > 0.f ? y3 : expm1f(y3));
  *(uint2*)(h + base) = make_uint2(o0, o1);
}

// ---------------- misc ----------------
__global__ void k_bcomb(const float* __restrict__ bpost, const float* __restrict__ Wlin,
                        const float* __restrict__ blin, float* __restrict__ bcomb, int FO) {
  int j = threadIdx.x;
  if (j < FO) {
    float acc = blin[j];
    for (int k = 0; k < FO; k++) acc += bpost[k] * Wlin[k * FO + j];
    bcomb[j] = acc;
  }
}

__global__ void k_add(const unsigned short* __restrict__ a, const unsigned short* __restrict__ b,
                      unsigned short* __restrict__ c) {
  int idx = blockIdx.x * blockDim.x + threadIdx.x;
  if (idx < N_NODES * 128) c[idx] = f2b(b2f(a[idx]) + b2f(b[idx]));
}

__global__ void k_logits(const unsigned short* __restrict__ h4, const float* __restrict__ Wc,
                         const float* __restrict__ bc, float* __restrict__ out) {
  int n = blockIdx.x * blockDim.x + threadIdx.x;
  if (n < N_NODES) {
    float acc0 = bc[0], acc1 = bc[1];
    const unsigned short* hr = h4 + (size_t)n * 64;
    for (int k = 0; k < 64; k++) {
      float v = b2f(hr[k]);
      acc0 += v * Wc[k * 2 + 0];
      acc1 += v * Wc[k * 2 + 1];
    }
    out[n * 2 + 0] = acc0;
    out[n * 2 + 1] = acc1;
  }
}

// ---------------- driver ----------------
struct WS {
  int *ptr, *col, *cnt, *degall;
  float *scal, *a_arr, *c_arr, *bnsum, *bnsq, *bnmean, *bnrs, *bcomb, *biasPre;
  unsigned short *wcombT, *wpreT;
  unsigned short *xb, *h1, *h2, *h3, *ts, *aggx;
  size_t agg_elems;
};

template <int F, typename To>
static void run_layer(const unsigned short* xin, To* o_ptr, float* bnout, unsigned short* hout,
                      const float* Wpre, const float* bpre, const float* Wpost, const float* bpost,
                      const float* Wlin, const float* blin, const float* gamma, const float* beta,
                      int FO, const WS& ws, hipStream_t stream) {
  const int N = N_NODES;
  const int K13 = 13 * F;
  // weight prep (wcombT written transposed-bf16 directly)
  {
    dim3 g((FO + 127) / 128, (K13 + 127) / 128);
    k_wcombT<<<g, 256, 0, stream>>>(Wpost, Wlin, ws.wcombT, K13, FO, FO);
    k_bcomb<<<1, 256, 0, stream>>>(bpost, Wlin, blin, ws.bcomb, FO);
    k_tcast_pre<<<(2 * F * F + 255) / 256, 256, 0, stream>>>(Wpre, ws.wpreT, F);
    k_biaspre<<<1, 512, 0, stream>>>(bpre, ws.biasPre, F);
  }
  // fused pre-GEMM: ts = xin @ [W1 | W2] + [bpre | 0]
  {
    dim3 g(2 * F / 128, (N + 127) / 128);
    k_mm<unsigned short><<<g, 256, 0, stream>>>(xin, F, ws.wpreT, ws.biasPre, ws.ts, 0, N, 2 * F);
  }
  // chunked: edge aggregation (materializes 13F A) -> m97-style post GEMM
  int NB = (int)(ws.agg_elems / (size_t)K13);
  NB &= ~127;
  if (NB > N) NB = N;
  if (NB < 128) NB = 128;
  for (int c0 = 0; c0 < N; c0 += NB) {
    int nc = (N - c0 < NB) ? (N - c0) : NB;
    k_edge_agg<F><<<(nc + 3) / 4, 256, 0, stream>>>(ws.ts, xin, ws.ptr, ws.col,
                                                    ws.a_arr, ws.c_arr, ws.aggx, c0, nc);
    if (FO == 64) {
      dim3 g(1, (nc + 127) / 128);
      k_tile<64, To><<<g, 256, 0, stream>>>(ws.aggx, K13, K13, ws.wcombT, ws.bcomb, o_ptr, c0, nc, FO);
    } else {
      dim3 g(FO / 128, (nc + 127) / 128);
      k_mm<To><<<g, 256, 0, stream>>>(ws.aggx, K13, ws.wcombT, ws.bcomb, o_ptr, c0, nc, FO);
    }
  }
  // BN + ELU
  hipMemsetAsync(ws.bnsum, 0, 256 * sizeof(float), stream);
  hipMemsetAsync(ws.bnsq, 0, 256 * sizeof(float), stream);
  constexpr bool is_bf = (sizeof(To) == 2);
  if constexpr (is_bf) {
    int gs = imin((N * FO) / 2048 + 1, 1024);
    if (FO == 128)
      k_bn_stats_bf<128><<<gs, 256, 0, stream>>>((const unsigned short*)o_ptr, ws.bnsum, ws.bnsq);
    else
      k_bn_stats_bf<256><<<gs, 256, 0, stream>>>((const unsigned short*)o_ptr, ws.bnsum, ws.bnsq);
  } else {
    int gs = imin((N * FO) / 1024 + 1, 1024);
    k_bn_stats_f32<64><<<gs, 256, 0, stream>>>((const float*)o_ptr, ws.bnsum, ws.bnsq);
  }
  k_bn_fin<<<1, 256, 0, stream>>>(ws.bnsum, ws.bnsq, ws.bnmean, ws.bnrs, FO);
  int total = N_NODES * FO;
  if constexpr (is_bf) {
    int ge = (total / 8 + 255) / 256;
    if (FO == 128)
      k_bn_elu_bf<128><<<ge, 256, 0, stream>>>((const unsigned short*)o_ptr, ws.bnmean, ws.bnrs, gamma, beta, hout);
    else
      k_bn_elu_bf<256><<<ge, 256, 0, stream>>>((const unsigned short*)o_ptr, ws.bnmean, ws.bnrs, gamma, beta, hout);
  } else {
    int ge = (total / 4 + 255) / 256;
    k_bn_elu_f32<64><<<ge, 256, 0, stream>>>((const float*)o_ptr, ws.bnmean, ws.bnrs, gamma, beta, hout, bnout);
  }
}

extern "C" void kernel_launch(void* const* d_in, const int* in_sizes, int n_in,
                              void* d_out, int out_size, void* d_ws, size_t ws_size,
                              hipStream_t stream) {
  const int N = N_NODES, E = N_EDGES;
  const float* x = (const float*)d_in[0];
  const int* ei = (const int*)d_in[1];
  const int* src = ei;
  const int* dst = ei + E;
  const float *Wpre[4], *bpre[4], *Wpost[4], *bpost[4], *Wlin[4], *blin[4], *gamma[4], *beta[4];
  for (int i = 0; i < 4; i++) {
    const int b = 2 + i * 8;
    Wpre[i] = (const float*)d_in[b + 0];
    bpre[i] = (const float*)d_in[b + 1];
    Wpost[i] = (const float*)d_in[b + 2];
    bpost[i] = (const float*)d_in[b + 3];
    Wlin[i] = (const float*)d_in[b + 4];
    blin[i] = (const float*)d_in[b + 5];
    gamma[i] = (const float*)d_in[b + 6];
    beta[i] = (const float*)d_in[b + 7];
  }
  const float* Wc = (const float*)d_in[34];
  const float* bcv = (const float*)d_in[35];

  // ----- workspace layout (~119 MB fixed + adaptive aggx) -----
  char* w = (char*)d_ws;
  size_t off = 0;
  auto alloc = [&](size_t bytes) -> void* {
    void* p = (void*)(w + off);
    off = (off + bytes + 255) & ~(size_t)255;
    return p;
  };
  WS ws;
  ws.ptr = (int*)alloc((N + 1) * sizeof(int));
  ws.col = (int*)alloc((size_t)E * sizeof(int));
  ws.cnt = (int*)alloc((size_t)N * sizeof(int));
  ws.degall = (int*)alloc((size_t)N * sizeof(int));
  ws.scal = (float*)alloc(16 * sizeof(float));
  ws.a_arr = (float*)alloc((size_t)N * sizeof(float));
  ws.c_arr = (float*)alloc((size_t)N * sizeof(float));
  ws.bnsum = (float*)alloc(256 * sizeof(float));
  ws.bnsq = (float*)alloc(256 * sizeof(float));
  ws.bnmean = (float*)alloc(256 * sizeof(float));
  ws.bnrs = (float*)alloc(256 * sizeof(float));
  ws.bcomb = (float*)alloc(256 * sizeof(float));
  ws.biasPre = (float*)alloc(512 * sizeof(float));
  ws.wcombT = (unsigned short*)alloc((size_t)256 * 3328 * sizeof(unsigned short));
  ws.wpreT = (unsigned short*)alloc((size_t)512 * 256 * sizeof(unsigned short));
  ws.xb = (unsigned short*)alloc((size_t)N * 128 * sizeof(unsigned short));
  ws.h1 = (unsigned short*)alloc((size_t)N * 128 * sizeof(unsigned short));
  ws.h2 = (unsigned short*)alloc((size_t)N * 256 * sizeof(unsigned short));
  ws.h3 = (unsigned short*)alloc((size_t)N * 128 * sizeof(unsigned short));
  ws.ts = (unsigned short*)alloc((size_t)N * 512 * sizeof(unsigned short));
  size_t rem = (ws_size > off) ? (ws_size - off) : 0;
  ws.agg_elems = rem / sizeof(unsigned short);
  ws.aggx = (unsigned short*)(w + off);
  unsigned short* h4 = ws.xb;  // alias: x dead after layer 1; h4 is [N,64]

  float* outp = (float*)d_out;
  float* logits = outp;              // [N,2]
  float* p4 = outp + (size_t)N * 2;  // [N,64]
  float* b4 = p4 + (size_t)N * 64;   // [N,64]
  unsigned short* o_scratch = (unsigned short*)p4;  // pre-BN scratch, overwritten by layer 4

  // ----- degree / CSR / scalars -----
  hipMemsetAsync(ws.cnt, 0, N * sizeof(int), stream);
  hipMemsetAsync(ws.degall, 0, N * sizeof(int), stream);
  hipMemsetAsync(ws.scal, 0, 16 * sizeof(float), stream);
  k_count<<<(E + 255) / 256, 256, 0, stream>>>(src, dst, ws.cnt, ws.degall);
  k_scan<<<1, 1024, 0, stream>>>(ws.cnt, ws.ptr);
  hipMemsetAsync(ws.cnt, 0, N * sizeof(int), stream);
  k_fill<<<(E + 255) / 256, 256, 0, stream>>>(src, dst, ws.ptr, ws.cnt, ws.col);
  k_avglog<<<64, 256, 0, stream>>>(ws.degall, ws.scal);
  k_avg_fin<<<1, 1, 0, stream>>>(ws.scal);
  k_scalars<<<(N + 255) / 256, 256, 0, stream>>>(ws.ptr, ws.scal, ws.a_arr, ws.c_arr);
  k_cast<<<(N * 128 + 255) / 256, 256, 0, stream>>>(x, ws.xb, N * 128);

  run_layer<128, unsigned short>(ws.xb, o_scratch, nullptr, ws.h1,
                                 Wpre[0], bpre[0], Wpost[0], bpost[0], Wlin[0], blin[0], gamma[0], beta[0],
                                 128, ws, stream);
  run_layer<128, unsigned short>(ws.h1, o_scratch, nullptr, ws.h2,
                                 Wpre[1], bpre[1], Wpost[1], bpost[1], Wlin[1], blin[1], gamma[1], beta[1],
                                 256, ws, stream);
  run_layer<256, unsigned short>(ws.h2, o_scratch, nullptr, ws.h3,
                                 Wpre[2], bpre[2], Wpost[2], bpost[2], Wlin[2], blin[2], gamma[2], beta[2],
                                 128, ws, stream);
  k_add<<<((N * 128) + 255) / 256, 256, 0, stream>>>(ws.h1, ws.h3, ws.h3);  // x4 = h1 + h3 in place
  run_layer<128, float>(ws.h3, p4, b4, h4,
                        Wpre[3], bpre[3], Wpost[3], bpost[3], Wlin[3], blin[3], gamma[3], beta[3],
                        64, ws, stream);
  k_logits<<<(N + 255) / 256, 256, 0, stream>>>(h4, Wc, bcv, logits);
  (void)in_sizes; (void)n_in; (void)out_size; (void)ws_size;
}

// Round 11
// 1462.316 us; speedup vs baseline: 1.5446x; 1.0602x over previous
//
#include <hip/hip_runtime.h>
#include <math.h>

#define N_NODES 50000
#define N_EDGES 500000
#define SCAN_NB ((N_NODES + 1023) / 1024)

using bf16x8 = __attribute__((ext_vector_type(8))) short;
using f32x4  = __attribute__((ext_vector_type(4))) float;

// ---------- bf16 helpers ----------
__device__ inline float b2f(unsigned short u) {
  union { unsigned int i; float f; } v; v.i = ((unsigned int)u) << 16; return v.f;
}
__device__ inline unsigned short f2b(float f) {
  union { float f; unsigned int i; } v; v.f = f;
  unsigned int x = v.i;
  return (unsigned short)((x + 0x7fffu + ((x >> 16) & 1u)) >> 16);
}
__device__ inline unsigned int pk2(float a, float b) {
  return (unsigned int)f2b(a) | ((unsigned int)f2b(b) << 16);
}
__device__ inline void stv(unsigned short* p, float v) { *p = f2b(v); }
__device__ inline void stv(float* p, float v) { *p = v; }
__device__ inline float ldf(unsigned short u) { return b2f(u); }
__device__ inline float ldf(float f) { return f; }
__host__ __device__ inline int imin(int a, int b) { return a < b ? a : b; }

// direct global->LDS DMA, 16B per lane; lds base is wave-uniform
__device__ inline void gload16(const unsigned short* g, unsigned short* l) {
  __builtin_amdgcn_global_load_lds((const __attribute__((address_space(1))) unsigned int*)g,
                                   (__attribute__((address_space(3))) unsigned int*)l, 16, 0, 0);
}

// ---------------- degree / CSR ----------------
__global__ void k_count(const int* __restrict__ src, const int* __restrict__ dst,
                        int* __restrict__ cnt, int* __restrict__ degall) {
  int e = blockIdx.x * blockDim.x + threadIdx.x;
  if (e < N_EDGES) {
    atomicAdd(&cnt[dst[e]], 1);
    atomicAdd(&degall[src[e]], 1);
    atomicAdd(&degall[dst[e]], 1);
  }
}

// 3-phase parallel exclusive scan over cnt[N_NODES] -> ptr (+ ptr[N]=total)
__global__ __launch_bounds__(1024) void k_scan1(const int* __restrict__ cnt, int* __restrict__ ptr,
                                                int* __restrict__ sums) {
  __shared__ int buf[1024];
  int i = blockIdx.x * 1024 + threadIdx.x;
  int v = (i < N_NODES) ? cnt[i] : 0;
  buf[threadIdx.x] = v;
  __syncthreads();
  for (int off = 1; off < 1024; off <<= 1) {
    int tv = (threadIdx.x >= off) ? buf[threadIdx.x - off] : 0;
    __syncthreads();
    buf[threadIdx.x] += tv;
    __syncthreads();
  }
  if (i < N_NODES) ptr[i] = buf[threadIdx.x] - v;  // block-local exclusive
  if (threadIdx.x == 1023) sums[blockIdx.x] = buf[1023];
}

__global__ void k_scan2(int* __restrict__ sums) {
  if (threadIdx.x == 0) {
    int acc = 0;
    for (int b = 0; b < SCAN_NB; b++) {
      int t = sums[b];
      sums[b] = acc;
      acc += t;
    }
    sums[SCAN_NB] = acc;
  }
}

__global__ __launch_bounds__(1024) void k_scan3(int* __restrict__ ptr, const int* __restrict__ sums) {
  int i = blockIdx.x * 1024 + threadIdx.x;
  if (i < N_NODES) ptr[i] += sums[blockIdx.x];
  if (blockIdx.x == 0 && threadIdx.x == 0) ptr[N_NODES] = sums[SCAN_NB];
}

__global__ void k_fill(const int* __restrict__ src, const int* __restrict__ dst,
                       const int* __restrict__ ptr, int* __restrict__ cnt, int* __restrict__ col) {
  int e = blockIdx.x * blockDim.x + threadIdx.x;
  if (e < N_EDGES) {
    int d = dst[e];
    int pos = atomicAdd(&cnt[d], 1);
    col[ptr[d] + pos] = src[e];
  }
}

__global__ void k_avglog(const int* __restrict__ degall, float* __restrict__ scal) {
  __shared__ float L[256];
  float s = 0.f;
  for (int n = blockIdx.x * blockDim.x + threadIdx.x; n < N_NODES; n += gridDim.x * blockDim.x)
    s += logf((float)degall[n] + 1.0f);
  L[threadIdx.x] = s;
  __syncthreads();
  for (int o = 128; o > 0; o >>= 1) {
    if (threadIdx.x < o) L[threadIdx.x] += L[threadIdx.x + o];
    __syncthreads();
  }
  if (threadIdx.x == 0) atomicAdd(&scal[0], L[0]);
}

__global__ void k_avg_fin(float* scal) {
  float avg = scal[0] / (float)N_NODES;
  scal[1] = avg;
  scal[2] = 1.0f / avg;
}

__global__ void k_scalars(const int* __restrict__ ptr, const float* __restrict__ scal,
                          float* __restrict__ a_arr, float* __restrict__ c_arr) {
  int n = blockIdx.x * blockDim.x + threadIdx.x;
  if (n < N_NODES) {
    int d = ptr[n + 1] - ptr[n];
    float degc = fmaxf((float)d, 1.f);
    float logd = logf(degc + 1.f);
    a_arr[n] = logd * scal[2];
    c_arr[n] = scal[1] / logd;
  }
}

__global__ void k_cast(const float* __restrict__ x, unsigned short* __restrict__ xb, int total) {
  int i = blockIdx.x * blockDim.x + threadIdx.x;
  if (i < total) xb[i] = f2b(x[i]);
}

// pre-weights: BT_pre[j][k] = j<F ? Wpre[k][j] : Wpre[F+k][j-F]   (j<2F, k<F)
__global__ void k_tcast_pre(const float* __restrict__ Wpre, unsigned short* __restrict__ out, int F) {
  int i = blockIdx.x * blockDim.x + threadIdx.x;
  if (i < 2 * F * F) {
    int j = i / F, k = i % F;
    float v = (j < F) ? Wpre[(size_t)k * F + j] : Wpre[(size_t)(F + k) * F + (j - F)];
    out[i] = f2b(v);
  }
}

__global__ void k_biaspre(const float* __restrict__ bpre, float* __restrict__ biasPre, int F) {
  int j = threadIdx.x;
  if (j < 2 * F) biasPre[j] = (j < F) ? bpre[j] : 0.f;
}

// ---------------- weight GEMM: CT[c][r] = bf16( (Wpost@Wlin)[r][c] ) ----------------
__global__ __launch_bounds__(256) void k_wcombT(const float* __restrict__ A, const float* __restrict__ B,
                                                unsigned short* __restrict__ CT, int M, int Ncol, int K) {
  __shared__ float As[16][136];
  __shared__ float Bs[16][128];
  int tid = threadIdx.x;
  int row0 = blockIdx.y * 128, col0 = blockIdx.x * 128;
  int am = tid >> 1, ah = (tid & 1) * 8;
  int ty = tid >> 4, tx = tid & 15;
  float acc[8][8];
#pragma unroll
  for (int i = 0; i < 8; i++)
#pragma unroll
    for (int j = 0; j < 8; j++) acc[i][j] = 0.f;
  int arow = row0 + am;
  bool av = arow < M;
  const float* Ar = A + (size_t)arow * K;
  for (int k0 = 0; k0 < K; k0 += 16) {
    float4 a0 = make_float4(0, 0, 0, 0), a1 = make_float4(0, 0, 0, 0);
    if (av) {
      a0 = *(const float4*)(Ar + k0 + ah);
      a1 = *(const float4*)(Ar + k0 + ah + 4);
    }
    As[ah + 0][am] = a0.x; As[ah + 1][am] = a0.y; As[ah + 2][am] = a0.z; As[ah + 3][am] = a0.w;
    As[ah + 4][am] = a1.x; As[ah + 5][am] = a1.y; As[ah + 6][am] = a1.z; As[ah + 7][am] = a1.w;
#pragma unroll
    for (int i = 0; i < 2; i++) {
      int q = tid * 2 + i;
      int kk = q >> 5, j4 = (q & 31) * 4;
      int bc = col0 + j4;
      float4 b = make_float4(0, 0, 0, 0);
      if (bc < Ncol && (k0 + kk) < K) b = *(const float4*)(B + (size_t)(k0 + kk) * Ncol + bc);
      *(float4*)(&Bs[kk][j4]) = b;
    }
    __syncthreads();
#pragma unroll
    for (int kk = 0; kk < 16; kk++) {
      float av8[8], bv8[8];
#pragma unroll
      for (int i = 0; i < 8; i++) av8[i] = As[kk][ty * 8 + i];
#pragma unroll
      for (int j = 0; j < 8; j++) bv8[j] = Bs[kk][tx * 8 + j];
#pragma unroll
      for (int i = 0; i < 8; i++)
#pragma unroll
        for (int j = 0; j < 8; j++) acc[i][j] = fmaf(av8[i], bv8[j], acc[i][j]);
    }
    __syncthreads();
  }
#pragma unroll
  for (int i = 0; i < 8; i++) {
    int r = row0 + ty * 8 + i;
    if (r < M) {
#pragma unroll
      for (int j = 0; j < 8; j++) {
        int c = col0 + tx * 8 + j;
        if (c < Ncol) CT[(size_t)c * M + r] = f2b(acc[i][j]);
      }
    }
  }
}

// ---------------- m97-style MFMA GEMM: 128x128 tile, 64x64/wave, gload_lds dbuf ----------------
template <typename To>
__global__ __launch_bounds__(256) void k_mm(
    const unsigned short* __restrict__ A, int K,
    const unsigned short* __restrict__ BT,
    const float* __restrict__ bias,
    To* __restrict__ C, int n0, int M, int Ncol) {
  __shared__ unsigned short lds[2][2][4096];  // [buf][A/B][128 rows x 32 cols]
  const int tid = threadIdx.x;
  const int lane = tid & 63;
  const int wid = tid >> 6;
  const int wr = wid >> 1, wc = wid & 1;
  const int row0 = blockIdx.y * 128;
  const int col0 = blockIdx.x * 128;
  const int l15 = lane & 15, lq = lane >> 4;
  const int srow = wid * 32 + (lane >> 2);
  const int scol = (lane & 3) * 8;
  const unsigned short* gA0 = A + (size_t)imin(row0 + srow, N_NODES - 1) * K + scol;
  const unsigned short* gA1 = A + (size_t)imin(row0 + srow + 16, N_NODES - 1) * K + scol;
  const unsigned short* gB0 = BT + (size_t)(col0 + srow) * K + scol;
  const unsigned short* gB1 = BT + (size_t)(col0 + srow + 16) * K + scol;

  f32x4 acc[4][4];
#pragma unroll
  for (int m = 0; m < 4; m++)
#pragma unroll
    for (int n = 0; n < 4; n++) acc[m][n] = (f32x4){0.f, 0.f, 0.f, 0.f};

  auto stage = [&](int buf, int k0) {
    gload16(gA0 + k0, &lds[buf][0][wid * 1024]);
    gload16(gA1 + k0, &lds[buf][0][wid * 1024 + 512]);
    gload16(gB0 + k0, &lds[buf][1][wid * 1024]);
    gload16(gB1 + k0, &lds[buf][1][wid * 1024 + 512]);
  };

  const int nk = K / 32;
  stage(0, 0);
  __syncthreads();
  for (int t = 0; t < nk; ++t) {
    const int cur = t & 1;
    if (t + 1 < nk) stage(cur ^ 1, (t + 1) * 32);
    bf16x8 a[4], b[4];
#pragma unroll
    for (int m = 0; m < 4; m++)
      a[m] = *(const bf16x8*)&lds[cur][0][(wr * 64 + m * 16 + l15) * 32 + lq * 8];
#pragma unroll
    for (int n = 0; n < 4; n++)
      b[n] = *(const bf16x8*)&lds[cur][1][(wc * 64 + n * 16 + l15) * 32 + lq * 8];
#pragma unroll
    for (int m = 0; m < 4; m++)
#pragma unroll
      for (int n = 0; n < 4; n++)
        acc[m][n] = __builtin_amdgcn_mfma_f32_16x16x32_bf16(a[m], b[n], acc[m][n], 0, 0, 0);
    __syncthreads();
  }
#pragma unroll
  for (int n = 0; n < 4; n++) {
    int col = col0 + wc * 64 + n * 16 + l15;
    float bv = bias ? bias[col] : 0.f;
#pragma unroll
    for (int m = 0; m < 4; m++) {
#pragma unroll
      for (int j = 0; j < 4; j++) {
        int r = row0 + wr * 64 + m * 16 + lq * 4 + j;
        if (r < M) stv(&C[(size_t)(n0 + r) * Ncol + col], acc[m][n][j] + bv);
      }
    }
  }
}

// ---------------- reg-staged MFMA GEMM for Ncol=64 (layer-4 post) ----------------
template <int NTILE, typename To>
__global__ __launch_bounds__(256) void k_tile(
    const unsigned short* __restrict__ A, int lda, int K,
    const unsigned short* __restrict__ BT,
    const float* __restrict__ bias,
    To* __restrict__ C, int n0, int M, int Ncol) {
  constexpr int WN = NTILE / 64;
  constexpr int WM = 4 / WN;
  constexpr int MTILE = WM * 32;
  constexpr int PK = 40;
  constexpr int CA = MTILE / 64;
  constexpr int CB = NTILE / 64;
  __shared__ unsigned short As[MTILE][PK];
  __shared__ unsigned short Bs[NTILE][PK];
  const int tid = threadIdx.x;
  const int lane = tid & 63;
  const int wid = tid >> 6;
  const int wr = wid / WN;
  const int wc = wid % WN;
  const int row0 = blockIdx.y * MTILE;
  const int col0 = blockIdx.x * NTILE;
  const int l15 = lane & 15, lq = lane >> 4;
  uint4 apf[CA], bpf[CB];
  f32x4 acc[2][4];
#pragma unroll
  for (int m = 0; m < 2; m++)
#pragma unroll
    for (int n = 0; n < 4; n++) acc[m][n] = (f32x4){0.f, 0.f, 0.f, 0.f};

  auto load = [&](int k0) {
#pragma unroll
    for (int i = 0; i < CA; i++) {
      int idx = tid + 256 * i;
      int r = idx >> 2, c8 = (idx & 3) * 8;
      int gr = row0 + r;
      uint4 v = make_uint4(0u, 0u, 0u, 0u);
      if (gr < M) v = *(const uint4*)(A + (size_t)gr * lda + k0 + c8);
      apf[i] = v;
    }
#pragma unroll
    for (int i = 0; i < CB; i++) {
      int idx = tid + 256 * i;
      int r = idx >> 2, c8 = (idx & 3) * 8;
      bpf[i] = *(const uint4*)(BT + (size_t)(col0 + r) * K + k0 + c8);
    }
  };

  load(0);
  for (int k0 = 0; k0 < K; k0 += 32) {
#pragma unroll
    for (int i = 0; i < CA; i++) {
      int idx = tid + 256 * i;
      *(uint4*)&As[idx >> 2][(idx & 3) * 8] = apf[i];
    }
#pragma unroll
    for (int i = 0; i < CB; i++) {
      int idx = tid + 256 * i;
      *(uint4*)&Bs[idx >> 2][(idx & 3) * 8] = bpf[i];
    }
    __syncthreads();
    if (k0 + 32 < K) load(k0 + 32);
    bf16x8 af0 = *(const bf16x8*)&As[wr * 32 + l15][lq * 8];
    bf16x8 af1 = *(const bf16x8*)&As[wr * 32 + 16 + l15][lq * 8];
#pragma unroll
    for (int n = 0; n < 4; n++) {
      bf16x8 bf = *(const bf16x8*)&Bs[wc * 64 + n * 16 + l15][lq * 8];
      acc[0][n] = __builtin_amdgcn_mfma_f32_16x16x32_bf16(af0, bf, acc[0][n], 0, 0, 0);
      acc[1][n] = __builtin_amdgcn_mfma_f32_16x16x32_bf16(af1, bf, acc[1][n], 0, 0, 0);
    }
    __syncthreads();
  }
#pragma unroll
  for (int n = 0; n < 4; n++) {
    int col = col0 + wc * 64 + n * 16 + l15;
    float bv = bias ? bias[col] : 0.f;
#pragma unroll
    for (int m = 0; m < 2; m++) {
#pragma unroll
      for (int j = 0; j < 4; j++) {
        int r = row0 + wr * 32 + m * 16 + lq * 4 + j;
        if (r < M) stv(&C[(size_t)(n0 + r) * Ncol + col], acc[m][n][j] + bv);
      }
    }
  }
}

// ---------------- edge aggregation (vectorized): writes 13F rows [x | agg | an*agg | cn*agg] ----------------
template <int F>
__global__ __launch_bounds__(256) void k_edge_agg(
    const unsigned short* __restrict__ ts, const unsigned short* __restrict__ xin,
    const int* __restrict__ ptr, const int* __restrict__ col,
    const float* __restrict__ a_arr, const float* __restrict__ c_arr,
    unsigned short* __restrict__ aggx, int n0, int nchunk) {
  constexpr int VU = F / 128;
  int idx = (blockIdx.x * blockDim.x + threadIdx.x) >> 6;
  int lane = threadIdx.x & 63;
  if (idx >= nchunk) return;
  int n = n0 + idx;
  if (n >= N_NODES) return;
  float S1[2 * VU], S2[2 * VU], mn[2 * VU], mx[2 * VU];
#pragma unroll
  for (int u = 0; u < 2 * VU; u++) {
    S1[u] = 0.f; S2[u] = 0.f; mn[u] = 3.4e38f; mx[u] = -3.4e38f;
  }
  int e0 = ptr[n], e1 = ptr[n + 1];
  for (int e = e0; e < e1; ++e) {
    int sidx = col[e];
    const unsigned int* sr = (const unsigned int*)(ts + (size_t)sidx * 2 * F + F);
#pragma unroll
    for (int u = 0; u < VU; u++) {
      unsigned int v = sr[lane + 64 * u];
      float f0 = b2f((unsigned short)(v & 0xffff));
      float f1 = b2f((unsigned short)(v >> 16));
      S1[2 * u] += f0; S2[2 * u] += f0 * f0;
      mn[2 * u] = fminf(mn[2 * u], f0); mx[2 * u] = fmaxf(mx[2 * u], f0);
      S1[2 * u + 1] += f1; S2[2 * u + 1] += f1 * f1;
      mn[2 * u + 1] = fminf(mn[2 * u + 1], f1); mx[2 * u + 1] = fmaxf(mx[2 * u + 1], f1);
    }
  }
  int d = e1 - e0;
  float an = a_arr[n], cn = c_arr[n];
  const unsigned int* tr = (const unsigned int*)(ts + (size_t)n * 2 * F);
  const unsigned int* xr = (const unsigned int*)(xin + (size_t)n * F);
  unsigned int* ob = (unsigned int*)(aggx + (size_t)idx * 13 * F);
  constexpr int UB = 64 * VU;
#pragma unroll
  for (int u = 0; u < VU; u++) {
    int ui = lane + 64 * u;
    ob[ui] = xr[ui];
    float mean0, mean1, lo0, lo1, hi0, hi1, sd0, sd1;
    if (d > 0) {
      float inv = 1.f / (float)d;
      unsigned int tv = tr[ui];
      float t0 = b2f((unsigned short)(tv & 0xffff));
      float t1 = b2f((unsigned short)(tv >> 16));
      float ms0 = S1[2 * u] * inv, ms1 = S1[2 * u + 1] * inv;
      sd0 = sqrtf(fmaxf(S2[2 * u] * inv - ms0 * ms0, 0.f) + 1e-5f);
      sd1 = sqrtf(fmaxf(S2[2 * u + 1] * inv - ms1 * ms1, 0.f) + 1e-5f);
      mean0 = t0 + ms0; mean1 = t1 + ms1;
      lo0 = t0 + mn[2 * u]; lo1 = t1 + mn[2 * u + 1];
      hi0 = t0 + mx[2 * u]; hi1 = t1 + mx[2 * u + 1];
    } else {
      mean0 = mean1 = lo0 = lo1 = hi0 = hi1 = 0.f;
      sd0 = sd1 = sqrtf(1e-5f);
    }
    unsigned int* o1 = ob + UB + ui;
    o1[0] = pk2(mean0, mean1);
    o1[UB] = pk2(lo0, lo1);
    o1[2 * UB] = pk2(hi0, hi1);
    o1[3 * UB] = pk2(sd0, sd1);
    o1[4 * UB] = pk2(an * mean0, an * mean1);
    o1[5 * UB] = pk2(an * lo0, an * lo1);
    o1[6 * UB] = pk2(an * hi0, an * hi1);
    o1[7 * UB] = pk2(an * sd0, an * sd1);
    o1[8 * UB] = pk2(cn * mean0, cn * mean1);
    o1[9 * UB] = pk2(cn * lo0, cn * lo1);
    o1[10 * UB] = pk2(cn * hi0, cn * hi1);
    o1[11 * UB] = pk2(cn * sd0, cn * sd1);
  }
}

// ---------------- BN stats: vectorized grid-stride + LDS reduce + 1 atomic/col/block ----------------
template <int FO>
__global__ __launch_bounds__(256) void k_bn_stats_bf(const unsigned short* __restrict__ o,
                                                     float* __restrict__ gsum, float* __restrict__ gsq) {
  constexpr int TOTAL = N_NODES * FO;
  float s1[8], s2[8];
#pragma unroll
  for (int j = 0; j < 8; j++) { s1[j] = 0.f; s2[j] = 0.f; }
  const int stride = gridDim.x * 2048;
  for (int base = blockIdx.x * 2048 + threadIdx.x * 8; base < TOTAL; base += stride) {
    uint4 v = *(const uint4*)(o + base);
    const unsigned int* u = (const unsigned int*)&v;
#pragma unroll
    for (int w = 0; w < 4; w++) {
      float f0 = b2f((unsigned short)(u[w] & 0xffff));
      float f1 = b2f((unsigned short)(u[w] >> 16));
      s1[2 * w] += f0; s2[2 * w] += f0 * f0;
      s1[2 * w + 1] += f1; s2[2 * w + 1] += f1 * f1;
    }
  }
  __shared__ float L1[2048], L2[2048];
#pragma unroll
  for (int j = 0; j < 8; j++) {
    L1[threadIdx.x * 8 + j] = s1[j];
    L2[threadIdx.x * 8 + j] = s2[j];
  }
  __syncthreads();
  int c = threadIdx.x;
  if (c < FO) {
    float a1 = 0.f, a2 = 0.f;
    for (int i = c; i < 2048; i += FO) { a1 += L1[i]; a2 += L2[i]; }
    atomicAdd(&gsum[c], a1);
    atomicAdd(&gsq[c], a2);
  }
}

template <int FO>
__global__ __launch_bounds__(256) void k_bn_stats_f32(const float* __restrict__ o,
                                                      float* __restrict__ gsum, float* __restrict__ gsq) {
  constexpr int TOTAL = N_NODES * FO;
  float s1[4], s2[4];
#pragma unroll
  for (int j = 0; j < 4; j++) { s1[j] = 0.f; s2[j] = 0.f; }
  const int stride = gridDim.x * 1024;
  for (int base = blockIdx.x * 1024 + threadIdx.x * 4; base < TOTAL; base += stride) {
    float4 v = *(const float4*)(o + base);
    s1[0] += v.x; s2[0] += v.x * v.x;
    s1[1] += v.y; s2[1] += v.y * v.y;
    s1[2] += v.z; s2[2] += v.z * v.z;
    s1[3] += v.w; s2[3] += v.w * v.w;
  }
  __shared__ float L1[1024], L2[1024];
#pragma unroll
  for (int j = 0; j < 4; j++) {
    L1[threadIdx.x * 4 + j] = s1[j];
    L2[threadIdx.x * 4 + j] = s2[j];
  }
  __syncthreads();
  int c = threadIdx.x;
  if (c < FO) {
    float a1 = 0.f, a2 = 0.f;
    for (int i = c; i < 1024; i += FO) { a1 += L1[i]; a2 += L2[i]; }
    atomicAdd(&gsum[c], a1);
    atomicAdd(&gsq[c], a2);
  }
}

__global__ void k_bn_fin(const float* bnsum, const float* bnsq, float* bnmean, float* bnrs, int FO) {
  int c = threadIdx.x;
  if (c < FO) {
    float mean = bnsum[c] / (float)N_NODES;
    float var = bnsq[c] / (float)N_NODES - mean * mean;
    bnmean[c] = mean;
    bnrs[c] = rsqrtf(var + 1e-5f);
  }
}

// ---------------- BN+ELU (vectorized) ----------------
template <int FO>
__global__ __launch_bounds__(256) void k_bn_elu_bf(const unsigned short* __restrict__ o,
                                                   const float* __restrict__ mean, const float* __restrict__ rs,
                                                   const float* __restrict__ gamma, const float* __restrict__ beta,
                                                   unsigned short* __restrict__ h) {
  constexpr int TOTAL = N_NODES * FO;
  int base = (blockIdx.x * blockDim.x + threadIdx.x) * 8;
  if (base >= TOTAL) return;
  int c0 = base % FO;
  uint4 v = *(const uint4*)(o + base);
  const unsigned int* u = (const unsigned int*)&v;
  unsigned int outw[4];
#pragma unroll
  for (int w = 0; w < 4; w++) {
    int c = c0 + 2 * w;
    float f0 = b2f((unsigned short)(u[w] & 0xffff));
    float f1 = b2f((unsigned short)(u[w] >> 16));
    float y0 = gamma[c] * (f0 - mean[c]) * rs[c] + beta[c];
    float y1 = gamma[c + 1] * (f1 - mean[c + 1]) * rs[c + 1] + beta[c + 1];
    y0 = y0 > 0.f ? y0 : expm1f(y0);
    y1 = y1 > 0.f ? y1 : expm1f(y1);
    outw[w] = pk2(y0, y1);
  }
  *(uint4*)(h + base) = *(uint4*)outw;
}

template <int FO>
__global__ __launch_bounds__(256) void k_bn_elu_f32(const float* __restrict__ o,
                                                    const float* __restrict__ mean, const float* __restrict__ rs,
                                                    const float* __restrict__ gamma, const float* __restrict__ beta,
                                                    unsigned short* __restrict__ h, float* __restrict__ bnout) {
  constexpr int TOTAL = N_NODES * FO;
  int base = (blockIdx.x * blockDim.x + threadIdx.x) * 4;
  if (base >= TOTAL) return;
  int c = base % FO;
  float4 v = *(const float4*)(o + base);
  float y0 = gamma[c] * (v.x - mean[c]) * rs[c] + beta[c];
  float y1 = gamma[c + 1] * (v.y - mean[c + 1]) * rs[c + 1] + beta[c + 1];
  float y2 = gamma[c + 2] * (v.z - mean[c + 2]) * rs[c + 2] + beta[c + 2];
  float y3 = gamma[c + 3] * (v.w - mean[c + 3]) * rs[c + 3] + beta[c + 3];
  if (bnout) *(float4*)(bnout + base) = make_float4(y0, y1, y2, y3);
  unsigned int o0 = pk2(y0 > 0.f ? y0 : expm1f(y0), y1 > 0.f ? y1 : expm1f(y1));
  unsigned int o1 = pk2(y2 > 0.f ? y2 : expm1f(y2), y3 > 0.f ? y3 : expm1f(y3));
  *(uint2*)(h + base) = make_uint2(o0, o1);
}

// ---------------- misc ----------------
__global__ void k_bcomb(const float* __restrict__ bpost, const float* __restrict__ Wlin,
                        const float* __restrict__ blin, float* __restrict__ bcomb, int FO) {
  int j = threadIdx.x;
  if (j < FO) {
    float acc = blin[j];
    for (int k = 0; k < FO; k++) acc += bpost[k] * Wlin[k * FO + j];
    bcomb[j] = acc;
  }
}

__global__ void k_add(const unsigned short* __restrict__ a, const unsigned short* __restrict__ b,
                      unsigned short* __restrict__ c) {
  int idx = blockIdx.x * blockDim.x + threadIdx.x;
  if (idx < N_NODES * 128) c[idx] = f2b(b2f(a[idx]) + b2f(b[idx]));
}

__global__ void k_logits(const unsigned short* __restrict__ h4, const float* __restrict__ Wc,
                         const float* __restrict__ bc, float* __restrict__ out) {
  int n = blockIdx.x * blockDim.x + threadIdx.x;
  if (n < N_NODES) {
    float acc0 = bc[0], acc1 = bc[1];
    const unsigned short* hr = h4 + (size_t)n * 64;
    for (int k = 0; k < 64; k++) {
      float v = b2f(hr[k]);
      acc0 += v * Wc[k * 2 + 0];
      acc1 += v * Wc[k * 2 + 1];
    }
    out[n * 2 + 0] = acc0;
    out[n * 2 + 1] = acc1;
  }
}

// ---------------- driver ----------------
struct WS {
  int *ptr, *col, *cnt, *degall, *scansums;
  float *scal, *a_arr, *c_arr, *bnsum, *bnsq, *bnmean, *bnrs, *bcomb, *biasPre;
  unsigned short *wcombT, *wpreT;
  unsigned short *xb, *h1, *h2, *h3, *ts, *aggx;
  size_t agg_elems;
};

template <int F, typename To>
static void run_layer(const unsigned short* xin, To* o_ptr, float* bnout, unsigned short* hout,
                      const float* Wpre, const float* bpre, const float* Wpost, const float* bpost,
                      const float* Wlin, const float* blin, const float* gamma, const float* beta,
                      int FO, const WS& ws, hipStream_t stream) {
  const int N = N_NODES;
  const int K13 = 13 * F;
  // weight prep (wcombT written transposed-bf16 directly)
  {
    dim3 g((FO + 127) / 128, (K13 + 127) / 128);
    k_wcombT<<<g, 256, 0, stream>>>(Wpost, Wlin, ws.wcombT, K13, FO, FO);
    k_bcomb<<<1, 256, 0, stream>>>(bpost, Wlin, blin, ws.bcomb, FO);
    k_tcast_pre<<<(2 * F * F + 255) / 256, 256, 0, stream>>>(Wpre, ws.wpreT, F);
    k_biaspre<<<1, 512, 0, stream>>>(bpre, ws.biasPre, F);
  }
  // fused pre-GEMM: ts = xin @ [W1 | W2] + [bpre | 0]
  {
    dim3 g(2 * F / 128, (N + 127) / 128);
    k_mm<unsigned short><<<g, 256, 0, stream>>>(xin, F, ws.wpreT, ws.biasPre, ws.ts, 0, N, 2 * F);
  }
  // chunked: edge aggregation (materializes 13F A) -> m97-style post GEMM
  int NB = (int)(ws.agg_elems / (size_t)K13);
  NB &= ~127;
  if (NB > N) NB = N;
  if (NB < 128) NB = 128;
  for (int c0 = 0; c0 < N; c0 += NB) {
    int nc = (N - c0 < NB) ? (N - c0) : NB;
    k_edge_agg<F><<<(nc + 3) / 4, 256, 0, stream>>>(ws.ts, xin, ws.ptr, ws.col,
                                                    ws.a_arr, ws.c_arr, ws.aggx, c0, nc);
    if (FO == 64) {
      dim3 g(1, (nc + 127) / 128);
      k_tile<64, To><<<g, 256, 0, stream>>>(ws.aggx, K13, K13, ws.wcombT, ws.bcomb, o_ptr, c0, nc, FO);
    } else {
      dim3 g(FO / 128, (nc + 127) / 128);
      k_mm<To><<<g, 256, 0, stream>>>(ws.aggx, K13, ws.wcombT, ws.bcomb, o_ptr, c0, nc, FO);
    }
  }
  // BN + ELU
  hipMemsetAsync(ws.bnsum, 0, 512 * sizeof(float), stream);  // bnsum+bnsq contiguous
  constexpr bool is_bf = (sizeof(To) == 2);
  if constexpr (is_bf) {
    int gs = imin((N * FO) / 2048 + 1, 1024);
    if (FO == 128)
      k_bn_stats_bf<128><<<gs, 256, 0, stream>>>((const unsigned short*)o_ptr, ws.bnsum, ws.bnsq);
    else
      k_bn_stats_bf<256><<<gs, 256, 0, stream>>>((const unsigned short*)o_ptr, ws.bnsum, ws.bnsq);
  } else {
    int gs = imin((N * FO) / 1024 + 1, 1024);
    k_bn_stats_f32<64><<<gs, 256, 0, stream>>>((const float*)o_ptr, ws.bnsum, ws.bnsq);
  }
  k_bn_fin<<<1, 256, 0, stream>>>(ws.bnsum, ws.bnsq, ws.bnmean, ws.bnrs, FO);
  int total = N_NODES * FO;
  if constexpr (is_bf) {
    int ge = (total / 8 + 255) / 256;
    if (FO == 128)
      k_bn_elu_bf<128><<<ge, 256, 0, stream>>>((const unsigned short*)o_ptr, ws.bnmean, ws.bnrs, gamma, beta, hout);
    else
      k_bn_elu_bf<256><<<ge, 256, 0, stream>>>((const unsigned short*)o_ptr, ws.bnmean, ws.bnrs, gamma, beta, hout);
  } else {
    int ge = (total / 4 + 255) / 256;
    k_bn_elu_f32<64><<<ge, 256, 0, stream>>>((const float*)o_ptr, ws.bnmean, ws.bnrs, gamma, beta, hout, bnout);
  }
}

extern "C" void kernel_launch(void* const* d_in, const int* in_sizes, int n_in,
                              void* d_out, int out_size, void* d_ws, size_t ws_size,
                              hipStream_t stream) {
  const int N = N_NODES, E = N_EDGES;
  const float* x = (const float*)d_in[0];
  const int* ei = (const int*)d_in[1];
  const int* src = ei;
  const int* dst = ei + E;
  const float *Wpre[4], *bpre[4], *Wpost[4], *bpost[4], *Wlin[4], *blin[4], *gamma[4], *beta[4];
  for (int i = 0; i < 4; i++) {
    const int b = 2 + i * 8;
    Wpre[i] = (const float*)d_in[b + 0];
    bpre[i] = (const float*)d_in[b + 1];
    Wpost[i] = (const float*)d_in[b + 2];
    bpost[i] = (const float*)d_in[b + 3];
    Wlin[i] = (const float*)d_in[b + 4];
    blin[i] = (const float*)d_in[b + 5];
    gamma[i] = (const float*)d_in[b + 6];
    beta[i] = (const float*)d_in[b + 7];
  }
  const float* Wc = (const float*)d_in[34];
  const float* bcv = (const float*)d_in[35];

  // ----- workspace layout (~119 MB fixed + adaptive aggx) -----
  char* w = (char*)d_ws;
  size_t off = 0;
  auto alloc = [&](size_t bytes) -> void* {
    void* p = (void*)(w + off);
    off = (off + bytes + 255) & ~(size_t)255;
    return p;
  };
  WS ws;
  ws.ptr = (int*)alloc((N + 1) * sizeof(int));
  ws.col = (int*)alloc((size_t)E * sizeof(int));
  ws.cnt = (int*)alloc((size_t)N * sizeof(int));
  ws.degall = (int*)alloc((size_t)N * sizeof(int));
  ws.scansums = (int*)alloc((SCAN_NB + 1) * sizeof(int));
  ws.scal = (float*)alloc(16 * sizeof(float));
  ws.a_arr = (float*)alloc((size_t)N * sizeof(float));
  ws.c_arr = (float*)alloc((size_t)N * sizeof(float));
  ws.bnsum = (float*)alloc(256 * sizeof(float));
  ws.bnsq = (float*)alloc(256 * sizeof(float));
  ws.bnmean = (float*)alloc(256 * sizeof(float));
  ws.bnrs = (float*)alloc(256 * sizeof(float));
  ws.bcomb = (float*)alloc(256 * sizeof(float));
  ws.biasPre = (float*)alloc(512 * sizeof(float));
  ws.wcombT = (unsigned short*)alloc((size_t)256 * 3328 * sizeof(unsigned short));
  ws.wpreT = (unsigned short*)alloc((size_t)512 * 256 * sizeof(unsigned short));
  ws.xb = (unsigned short*)alloc((size_t)N * 128 * sizeof(unsigned short));
  ws.h1 = (unsigned short*)alloc((size_t)N * 128 * sizeof(unsigned short));
  ws.h2 = (unsigned short*)alloc((size_t)N * 256 * sizeof(unsigned short));
  ws.h3 = (unsigned short*)alloc((size_t)N * 128 * sizeof(unsigned short));
  ws.ts = (unsigned short*)alloc((size_t)N * 512 * sizeof(unsigned short));
  size_t rem = (ws_size > off) ? (ws_size - off) : 0;
  ws.agg_elems = rem / sizeof(unsigned short);
  ws.aggx = (unsigned short*)(w + off);
  unsigned short* h4 = ws.xb;  // alias: x dead after layer 1; h4 is [N,64]

  float* outp = (float*)d_out;
  float* logits = outp;              // [N,2]
  float* p4 = outp + (size_t)N * 2;  // [N,64]
  float* b4 = p4 + (size_t)N * 64;   // [N,64]
  unsigned short* o_scratch = (unsigned short*)p4;  // pre-BN scratch, overwritten by layer 4

  // ----- degree / CSR / scalars -----
  hipMemsetAsync(ws.cnt, 0, N * sizeof(int), stream);
  hipMemsetAsync(ws.degall, 0, N * sizeof(int), stream);
  hipMemsetAsync(ws.scal, 0, 16 * sizeof(float), stream);
  k_count<<<(E + 255) / 256, 256, 0, stream>>>(src, dst, ws.cnt, ws.degall);
  k_scan1<<<SCAN_NB, 1024, 0, stream>>>(ws.cnt, ws.ptr, ws.scansums);
  k_scan2<<<1, 64, 0, stream>>>(ws.scansums);
  k_scan3<<<SCAN_NB, 1024, 0, stream>>>(ws.ptr, ws.scansums);
  hipMemsetAsync(ws.cnt, 0, N * sizeof(int), stream);
  k_fill<<<(E + 255) / 256, 256, 0, stream>>>(src, dst, ws.ptr, ws.cnt, ws.col);
  k_avglog<<<64, 256, 0, stream>>>(ws.degall, ws.scal);
  k_avg_fin<<<1, 1, 0, stream>>>(ws.scal);
  k_scalars<<<(N + 255) / 256, 256, 0, stream>>>(ws.ptr, ws.scal, ws.a_arr, ws.c_arr);
  k_cast<<<(N * 128 + 255) / 256, 256, 0, stream>>>(x, ws.xb, N * 128);

  run_layer<128, unsigned short>(ws.xb, o_scratch, nullptr, ws.h1,
                                 Wpre[0], bpre[0], Wpost[0], bpost[0], Wlin[0], blin[0], gamma[0], beta[0],
                                 128, ws, stream);
  run_layer<128, unsigned short>(ws.h1, o_scratch, nullptr, ws.h2,
                                 Wpre[1], bpre[1], Wpost[1], bpost[1], Wlin[1], blin[1], gamma[1], beta[1],
                                 256, ws, stream);
  run_layer<256, unsigned short>(ws.h2, o_scratch, nullptr, ws.h3,
                                 Wpre[2], bpre[2], Wpost[2], bpost[2], Wlin[2], blin[2], gamma[2], beta[2],
                                 128, ws, stream);
  k_add<<<((N * 128) + 255) / 256, 256, 0, stream>>>(ws.h1, ws.h3, ws.h3);  // x4 = h1 + h3 in place
  run_layer<128, float>(ws.h3, p4, b4, h4,
                        Wpre[3], bpre[3], Wpost[3], bpost[3], Wlin[3], blin[3], gamma[3], beta[3],
                        64, ws, stream);
  k_logits<<<(N + 255) / 256, 256, 0, stream>>>(h4, Wc, bcv, logits);
  (void)in_sizes; (void)n_in; (void)out_size; (void)ws_size;
}

// Round 12
// 1345.900 us; speedup vs baseline: 1.6782x; 1.0865x over previous
//
#include <hip/hip_runtime.h>
#include <math.h>

#define N_NODES 50000
#define N_EDGES 500000
#define SCAN_NB ((N_NODES + 1023) / 1024)

using bf16x8 = __attribute__((ext_vector_type(8))) short;
using f32x4  = __attribute__((ext_vector_type(4))) float;

// ---------- bf16 helpers ----------
__device__ inline float b2f(unsigned short u) {
  union { unsigned int i; float f; } v; v.i = ((unsigned int)u) << 16; return v.f;
}
__device__ inline unsigned short f2b(float f) {
  union { float f; unsigned int i; } v; v.f = f;
  unsigned int x = v.i;
  return (unsigned short)((x + 0x7fffu + ((x >> 16) & 1u)) >> 16);
}
__device__ inline unsigned int pk2(float a, float b) {
  return (unsigned int)f2b(a) | ((unsigned int)f2b(b) << 16);
}
__device__ inline void stv(unsigned short* p, float v) { *p = f2b(v); }
__device__ inline void stv(float* p, float v) { *p = v; }
__device__ inline float ldf(unsigned short u) { return b2f(u); }
__device__ inline float ldf(float f) { return f; }
__host__ __device__ inline int imin(int a, int b) { return a < b ? a : b; }

// direct global->LDS DMA, 16B per lane; lds base is wave-uniform, lane offset = lane*16
__device__ inline void gload16(const unsigned short* g, unsigned short* l) {
  __builtin_amdgcn_global_load_lds((const __attribute__((address_space(1))) unsigned int*)g,
                                   (__attribute__((address_space(3))) unsigned int*)l, 16, 0, 0);
}

// ---------------- degree / CSR ----------------
__global__ void k_count(const int* __restrict__ src, const int* __restrict__ dst,
                        int* __restrict__ cnt, int* __restrict__ degall) {
  int e = blockIdx.x * blockDim.x + threadIdx.x;
  if (e < N_EDGES) {
    atomicAdd(&cnt[dst[e]], 1);
    atomicAdd(&degall[src[e]], 1);
    atomicAdd(&degall[dst[e]], 1);
  }
}

// 3-phase parallel exclusive scan over cnt[N_NODES] -> ptr (+ ptr[N]=total)
__global__ __launch_bounds__(1024) void k_scan1(const int* __restrict__ cnt, int* __restrict__ ptr,
                                                int* __restrict__ sums) {
  __shared__ int buf[1024];
  int i = blockIdx.x * 1024 + threadIdx.x;
  int v = (i < N_NODES) ? cnt[i] : 0;
  buf[threadIdx.x] = v;
  __syncthreads();
  for (int off = 1; off < 1024; off <<= 1) {
    int tv = (threadIdx.x >= off) ? buf[threadIdx.x - off] : 0;
    __syncthreads();
    buf[threadIdx.x] += tv;
    __syncthreads();
  }
  if (i < N_NODES) ptr[i] = buf[threadIdx.x] - v;  // block-local exclusive
  if (threadIdx.x == 1023) sums[blockIdx.x] = buf[1023];
}

__global__ void k_scan2(int* __restrict__ sums) {
  if (threadIdx.x == 0) {
    int acc = 0;
    for (int b = 0; b < SCAN_NB; b++) {
      int t = sums[b];
      sums[b] = acc;
      acc += t;
    }
    sums[SCAN_NB] = acc;
  }
}

__global__ __launch_bounds__(1024) void k_scan3(int* __restrict__ ptr, const int* __restrict__ sums) {
  int i = blockIdx.x * 1024 + threadIdx.x;
  if (i < N_NODES) ptr[i] += sums[blockIdx.x];
  if (blockIdx.x == 0 && threadIdx.x == 0) ptr[N_NODES] = sums[SCAN_NB];
}

__global__ void k_fill(const int* __restrict__ src, const int* __restrict__ dst,
                       const int* __restrict__ ptr, int* __restrict__ cnt, int* __restrict__ col) {
  int e = blockIdx.x * blockDim.x + threadIdx.x;
  if (e < N_EDGES) {
    int d = dst[e];
    int pos = atomicAdd(&cnt[d], 1);
    col[ptr[d] + pos] = src[e];
  }
}

__global__ void k_avglog(const int* __restrict__ degall, float* __restrict__ scal) {
  __shared__ float L[256];
  float s = 0.f;
  for (int n = blockIdx.x * blockDim.x + threadIdx.x; n < N_NODES; n += gridDim.x * blockDim.x)
    s += logf((float)degall[n] + 1.0f);
  L[threadIdx.x] = s;
  __syncthreads();
  for (int o = 128; o > 0; o >>= 1) {
    if (threadIdx.x < o) L[threadIdx.x] += L[threadIdx.x + o];
    __syncthreads();
  }
  if (threadIdx.x == 0) atomicAdd(&scal[0], L[0]);
}

__global__ void k_avg_fin(float* scal) {
  float avg = scal[0] / (float)N_NODES;
  scal[1] = avg;
  scal[2] = 1.0f / avg;
}

__global__ void k_scalars(const int* __restrict__ ptr, const float* __restrict__ scal,
                          float* __restrict__ a_arr, float* __restrict__ c_arr) {
  int n = blockIdx.x * blockDim.x + threadIdx.x;
  if (n < N_NODES) {
    int d = ptr[n + 1] - ptr[n];
    float degc = fmaxf((float)d, 1.f);
    float logd = logf(degc + 1.f);
    a_arr[n] = logd * scal[2];
    c_arr[n] = scal[1] / logd;
  }
}

__global__ void k_cast(const float* __restrict__ x, unsigned short* __restrict__ xb, int total) {
  int i = blockIdx.x * blockDim.x + threadIdx.x;
  if (i < total) xb[i] = f2b(x[i]);
}

// pre-weights: BT_pre[j][k] = j<F ? Wpre[k][j] : Wpre[F+k][j-F]   (j<2F, k<F)
__global__ void k_tcast_pre(const float* __restrict__ Wpre, unsigned short* __restrict__ out, int F) {
  int i = blockIdx.x * blockDim.x + threadIdx.x;
  if (i < 2 * F * F) {
    int j = i / F, k = i % F;
    float v = (j < F) ? Wpre[(size_t)k * F + j] : Wpre[(size_t)(F + k) * F + (j - F)];
    out[i] = f2b(v);
  }
}

__global__ void k_biaspre(const float* __restrict__ bpre, float* __restrict__ biasPre, int F) {
  int j = threadIdx.x;
  if (j < 2 * F) biasPre[j] = (j < F) ? bpre[j] : 0.f;
}

// ---------------- weight GEMM: CT[c][r] = bf16( (Wpost@Wlin)[r][c] ) ----------------
__global__ __launch_bounds__(256) void k_wcombT(const float* __restrict__ A, const float* __restrict__ B,
                                                unsigned short* __restrict__ CT, int M, int Ncol, int K) {
  __shared__ float As[16][136];
  __shared__ float Bs[16][128];
  int tid = threadIdx.x;
  int row0 = blockIdx.y * 128, col0 = blockIdx.x * 128;
  int am = tid >> 1, ah = (tid & 1) * 8;
  int ty = tid >> 4, tx = tid & 15;
  float acc[8][8];
#pragma unroll
  for (int i = 0; i < 8; i++)
#pragma unroll
    for (int j = 0; j < 8; j++) acc[i][j] = 0.f;
  int arow = row0 + am;
  bool av = arow < M;
  const float* Ar = A + (size_t)arow * K;
  for (int k0 = 0; k0 < K; k0 += 16) {
    float4 a0 = make_float4(0, 0, 0, 0), a1 = make_float4(0, 0, 0, 0);
    if (av) {
      a0 = *(const float4*)(Ar + k0 + ah);
      a1 = *(const float4*)(Ar + k0 + ah + 4);
    }
    As[ah + 0][am] = a0.x; As[ah + 1][am] = a0.y; As[ah + 2][am] = a0.z; As[ah + 3][am] = a0.w;
    As[ah + 4][am] = a1.x; As[ah + 5][am] = a1.y; As[ah + 6][am] = a1.z; As[ah + 7][am] = a1.w;
#pragma unroll
    for (int i = 0; i < 2; i++) {
      int q = tid * 2 + i;
      int kk = q >> 5, j4 = (q & 31) * 4;
      int bc = col0 + j4;
      float4 b = make_float4(0, 0, 0, 0);
      if (bc < Ncol && (k0 + kk) < K) b = *(const float4*)(B + (size_t)(k0 + kk) * Ncol + bc);
      *(float4*)(&Bs[kk][j4]) = b;
    }
    __syncthreads();
#pragma unroll
    for (int kk = 0; kk < 16; kk++) {
      float av8[8], bv8[8];
#pragma unroll
      for (int i = 0; i < 8; i++) av8[i] = As[kk][ty * 8 + i];
#pragma unroll
      for (int j = 0; j < 8; j++) bv8[j] = Bs[kk][tx * 8 + j];
#pragma unroll
      for (int i = 0; i < 8; i++)
#pragma unroll
        for (int j = 0; j < 8; j++) acc[i][j] = fmaf(av8[i], bv8[j], acc[i][j]);
    }
    __syncthreads();
  }
#pragma unroll
  for (int i = 0; i < 8; i++) {
    int r = row0 + ty * 8 + i;
    if (r < M) {
#pragma unroll
      for (int j = 0; j < 8; j++) {
        int c = col0 + tx * 8 + j;
        if (c < Ncol) CT[(size_t)c * M + r] = f2b(acc[i][j]);
      }
    }
  }
}

// ---------------- m97-style MFMA GEMM (pre-GEMM): 128x128 tile, BK=32 ----------------
template <typename To>
__global__ __launch_bounds__(256) void k_mm(
    const unsigned short* __restrict__ A, int K,
    const unsigned short* __restrict__ BT,
    const float* __restrict__ bias,
    To* __restrict__ C, int n0, int M, int Ncol) {
  __shared__ unsigned short lds[2][2][4096];
  const int tid = threadIdx.x;
  const int lane = tid & 63;
  const int wid = tid >> 6;
  const int wr = wid >> 1, wc = wid & 1;
  const int row0 = blockIdx.y * 128;
  const int col0 = blockIdx.x * 128;
  const int l15 = lane & 15, lq = lane >> 4;
  const int srow = wid * 32 + (lane >> 2);
  const int scol = (lane & 3) * 8;
  const unsigned short* gA0 = A + (size_t)imin(row0 + srow, N_NODES - 1) * K + scol;
  const unsigned short* gA1 = A + (size_t)imin(row0 + srow + 16, N_NODES - 1) * K + scol;
  const unsigned short* gB0 = BT + (size_t)(col0 + srow) * K + scol;
  const unsigned short* gB1 = BT + (size_t)(col0 + srow + 16) * K + scol;

  f32x4 acc[4][4];
#pragma unroll
  for (int m = 0; m < 4; m++)
#pragma unroll
    for (int n = 0; n < 4; n++) acc[m][n] = (f32x4){0.f, 0.f, 0.f, 0.f};

  auto stage = [&](int buf, int k0) {
    gload16(gA0 + k0, &lds[buf][0][wid * 1024]);
    gload16(gA1 + k0, &lds[buf][0][wid * 1024 + 512]);
    gload16(gB0 + k0, &lds[buf][1][wid * 1024]);
    gload16(gB1 + k0, &lds[buf][1][wid * 1024 + 512]);
  };

  const int nk = K / 32;
  stage(0, 0);
  __syncthreads();
  for (int t = 0; t < nk; ++t) {
    const int cur = t & 1;
    if (t + 1 < nk) stage(cur ^ 1, (t + 1) * 32);
    bf16x8 a[4], b[4];
#pragma unroll
    for (int m = 0; m < 4; m++)
      a[m] = *(const bf16x8*)&lds[cur][0][(wr * 64 + m * 16 + l15) * 32 + lq * 8];
#pragma unroll
    for (int n = 0; n < 4; n++)
      b[n] = *(const bf16x8*)&lds[cur][1][(wc * 64 + n * 16 + l15) * 32 + lq * 8];
#pragma unroll
    for (int m = 0; m < 4; m++)
#pragma unroll
      for (int n = 0; n < 4; n++)
        acc[m][n] = __builtin_amdgcn_mfma_f32_16x16x32_bf16(a[m], b[n], acc[m][n], 0, 0, 0);
    __syncthreads();
  }
#pragma unroll
  for (int n = 0; n < 4; n++) {
    int col = col0 + wc * 64 + n * 16 + l15;
    float bv = bias ? bias[col] : 0.f;
#pragma unroll
    for (int m = 0; m < 4; m++) {
#pragma unroll
      for (int j = 0; j < 4; j++) {
        int r = row0 + wr * 64 + m * 16 + lq * 4 + j;
        if (r < M) stv(&C[(size_t)(n0 + r) * Ncol + col], acc[m][n][j] + bv);
      }
    }
  }
}

// ---------------- post-GEMM: 64xNTILE tile, BK=64, XOR-swizzled LDS (pre-swizzled global src) ----------------
// LDS[row][cc] holds global[row][cc ^ (row&7)] (cc = 16B chunk index, 8 chunks per 64-col row).
// ds_read applies the same XOR -> ~2-way (free) bank pattern.
template <int NTILE, typename To>
__global__ __launch_bounds__(256) void k_mmT(
    const unsigned short* __restrict__ A, int K, int Mbuf,
    const unsigned short* __restrict__ BT,
    const float* __restrict__ bias,
    To* __restrict__ C, int n0, int M, int Ncol) {
  constexpr int CB = NTILE / 32;      // B 1KB-chunks per wave
  constexpr int NF = NTILE / 32;      // 16-col frags per wave (wave covers NTILE/2 cols)
  __shared__ unsigned short lds[2][(64 + NTILE) * 64];
  const int tid = threadIdx.x;
  const int lane = tid & 63;
  const int wid = tid >> 6;
  const int wr = wid >> 1, wc = wid & 1;
  const int row0 = blockIdx.y * 64;
  const int col0 = blockIdx.x * NTILE;
  const int l15 = lane & 15, lq = lane >> 4;
  const int lr8 = lane >> 3;  // 0..7
  const int lc8 = lane & 7;   // 16B chunk within row

  f32x4 acc[2][NF];
#pragma unroll
  for (int m = 0; m < 2; m++)
#pragma unroll
    for (int n = 0; n < NF; n++) acc[m][n] = (f32x4){0.f, 0.f, 0.f, 0.f};

  auto stage = [&](int buf, int k0) {
    unsigned short* Ar = &lds[buf][0];
    unsigned short* Br = &lds[buf][64 * 64];
#pragma unroll
    for (int c = 0; c < 2; c++) {
      int r = (wid * 2 + c) * 8 + lr8;
      int gr = imin(row0 + r, Mbuf - 1);
      int gc = (lc8 ^ (r & 7)) * 8;
      gload16(A + (size_t)gr * K + k0 + gc, Ar + (wid * 2 + c) * 512);
    }
#pragma unroll
    for (int c = 0; c < CB; c++) {
      int r = (wid * CB + c) * 8 + lr8;
      int gc = (lc8 ^ (r & 7)) * 8;
      gload16(BT + (size_t)(col0 + r) * K + k0 + gc, Br + (wid * CB + c) * 512);
    }
  };

  const int nk = K / 64;
  stage(0, 0);
  __syncthreads();
  for (int t = 0; t < nk; ++t) {
    const int cur = t & 1;
    if (t + 1 < nk) stage(cur ^ 1, (t + 1) * 64);
    const unsigned short* Ar = &lds[cur][0];
    const unsigned short* Br = &lds[cur][64 * 64];
#pragma unroll
    for (int ks = 0; ks < 2; ks++) {
      bf16x8 a[2], b[NF];
#pragma unroll
      for (int m = 0; m < 2; m++) {
        int r = wr * 32 + m * 16 + l15;
        a[m] = *(const bf16x8*)&Ar[r * 64 + ((lq + ks * 4) ^ (r & 7)) * 8];
      }
#pragma unroll
      for (int n = 0; n < NF; n++) {
        int r = wc * (NTILE / 2) + n * 16 + l15;
        b[n] = *(const bf16x8*)&Br[r * 64 + ((lq + ks * 4) ^ (r & 7)) * 8];
      }
#pragma unroll
      for (int m = 0; m < 2; m++)
#pragma unroll
        for (int n = 0; n < NF; n++)
          acc[m][n] = __builtin_amdgcn_mfma_f32_16x16x32_bf16(a[m], b[n], acc[m][n], 0, 0, 0);
    }
    __syncthreads();
  }
#pragma unroll
  for (int n = 0; n < NF; n++) {
    int col = col0 + wc * (NTILE / 2) + n * 16 + l15;
    float bv = bias ? bias[col] : 0.f;
#pragma unroll
    for (int m = 0; m < 2; m++) {
#pragma unroll
      for (int j = 0; j < 4; j++) {
        int r = row0 + wr * 32 + m * 16 + lq * 4 + j;
        if (r < M) stv(&C[(size_t)(n0 + r) * Ncol + col], acc[m][n][j] + bv);
      }
    }
  }
}

// ---------------- edge aggregation (vectorized): writes 13F rows [x | agg | an*agg | cn*agg] ----------------
template <int F>
__global__ __launch_bounds__(256) void k_edge_agg(
    const unsigned short* __restrict__ ts, const unsigned short* __restrict__ xin,
    const int* __restrict__ ptr, const int* __restrict__ col,
    const float* __restrict__ a_arr, const float* __restrict__ c_arr,
    unsigned short* __restrict__ aggx, int n0, int nchunk) {
  constexpr int VU = F / 128;
  int idx = (blockIdx.x * blockDim.x + threadIdx.x) >> 6;
  int lane = threadIdx.x & 63;
  if (idx >= nchunk) return;
  int n = n0 + idx;
  if (n >= N_NODES) return;
  float S1[2 * VU], S2[2 * VU], mn[2 * VU], mx[2 * VU];
#pragma unroll
  for (int u = 0; u < 2 * VU; u++) {
    S1[u] = 0.f; S2[u] = 0.f; mn[u] = 3.4e38f; mx[u] = -3.4e38f;
  }
  int e0 = ptr[n], e1 = ptr[n + 1];
  for (int e = e0; e < e1; ++e) {
    int sidx = col[e];
    const unsigned int* sr = (const unsigned int*)(ts + (size_t)sidx * 2 * F + F);
#pragma unroll
    for (int u = 0; u < VU; u++) {
      unsigned int v = sr[lane + 64 * u];
      float f0 = b2f((unsigned short)(v & 0xffff));
      float f1 = b2f((unsigned short)(v >> 16));
      S1[2 * u] += f0; S2[2 * u] += f0 * f0;
      mn[2 * u] = fminf(mn[2 * u], f0); mx[2 * u] = fmaxf(mx[2 * u], f0);
      S1[2 * u + 1] += f1; S2[2 * u + 1] += f1 * f1;
      mn[2 * u + 1] = fminf(mn[2 * u + 1], f1); mx[2 * u + 1] = fmaxf(mx[2 * u + 1], f1);
    }
  }
  int d = e1 - e0;
  float an = a_arr[n], cn = c_arr[n];
  const unsigned int* tr = (const unsigned int*)(ts + (size_t)n * 2 * F);
  const unsigned int* xr = (const unsigned int*)(xin + (size_t)n * F);
  unsigned int* ob = (unsigned int*)(aggx + (size_t)idx * 13 * F);
  constexpr int UB = 64 * VU;
#pragma unroll
  for (int u = 0; u < VU; u++) {
    int ui = lane + 64 * u;
    ob[ui] = xr[ui];
    float mean0, mean1, lo0, lo1, hi0, hi1, sd0, sd1;
    if (d > 0) {
      float inv = 1.f / (float)d;
      unsigned int tv = tr[ui];
      float t0 = b2f((unsigned short)(tv & 0xffff));
      float t1 = b2f((unsigned short)(tv >> 16));
      float ms0 = S1[2 * u] * inv, ms1 = S1[2 * u + 1] * inv;
      sd0 = sqrtf(fmaxf(S2[2 * u] * inv - ms0 * ms0, 0.f) + 1e-5f);
      sd1 = sqrtf(fmaxf(S2[2 * u + 1] * inv - ms1 * ms1, 0.f) + 1e-5f);
      mean0 = t0 + ms0; mean1 = t1 + ms1;
      lo0 = t0 + mn[2 * u]; lo1 = t1 + mn[2 * u + 1];
      hi0 = t0 + mx[2 * u]; hi1 = t1 + mx[2 * u + 1];
    } else {
      mean0 = mean1 = lo0 = lo1 = hi0 = hi1 = 0.f;
      sd0 = sd1 = sqrtf(1e-5f);
    }
    unsigned int* o1 = ob + UB + ui;
    o1[0] = pk2(mean0, mean1);
    o1[UB] = pk2(lo0, lo1);
    o1[2 * UB] = pk2(hi0, hi1);
    o1[3 * UB] = pk2(sd0, sd1);
    o1[4 * UB] = pk2(an * mean0, an * mean1);
    o1[5 * UB] = pk2(an * lo0, an * lo1);
    o1[6 * UB] = pk2(an * hi0, an * hi1);
    o1[7 * UB] = pk2(an * sd0, an * sd1);
    o1[8 * UB] = pk2(cn * mean0, cn * mean1);
    o1[9 * UB] = pk2(cn * lo0, cn * lo1);
    o1[10 * UB] = pk2(cn * hi0, cn * hi1);
    o1[11 * UB] = pk2(cn * sd0, cn * sd1);
  }
}

// ---------------- BN stats: vectorized grid-stride + LDS reduce + 1 atomic/col/block ----------------
template <int FO>
__global__ __launch_bounds__(256) void k_bn_stats_bf(const unsigned short* __restrict__ o,
                                                     float* __restrict__ gsum, float* __restrict__ gsq) {
  constexpr int TOTAL = N_NODES * FO;
  float s1[8], s2[8];
#pragma unroll
  for (int j = 0; j < 8; j++) { s1[j] = 0.f; s2[j] = 0.f; }
  const int stride = gridDim.x * 2048;
  for (int base = blockIdx.x * 2048 + threadIdx.x * 8; base < TOTAL; base += stride) {
    uint4 v = *(const uint4*)(o + base);
    const unsigned int* u = (const unsigned int*)&v;
#pragma unroll
    for (int w = 0; w < 4; w++) {
      float f0 = b2f((unsigned short)(u[w] & 0xffff));
      float f1 = b2f((unsigned short)(u[w] >> 16));
      s1[2 * w] += f0; s2[2 * w] += f0 * f0;
      s1[2 * w + 1] += f1; s2[2 * w + 1] += f1 * f1;
    }
  }
  __shared__ float L1[2048], L2[2048];
#pragma unroll
  for (int j = 0; j < 8; j++) {
    L1[threadIdx.x * 8 + j] = s1[j];
    L2[threadIdx.x * 8 + j] = s2[j];
  }
  __syncthreads();
  int c = threadIdx.x;
  if (c < FO) {
    float a1 = 0.f, a2 = 0.f;
    for (int i = c; i < 2048; i += FO) { a1 += L1[i]; a2 += L2[i]; }
    atomicAdd(&gsum[c], a1);
    atomicAdd(&gsq[c], a2);
  }
}

template <int FO>
__global__ __launch_bounds__(256) void k_bn_stats_f32(const float* __restrict__ o,
                                                      float* __restrict__ gsum, float* __restrict__ gsq) {
  constexpr int TOTAL = N_NODES * FO;
  float s1[4], s2[4];
#pragma unroll
  for (int j = 0; j < 4; j++) { s1[j] = 0.f; s2[j] = 0.f; }
  const int stride = gridDim.x * 1024;
  for (int base = blockIdx.x * 1024 + threadIdx.x * 4; base < TOTAL; base += stride) {
    float4 v = *(const float4*)(o + base);
    s1[0] += v.x; s2[0] += v.x * v.x;
    s1[1] += v.y; s2[1] += v.y * v.y;
    s1[2] += v.z; s2[2] += v.z * v.z;
    s1[3] += v.w; s2[3] += v.w * v.w;
  }
  __shared__ float L1[1024], L2[1024];
#pragma unroll
  for (int j = 0; j < 4; j++) {
    L1[threadIdx.x * 4 + j] = s1[j];
    L2[threadIdx.x * 4 + j] = s2[j];
  }
  __syncthreads();
  int c = threadIdx.x;
  if (c < FO) {
    float a1 = 0.f, a2 = 0.f;
    for (int i = c; i < 1024; i += FO) { a1 += L1[i]; a2 += L2[i]; }
    atomicAdd(&gsum[c], a1);
    atomicAdd(&gsq[c], a2);
  }
}

__global__ void k_bn_fin(const float* bnsum, const float* bnsq, float* bnmean, float* bnrs, int FO) {
  int c = threadIdx.x;
  if (c < FO) {
    float mean = bnsum[c] / (float)N_NODES;
    float var = bnsq[c] / (float)N_NODES - mean * mean;
    bnmean[c] = mean;
    bnrs[c] = rsqrtf(var + 1e-5f);
  }
}

// ---------------- BN+ELU (vectorized) ----------------
template <int FO>
__global__ __launch_bounds__(256) void k_bn_elu_bf(const unsigned short* __restrict__ o,
                                                   const float* __restrict__ mean, const float* __restrict__ rs,
                                                   const float* __restrict__ gamma, const float* __restrict__ beta,
                                                   unsigned short* __restrict__ h) {
  constexpr int TOTAL = N_NODES * FO;
  int base = (blockIdx.x * blockDim.x + threadIdx.x) * 8;
  if (base >= TOTAL) return;
  int c0 = base % FO;
  uint4 v = *(const uint4*)(o + base);
  const unsigned int* u = (const unsigned int*)&v;
  unsigned int outw[4];
#pragma unroll
  for (int w = 0; w < 4; w++) {
    int c = c0 + 2 * w;
    float f0 = b2f((unsigned short)(u[w] & 0xffff));
    float f1 = b2f((unsigned short)(u[w] >> 16));
    float y0 = gamma[c] * (f0 - mean[c]) * rs[c] + beta[c];
    float y1 = gamma[c + 1] * (f1 - mean[c + 1]) * rs[c + 1] + beta[c + 1];
    y0 = y0 > 0.f ? y0 : expm1f(y0);
    y1 = y1 > 0.f ? y1 : expm1f(y1);
    outw[w] = pk2(y0, y1);
  }
  *(uint4*)(h + base) = *(uint4*)outw;
}

template <int FO>
__global__ __launch_bounds__(256) void k_bn_elu_f32(const float* __restrict__ o,
                                                    const float* __restrict__ mean, const float* __restrict__ rs,
                                                    const float* __restrict__ gamma, const float* __restrict__ beta,
                                                    unsigned short* __restrict__ h, float* __restrict__ bnout) {
  constexpr int TOTAL = N_NODES * FO;
  int base = (blockIdx.x * blockDim.x + threadIdx.x) * 4;
  if (base >= TOTAL) return;
  int c = base % FO;
  float4 v = *(const float4*)(o + base);
  float y0 = gamma[c] * (v.x - mean[c]) * rs[c] + beta[c];
  float y1 = gamma[c + 1] * (v.y - mean[c + 1]) * rs[c + 1] + beta[c + 1];
  float y2 = gamma[c + 2] * (v.z - mean[c + 2]) * rs[c + 2] + beta[c + 2];
  float y3 = gamma[c + 3] * (v.w - mean[c + 3]) * rs[c + 3] + beta[c + 3];
  if (bnout) *(float4*)(bnout + base) = make_float4(y0, y1, y2, y3);
  unsigned int o0 = pk2(y0 > 0.f ? y0 : expm1f(y0), y1 > 0.f ? y1 : expm1f(y1));
  unsigned int o1 = pk2(y2 > 0.f ? y2 : expm1f(y2), y3 > 0.f ? y3 : expm1f(y3));
  *(uint2*)(h + base) = make_uint2(o0, o1);
}

// ---------------- misc ----------------
__global__ void k_bcomb(const float* __restrict__ bpost, const float* __restrict__ Wlin,
                        const float* __restrict__ blin, float* __restrict__ bcomb, int FO) {
  int j = threadIdx.x;
  if (j < FO) {
    float acc = blin[j];
    for (int k = 0; k < FO; k++) acc += bpost[k] * Wlin[k * FO + j];
    bcomb[j] = acc;
  }
}

__global__ void k_add(const unsigned short* __restrict__ a, const unsigned short* __restrict__ b,
                      unsigned short* __restrict__ c) {
  int idx = blockIdx.x * blockDim.x + threadIdx.x;
  if (idx < N_NODES * 128) c[idx] = f2b(b2f(a[idx]) + b2f(b[idx]));
}

__global__ void k_logits(const unsigned short* __restrict__ h4, const float* __restrict__ Wc,
                         const float* __restrict__ bc, float* __restrict__ out) {
  int n = blockIdx.x * blockDim.x + threadIdx.x;
  if (n < N_NODES) {
    float acc0 = bc[0], acc1 = bc[1];
    const unsigned short* hr = h4 + (size_t)n * 64;
    for (int k = 0; k < 64; k++) {
      float v = b2f(hr[k]);
      acc0 += v * Wc[k * 2 + 0];
      acc1 += v * Wc[k * 2 + 1];
    }
    out[n * 2 + 0] = acc0;
    out[n * 2 + 1] = acc1;
  }
}

// ---------------- driver ----------------
struct WS {
  int *ptr, *col, *cnt, *degall, *scansums;
  float *scal, *a_arr, *c_arr, *bnsum, *bnsq, *bnmean, *bnrs, *bcomb, *biasPre;
  unsigned short *wcombT, *wpreT;
  unsigned short *xb, *h1, *h2, *h3, *ts, *aggx;
  size_t agg_elems;
};

template <int F, typename To>
static void run_layer(const unsigned short* xin, To* o_ptr, float* bnout, unsigned short* hout,
                      const float* Wpre, const float* bpre, const float* Wpost, const float* bpost,
                      const float* Wlin, const float* blin, const float* gamma, const float* beta,
                      int FO, const WS& ws, hipStream_t stream) {
  const int N = N_NODES;
  const int K13 = 13 * F;
  // weight prep (wcombT written transposed-bf16 directly)
  {
    dim3 g((FO + 127) / 128, (K13 + 127) / 128);
    k_wcombT<<<g, 256, 0, stream>>>(Wpost, Wlin, ws.wcombT, K13, FO, FO);
    k_bcomb<<<1, 256, 0, stream>>>(bpost, Wlin, blin, ws.bcomb, FO);
    k_tcast_pre<<<(2 * F * F + 255) / 256, 256, 0, stream>>>(Wpre, ws.wpreT, F);
    k_biaspre<<<1, 512, 0, stream>>>(bpre, ws.biasPre, F);
  }
  // fused pre-GEMM: ts = xin @ [W1 | W2] + [bpre | 0]
  {
    dim3 g(2 * F / 128, (N + 127) / 128);
    k_mm<unsigned short><<<g, 256, 0, stream>>>(xin, F, ws.wpreT, ws.biasPre, ws.ts, 0, N, 2 * F);
  }
  // chunked: edge aggregation (materializes 13F A) -> 64-row-tile swizzled post GEMM
  int NB = (int)(ws.agg_elems / (size_t)K13);
  NB &= ~127;
  if (NB > N) NB = N;
  if (NB < 128) NB = 128;
  for (int c0 = 0; c0 < N; c0 += NB) {
    int nc = (N - c0 < NB) ? (N - c0) : NB;
    k_edge_agg<F><<<(nc + 3) / 4, 256, 0, stream>>>(ws.ts, xin, ws.ptr, ws.col,
                                                    ws.a_arr, ws.c_arr, ws.aggx, c0, nc);
    if (FO == 64) {
      dim3 g(1, (nc + 63) / 64);
      k_mmT<64, To><<<g, 256, 0, stream>>>(ws.aggx, K13, NB, ws.wcombT, ws.bcomb, o_ptr, c0, nc, FO);
    } else {
      dim3 g(FO / 128, (nc + 63) / 64);
      k_mmT<128, To><<<g, 256, 0, stream>>>(ws.aggx, K13, NB, ws.wcombT, ws.bcomb, o_ptr, c0, nc, FO);
    }
  }
  // BN + ELU
  hipMemsetAsync(ws.bnsum, 0, 512 * sizeof(float), stream);  // bnsum+bnsq contiguous
  constexpr bool is_bf = (sizeof(To) == 2);
  if constexpr (is_bf) {
    int gs = imin((N * FO) / 2048 + 1, 1024);
    if (FO == 128)
      k_bn_stats_bf<128><<<gs, 256, 0, stream>>>((const unsigned short*)o_ptr, ws.bnsum, ws.bnsq);
    else
      k_bn_stats_bf<256><<<gs, 256, 0, stream>>>((const unsigned short*)o_ptr, ws.bnsum, ws.bnsq);
  } else {
    int gs = imin((N * FO) / 1024 + 1, 1024);
    k_bn_stats_f32<64><<<gs, 256, 0, stream>>>((const float*)o_ptr, ws.bnsum, ws.bnsq);
  }
  k_bn_fin<<<1, 256, 0, stream>>>(ws.bnsum, ws.bnsq, ws.bnmean, ws.bnrs, FO);
  int total = N_NODES * FO;
  if constexpr (is_bf) {
    int ge = (total / 8 + 255) / 256;
    if (FO == 128)
      k_bn_elu_bf<128><<<ge, 256, 0, stream>>>((const unsigned short*)o_ptr, ws.bnmean, ws.bnrs, gamma, beta, hout);
    else
      k_bn_elu_bf<256><<<ge, 256, 0, stream>>>((const unsigned short*)o_ptr, ws.bnmean, ws.bnrs, gamma, beta, hout);
  } else {
    int ge = (total / 4 + 255) / 256;
    k_bn_elu_f32<64><<<ge, 256, 0, stream>>>((const float*)o_ptr, ws.bnmean, ws.bnrs, gamma, beta, hout, bnout);
  }
}

extern "C" void kernel_launch(void* const* d_in, const int* in_sizes, int n_in,
                              void* d_out, int out_size, void* d_ws, size_t ws_size,
                              hipStream_t stream) {
  const int N = N_NODES, E = N_EDGES;
  const float* x = (const float*)d_in[0];
  const int* ei = (const int*)d_in[1];
  const int* src = ei;
  const int* dst = ei + E;
  const float *Wpre[4], *bpre[4], *Wpost[4], *bpost[4], *Wlin[4], *blin[4], *gamma[4], *beta[4];
  for (int i = 0; i < 4; i++) {
    const int b = 2 + i * 8;
    Wpre[i] = (const float*)d_in[b + 0];
    bpre[i] = (const float*)d_in[b + 1];
    Wpost[i] = (const float*)d_in[b + 2];
    bpost[i] = (const float*)d_in[b + 3];
    Wlin[i] = (const float*)d_in[b + 4];
    blin[i] = (const float*)d_in[b + 5];
    gamma[i] = (const float*)d_in[b + 6];
    beta[i] = (const float*)d_in[b + 7];
  }
  const float* Wc = (const float*)d_in[34];
  const float* bcv = (const float*)d_in[35];

  // ----- workspace layout (~119 MB fixed + adaptive aggx) -----
  char* w = (char*)d_ws;
  size_t off = 0;
  auto alloc = [&](size_t bytes) -> void* {
    void* p = (void*)(w + off);
    off = (off + bytes + 255) & ~(size_t)255;
    return p;
  };
  WS ws;
  ws.ptr = (int*)alloc((N + 1) * sizeof(int));
  ws.col = (int*)alloc((size_t)E * sizeof(int));
  ws.cnt = (int*)alloc((size_t)N * sizeof(int));
  ws.degall = (int*)alloc((size_t)N * sizeof(int));
  ws.scansums = (int*)alloc((SCAN_NB + 1) * sizeof(int));
  ws.scal = (float*)alloc(16 * sizeof(float));
  ws.a_arr = (float*)alloc((size_t)N * sizeof(float));
  ws.c_arr = (float*)alloc((size_t)N * sizeof(float));
  ws.bnsum = (float*)alloc(256 * sizeof(float));
  ws.bnsq = (float*)alloc(256 * sizeof(float));
  ws.bnmean = (float*)alloc(256 * sizeof(float));
  ws.bnrs = (float*)alloc(256 * sizeof(float));
  ws.bcomb = (float*)alloc(256 * sizeof(float));
  ws.biasPre = (float*)alloc(512 * sizeof(float));
  ws.wcombT = (unsigned short*)alloc((size_t)256 * 3328 * sizeof(unsigned short));
  ws.wpreT = (unsigned short*)alloc((size_t)512 * 256 * sizeof(unsigned short));
  ws.xb = (unsigned short*)alloc((size_t)N * 128 * sizeof(unsigned short));
  ws.h1 = (unsigned short*)alloc((size_t)N * 128 * sizeof(unsigned short));
  ws.h2 = (unsigned short*)alloc((size_t)N * 256 * sizeof(unsigned short));
  ws.h3 = (unsigned short*)alloc((size_t)N * 128 * sizeof(unsigned short));
  ws.ts = (unsigned short*)alloc((size_t)N * 512 * sizeof(unsigned short));
  size_t rem = (ws_size > off) ? (ws_size - off) : 0;
  ws.agg_elems = rem / sizeof(unsigned short);
  ws.aggx = (unsigned short*)(w + off);
  unsigned short* h4 = ws.xb;  // alias: x dead after layer 1; h4 is [N,64]

  float* outp = (float*)d_out;
  float* logits = outp;              // [N,2]
  float* p4 = outp + (size_t)N * 2;  // [N,64]
  float* b4 = p4 + (size_t)N * 64;   // [N,64]
  unsigned short* o_scratch = (unsigned short*)p4;  // pre-BN scratch, overwritten by layer 4

  // ----- degree / CSR / scalars -----
  hipMemsetAsync(ws.cnt, 0, N * sizeof(int), stream);
  hipMemsetAsync(ws.degall, 0, N * sizeof(int), stream);
  hipMemsetAsync(ws.scal, 0, 16 * sizeof(float), stream);
  k_count<<<(E + 255) / 256, 256, 0, stream>>>(src, dst, ws.cnt, ws.degall);
  k_scan1<<<SCAN_NB, 1024, 0, stream>>>(ws.cnt, ws.ptr, ws.scansums);
  k_scan2<<<1, 64, 0, stream>>>(ws.scansums);
  k_scan3<<<SCAN_NB, 1024, 0, stream>>>(ws.ptr, ws.scansums);
  hipMemsetAsync(ws.cnt, 0, N * sizeof(int), stream);
  k_fill<<<(E + 255) / 256, 256, 0, stream>>>(src, dst, ws.ptr, ws.cnt, ws.col);
  k_avglog<<<64, 256, 0, stream>>>(ws.degall, ws.scal);
  k_avg_fin<<<1, 1, 0, stream>>>(ws.scal);
  k_scalars<<<(N + 255) / 256, 256, 0, stream>>>(ws.ptr, ws.scal, ws.a_arr, ws.c_arr);
  k_cast<<<(N * 128 + 255) / 256, 256, 0, stream>>>(x, ws.xb, N * 128);

  run_layer<128, unsigned short>(ws.xb, o_scratch, nullptr, ws.h1,
                                 Wpre[0], bpre[0], Wpost[0], bpost[0], Wlin[0], blin[0], gamma[0], beta[0],
                                 128, ws, stream);
  run_layer<128, unsigned short>(ws.h1, o_scratch, nullptr, ws.h2,
                                 Wpre[1], bpre[1], Wpost[1], bpost[1], Wlin[1], blin[1], gamma[1], beta[1],
                                 256, ws, stream);
  run_layer<256, unsigned short>(ws.h2, o_scratch, nullptr, ws.h3,
                                 Wpre[2], bpre[2], Wpost[2], bpost[2], Wlin[2], blin[2], gamma[2], beta[2],
                                 128, ws, stream);
  k_add<<<((N * 128) + 255) / 256, 256, 0, stream>>>(ws.h1, ws.h3, ws.h3);  // x4 = h1 + h3 in place
  run_layer<128, float>(ws.h3, p4, b4, h4,
                        Wpre[3], bpre[3], Wpost[3], bpost[3], Wlin[3], blin[3], gamma[3], beta[3],
                        64, ws, stream);
  k_logits<<<(N + 255) / 256, 256, 0, stream>>>(h4, Wc, bcv, logits);
  (void)in_sizes; (void)n_in; (void)out_size; (void)ws_size;
}

// Round 13
// 1193.267 us; speedup vs baseline: 1.8929x; 1.1279x over previous
//
#include <hip/hip_runtime.h>
#include <math.h>

#define N_NODES 50000
#define N_EDGES 500000
#define SCAN_NB ((N_NODES + 1023) / 1024)

using bf16x8 = __attribute__((ext_vector_type(8))) short;
using f32x4  = __attribute__((ext_vector_type(4))) float;

// ---------- bf16 helpers ----------
__device__ inline float b2f(unsigned short u) {
  union { unsigned int i; float f; } v; v.i = ((unsigned int)u) << 16; return v.f;
}
__device__ inline unsigned short f2b(float f) {
  union { float f; unsigned int i; } v; v.f = f;
  unsigned int x = v.i;
  return (unsigned short)((x + 0x7fffu + ((x >> 16) & 1u)) >> 16);
}
__device__ inline unsigned int pk2(float a, float b) {
  return (unsigned int)f2b(a) | ((unsigned int)f2b(b) << 16);
}
__device__ inline void stv(unsigned short* p, float v) { *p = f2b(v); }
__device__ inline void stv(float* p, float v) { *p = v; }
__device__ inline float ldf(unsigned short u) { return b2f(u); }
__device__ inline float ldf(float f) { return f; }
__host__ __device__ inline int imin(int a, int b) { return a < b ? a : b; }

// direct global->LDS DMA, 16B per lane; lds base is wave-uniform, lane offset = lane*16
__device__ inline void gload16(const unsigned short* g, unsigned short* l) {
  __builtin_amdgcn_global_load_lds((const __attribute__((address_space(1))) unsigned int*)g,
                                   (__attribute__((address_space(3))) unsigned int*)l, 16, 0, 0);
}

// ---------------- degree / CSR ----------------
__global__ void k_count(const int* __restrict__ src, const int* __restrict__ dst,
                        int* __restrict__ cnt, int* __restrict__ degall) {
  int e = blockIdx.x * blockDim.x + threadIdx.x;
  if (e < N_EDGES) {
    atomicAdd(&cnt[dst[e]], 1);
    atomicAdd(&degall[src[e]], 1);
    atomicAdd(&degall[dst[e]], 1);
  }
}

// 3-phase parallel exclusive scan over cnt[N_NODES] -> ptr (+ ptr[N]=total)
__global__ __launch_bounds__(1024) void k_scan1(const int* __restrict__ cnt, int* __restrict__ ptr,
                                                int* __restrict__ sums) {
  __shared__ int buf[1024];
  int i = blockIdx.x * 1024 + threadIdx.x;
  int v = (i < N_NODES) ? cnt[i] : 0;
  buf[threadIdx.x] = v;
  __syncthreads();
  for (int off = 1; off < 1024; off <<= 1) {
    int tv = (threadIdx.x >= off) ? buf[threadIdx.x - off] : 0;
    __syncthreads();
    buf[threadIdx.x] += tv;
    __syncthreads();
  }
  if (i < N_NODES) ptr[i] = buf[threadIdx.x] - v;  // block-local exclusive
  if (threadIdx.x == 1023) sums[blockIdx.x] = buf[1023];
}

__global__ void k_scan2(int* __restrict__ sums) {
  if (threadIdx.x == 0) {
    int acc = 0;
    for (int b = 0; b < SCAN_NB; b++) {
      int t = sums[b];
      sums[b] = acc;
      acc += t;
    }
    sums[SCAN_NB] = acc;
  }
}

__global__ __launch_bounds__(1024) void k_scan3(int* __restrict__ ptr, const int* __restrict__ sums) {
  int i = blockIdx.x * 1024 + threadIdx.x;
  if (i < N_NODES) ptr[i] += sums[blockIdx.x];
  if (blockIdx.x == 0 && threadIdx.x == 0) ptr[N_NODES] = sums[SCAN_NB];
}

__global__ void k_fill(const int* __restrict__ src, const int* __restrict__ dst,
                       const int* __restrict__ ptr, int* __restrict__ cnt, int* __restrict__ col) {
  int e = blockIdx.x * blockDim.x + threadIdx.x;
  if (e < N_EDGES) {
    int d = dst[e];
    int pos = atomicAdd(&cnt[d], 1);
    col[ptr[d] + pos] = src[e];
  }
}

__global__ void k_avglog(const int* __restrict__ degall, float* __restrict__ scal) {
  __shared__ float L[256];
  float s = 0.f;
  for (int n = blockIdx.x * blockDim.x + threadIdx.x; n < N_NODES; n += gridDim.x * blockDim.x)
    s += logf((float)degall[n] + 1.0f);
  L[threadIdx.x] = s;
  __syncthreads();
  for (int o = 128; o > 0; o >>= 1) {
    if (threadIdx.x < o) L[threadIdx.x] += L[threadIdx.x + o];
    __syncthreads();
  }
  if (threadIdx.x == 0) atomicAdd(&scal[0], L[0]);
}

__global__ void k_avg_fin(float* scal) {
  float avg = scal[0] / (float)N_NODES;
  scal[1] = avg;
  scal[2] = 1.0f / avg;
}

__global__ void k_scalars(const int* __restrict__ ptr, const float* __restrict__ scal,
                          float* __restrict__ a_arr, float* __restrict__ c_arr) {
  int n = blockIdx.x * blockDim.x + threadIdx.x;
  if (n < N_NODES) {
    int d = ptr[n + 1] - ptr[n];
    float degc = fmaxf((float)d, 1.f);
    float logd = logf(degc + 1.f);
    a_arr[n] = logd * scal[2];
    c_arr[n] = scal[1] / logd;
  }
}

__global__ void k_cast(const float* __restrict__ x, unsigned short* __restrict__ xb, int total) {
  int i = blockIdx.x * blockDim.x + threadIdx.x;
  if (i < total) xb[i] = f2b(x[i]);
}

// pre-weights: BT_pre[j][k] = j<F ? Wpre[k][j] : Wpre[F+k][j-F]   (j<2F, k<F)
__global__ void k_tcast_pre(const float* __restrict__ Wpre, unsigned short* __restrict__ out, int F) {
  int i = blockIdx.x * blockDim.x + threadIdx.x;
  if (i < 2 * F * F) {
    int j = i / F, k = i % F;
    float v = (j < F) ? Wpre[(size_t)k * F + j] : Wpre[(size_t)(F + k) * F + (j - F)];
    out[i] = f2b(v);
  }
}

__global__ void k_biaspre(const float* __restrict__ bpre, float* __restrict__ biasPre, int F) {
  int j = threadIdx.x;
  if (j < 2 * F) biasPre[j] = (j < F) ? bpre[j] : 0.f;
}

// ---------------- weight GEMM: CT[c][r] = bf16( (Wpost@Wlin)[r][c] ) ----------------
__global__ __launch_bounds__(256) void k_wcombT(const float* __restrict__ A, const float* __restrict__ B,
                                                unsigned short* __restrict__ CT, int M, int Ncol, int K) {
  __shared__ float As[16][136];
  __shared__ float Bs[16][128];
  int tid = threadIdx.x;
  int row0 = blockIdx.y * 128, col0 = blockIdx.x * 128;
  int am = tid >> 1, ah = (tid & 1) * 8;
  int ty = tid >> 4, tx = tid & 15;
  float acc[8][8];
#pragma unroll
  for (int i = 0; i < 8; i++)
#pragma unroll
    for (int j = 0; j < 8; j++) acc[i][j] = 0.f;
  int arow = row0 + am;
  bool av = arow < M;
  const float* Ar = A + (size_t)arow * K;
  for (int k0 = 0; k0 < K; k0 += 16) {
    float4 a0 = make_float4(0, 0, 0, 0), a1 = make_float4(0, 0, 0, 0);
    if (av) {
      a0 = *(const float4*)(Ar + k0 + ah);
      a1 = *(const float4*)(Ar + k0 + ah + 4);
    }
    As[ah + 0][am] = a0.x; As[ah + 1][am] = a0.y; As[ah + 2][am] = a0.z; As[ah + 3][am] = a0.w;
    As[ah + 4][am] = a1.x; As[ah + 5][am] = a1.y; As[ah + 6][am] = a1.z; As[ah + 7][am] = a1.w;
#pragma unroll
    for (int i = 0; i < 2; i++) {
      int q = tid * 2 + i;
      int kk = q >> 5, j4 = (q & 31) * 4;
      int bc = col0 + j4;
      float4 b = make_float4(0, 0, 0, 0);
      if (bc < Ncol && (k0 + kk) < K) b = *(const float4*)(B + (size_t)(k0 + kk) * Ncol + bc);
      *(float4*)(&Bs[kk][j4]) = b;
    }
    __syncthreads();
#pragma unroll
    for (int kk = 0; kk < 16; kk++) {
      float av8[8], bv8[8];
#pragma unroll
      for (int i = 0; i < 8; i++) av8[i] = As[kk][ty * 8 + i];
#pragma unroll
      for (int j = 0; j < 8; j++) bv8[j] = Bs[kk][tx * 8 + j];
#pragma unroll
      for (int i = 0; i < 8; i++)
#pragma unroll
        for (int j = 0; j < 8; j++) acc[i][j] = fmaf(av8[i], bv8[j], acc[i][j]);
    }
    __syncthreads();
  }
#pragma unroll
  for (int i = 0; i < 8; i++) {
    int r = row0 + ty * 8 + i;
    if (r < M) {
#pragma unroll
      for (int j = 0; j < 8; j++) {
        int c = col0 + tx * 8 + j;
        if (c < Ncol) CT[(size_t)c * M + r] = f2b(acc[i][j]);
      }
    }
  }
}

// ---------------- m97-style MFMA GEMM (pre-GEMM): 128x128 tile, BK=32 ----------------
template <typename To>
__global__ __launch_bounds__(256) void k_mm(
    const unsigned short* __restrict__ A, int K,
    const unsigned short* __restrict__ BT,
    const float* __restrict__ bias,
    To* __restrict__ C, int n0, int M, int Ncol) {
  __shared__ unsigned short lds[2][2][4096];
  const int tid = threadIdx.x;
  const int lane = tid & 63;
  const int wid = tid >> 6;
  const int wr = wid >> 1, wc = wid & 1;
  const int row0 = blockIdx.y * 128;
  const int col0 = blockIdx.x * 128;
  const int l15 = lane & 15, lq = lane >> 4;
  const int srow = wid * 32 + (lane >> 2);
  const int scol = (lane & 3) * 8;
  const unsigned short* gA0 = A + (size_t)imin(row0 + srow, N_NODES - 1) * K + scol;
  const unsigned short* gA1 = A + (size_t)imin(row0 + srow + 16, N_NODES - 1) * K + scol;
  const unsigned short* gB0 = BT + (size_t)(col0 + srow) * K + scol;
  const unsigned short* gB1 = BT + (size_t)(col0 + srow + 16) * K + scol;

  f32x4 acc[4][4];
#pragma unroll
  for (int m = 0; m < 4; m++)
#pragma unroll
    for (int n = 0; n < 4; n++) acc[m][n] = (f32x4){0.f, 0.f, 0.f, 0.f};

  auto stage = [&](int buf, int k0) {
    gload16(gA0 + k0, &lds[buf][0][wid * 1024]);
    gload16(gA1 + k0, &lds[buf][0][wid * 1024 + 512]);
    gload16(gB0 + k0, &lds[buf][1][wid * 1024]);
    gload16(gB1 + k0, &lds[buf][1][wid * 1024 + 512]);
  };

  const int nk = K / 32;
  stage(0, 0);
  __syncthreads();
  for (int t = 0; t < nk; ++t) {
    const int cur = t & 1;
    if (t + 1 < nk) stage(cur ^ 1, (t + 1) * 32);
    bf16x8 a[4], b[4];
#pragma unroll
    for (int m = 0; m < 4; m++)
      a[m] = *(const bf16x8*)&lds[cur][0][(wr * 64 + m * 16 + l15) * 32 + lq * 8];
#pragma unroll
    for (int n = 0; n < 4; n++)
      b[n] = *(const bf16x8*)&lds[cur][1][(wc * 64 + n * 16 + l15) * 32 + lq * 8];
#pragma unroll
    for (int m = 0; m < 4; m++)
#pragma unroll
      for (int n = 0; n < 4; n++)
        acc[m][n] = __builtin_amdgcn_mfma_f32_16x16x32_bf16(a[m], b[n], acc[m][n], 0, 0, 0);
    __syncthreads();
  }
#pragma unroll
  for (int n = 0; n < 4; n++) {
    int col = col0 + wc * 64 + n * 16 + l15;
    float bv = bias ? bias[col] : 0.f;
#pragma unroll
    for (int m = 0; m < 4; m++) {
#pragma unroll
      for (int j = 0; j < 4; j++) {
        int r = row0 + wr * 64 + m * 16 + lq * 4 + j;
        if (r < M) stv(&C[(size_t)(n0 + r) * Ncol + col], acc[m][n][j] + bv);
      }
    }
  }
}

// ---------------- post-GEMM: virtual 13F A from [x (global) | 4F stats (chunk)] ----------------
// 64xNTILE tile, BK=64, XOR-swizzled LDS (pre-swizzled global src, 0-conflict ds_read).
// Regions: k<F -> X; [F,5F),[5F,9F),[9F,13F) -> G (same 4F buffer, 3 passes).
// Folds: master=acc at 5F; master+=an*acc at 9F; master+=cn*acc at end. an/cn per-row f32.
template <int NTILE, int F, typename To>
__global__ __launch_bounds__(256) void k_mmP(
    const unsigned short* __restrict__ X,
    const unsigned short* __restrict__ G,
    const float* __restrict__ a_arr, const float* __restrict__ c_arr,
    const unsigned short* __restrict__ BT,
    const float* __restrict__ bias,
    To* __restrict__ C, int n0, int M, int Mbuf, int Ncol) {
  constexpr int K13 = 13 * F;
  constexpr int F4 = 4 * F;
  constexpr int CB = NTILE / 32;
  constexpr int NF = NTILE / 32;
  __shared__ unsigned short lds[2][(64 + NTILE) * 64];
  const int tid = threadIdx.x;
  const int lane = tid & 63;
  const int wid = tid >> 6;
  const int wr = wid >> 1, wc = wid & 1;
  const int row0 = blockIdx.y * 64;
  const int col0 = blockIdx.x * NTILE;
  const int l15 = lane & 15, lq = lane >> 4;
  const int lr8 = lane >> 3;
  const int lc8 = lane & 7;

  // per-row combine scales
  f32x4 anv[2], cnv[2];
#pragma unroll
  for (int m = 0; m < 2; m++)
#pragma unroll
    for (int j = 0; j < 4; j++) {
      int g = imin(n0 + row0 + wr * 32 + m * 16 + lq * 4 + j, N_NODES - 1);
      anv[m][j] = a_arr[g];
      cnv[m][j] = c_arr[g];
    }

  f32x4 master[2][NF], acc[2][NF];
#pragma unroll
  for (int m = 0; m < 2; m++)
#pragma unroll
    for (int n = 0; n < NF; n++) {
      master[m][n] = (f32x4){0.f, 0.f, 0.f, 0.f};
      acc[m][n] = (f32x4){0.f, 0.f, 0.f, 0.f};
    }

  auto stage = [&](int buf, int k0) {
    unsigned short* Ar = &lds[buf][0];
    unsigned short* Br = &lds[buf][64 * 64];
#pragma unroll
    for (int c = 0; c < 2; c++) {
      int r = (wid * 2 + c) * 8 + lr8;
      int gc = (lc8 ^ (r & 7)) * 8;
      const unsigned short* src;
      if (k0 < F) {
        src = X + (size_t)imin(n0 + row0 + r, N_NODES - 1) * F + k0 + gc;
      } else {
        int q = k0 - F;
        int reg = q / F4;
        int koff = q - reg * F4;
        src = G + (size_t)imin(row0 + r, Mbuf - 1) * F4 + koff + gc;
      }
      gload16(src, Ar + (wid * 2 + c) * 512);
    }
#pragma unroll
    for (int c = 0; c < CB; c++) {
      int r = (wid * CB + c) * 8 + lr8;
      int gc = (lc8 ^ (r & 7)) * 8;
      gload16(BT + (size_t)(col0 + r) * K13 + k0 + gc, Br + (wid * CB + c) * 512);
    }
  };

  const int nk = K13 / 64;
  stage(0, 0);
  __syncthreads();
  for (int t = 0; t < nk; ++t) {
    const int k0 = t * 64;
    const int cur = t & 1;
    if (t + 1 < nk) stage(cur ^ 1, (t + 1) * 64);
    const unsigned short* Ar = &lds[cur][0];
    const unsigned short* Br = &lds[cur][64 * 64];
#pragma unroll
    for (int ks = 0; ks < 2; ks++) {
      bf16x8 a[2], b[NF];
#pragma unroll
      for (int m = 0; m < 2; m++) {
        int r = wr * 32 + m * 16 + l15;
        a[m] = *(const bf16x8*)&Ar[r * 64 + ((lq + ks * 4) ^ (r & 7)) * 8];
      }
#pragma unroll
      for (int n = 0; n < NF; n++) {
        int r = wc * (NTILE / 2) + n * 16 + l15;
        b[n] = *(const bf16x8*)&Br[r * 64 + ((lq + ks * 4) ^ (r & 7)) * 8];
      }
#pragma unroll
      for (int m = 0; m < 2; m++)
#pragma unroll
        for (int n = 0; n < NF; n++)
          acc[m][n] = __builtin_amdgcn_mfma_f32_16x16x32_bf16(a[m], b[n], acc[m][n], 0, 0, 0);
    }
    __syncthreads();
    // region-boundary folds (wave-uniform branch)
    if (k0 + 64 == 5 * F) {
#pragma unroll
      for (int m = 0; m < 2; m++)
#pragma unroll
        for (int n = 0; n < NF; n++) {
          master[m][n] = acc[m][n];
          acc[m][n] = (f32x4){0.f, 0.f, 0.f, 0.f};
        }
    } else if (k0 + 64 == 9 * F) {
#pragma unroll
      for (int m = 0; m < 2; m++)
#pragma unroll
        for (int n = 0; n < NF; n++) {
          master[m][n] += anv[m] * acc[m][n];
          acc[m][n] = (f32x4){0.f, 0.f, 0.f, 0.f};
        }
    }
  }
#pragma unroll
  for (int m = 0; m < 2; m++)
#pragma unroll
    for (int n = 0; n < NF; n++) master[m][n] += cnv[m] * acc[m][n];
  // epilogue
#pragma unroll
  for (int n = 0; n < NF; n++) {
    int col = col0 + wc * (NTILE / 2) + n * 16 + l15;
    float bv = bias[col];
#pragma unroll
    for (int m = 0; m < 2; m++) {
#pragma unroll
      for (int j = 0; j < 4; j++) {
        int r = row0 + wr * 32 + m * 16 + lq * 4 + j;
        if (r < M) stv(&C[(size_t)(n0 + r) * Ncol + col], master[m][n][j] + bv);
      }
    }
  }
}

// ---------------- edge aggregation (vectorized): writes 4F rows [mean | min | max | std] ----------------
template <int F>
__global__ __launch_bounds__(256) void k_edge_agg(
    const unsigned short* __restrict__ ts,
    const int* __restrict__ ptr, const int* __restrict__ col,
    unsigned short* __restrict__ aggc, int n0, int nchunk) {
  constexpr int VU = F / 128;
  int idx = (blockIdx.x * blockDim.x + threadIdx.x) >> 6;
  int lane = threadIdx.x & 63;
  if (idx >= nchunk) return;
  int n = n0 + idx;
  if (n >= N_NODES) return;
  float S1[2 * VU], S2[2 * VU], mn[2 * VU], mx[2 * VU];
#pragma unroll
  for (int u = 0; u < 2 * VU; u++) {
    S1[u] = 0.f; S2[u] = 0.f; mn[u] = 3.4e38f; mx[u] = -3.4e38f;
  }
  int e0 = ptr[n], e1 = ptr[n + 1];
  for (int e = e0; e < e1; ++e) {
    int sidx = col[e];
    const unsigned int* sr = (const unsigned int*)(ts + (size_t)sidx * 2 * F + F);
#pragma unroll
    for (int u = 0; u < VU; u++) {
      unsigned int v = sr[lane + 64 * u];
      float f0 = b2f((unsigned short)(v & 0xffff));
      float f1 = b2f((unsigned short)(v >> 16));
      S1[2 * u] += f0; S2[2 * u] += f0 * f0;
      mn[2 * u] = fminf(mn[2 * u], f0); mx[2 * u] = fmaxf(mx[2 * u], f0);
      S1[2 * u + 1] += f1; S2[2 * u + 1] += f1 * f1;
      mn[2 * u + 1] = fminf(mn[2 * u + 1], f1); mx[2 * u + 1] = fmaxf(mx[2 * u + 1], f1);
    }
  }
  int d = e1 - e0;
  const unsigned int* tr = (const unsigned int*)(ts + (size_t)n * 2 * F);
  unsigned int* ob = (unsigned int*)(aggc + (size_t)idx * 4 * F);
  constexpr int UB = 64 * VU;
#pragma unroll
  for (int u = 0; u < VU; u++) {
    int ui = lane + 64 * u;
    float mean0, mean1, lo0, lo1, hi0, hi1, sd0, sd1;
    if (d > 0) {
      float inv = 1.f / (float)d;
      unsigned int tv = tr[ui];
      float t0 = b2f((unsigned short)(tv & 0xffff));
      float t1 = b2f((unsigned short)(tv >> 16));
      float ms0 = S1[2 * u] * inv, ms1 = S1[2 * u + 1] * inv;
      sd0 = sqrtf(fmaxf(S2[2 * u] * inv - ms0 * ms0, 0.f) + 1e-5f);
      sd1 = sqrtf(fmaxf(S2[2 * u + 1] * inv - ms1 * ms1, 0.f) + 1e-5f);
      mean0 = t0 + ms0; mean1 = t1 + ms1;
      lo0 = t0 + mn[2 * u]; lo1 = t1 + mn[2 * u + 1];
      hi0 = t0 + mx[2 * u]; hi1 = t1 + mx[2 * u + 1];
    } else {
      mean0 = mean1 = lo0 = lo1 = hi0 = hi1 = 0.f;
      sd0 = sd1 = sqrtf(1e-5f);
    }
    unsigned int* o1 = ob + ui;
    o1[0] = pk2(mean0, mean1);
    o1[UB] = pk2(lo0, lo1);
    o1[2 * UB] = pk2(hi0, hi1);
    o1[3 * UB] = pk2(sd0, sd1);
  }
}

// ---------------- BN stats ----------------
template <int FO>
__global__ __launch_bounds__(256) void k_bn_stats_bf(const unsigned short* __restrict__ o,
                                                     float* __restrict__ gsum, float* __restrict__ gsq) {
  constexpr int TOTAL = N_NODES * FO;
  float s1[8], s2[8];
#pragma unroll
  for (int j = 0; j < 8; j++) { s1[j] = 0.f; s2[j] = 0.f; }
  const int stride = gridDim.x * 2048;
  for (int base = blockIdx.x * 2048 + threadIdx.x * 8; base < TOTAL; base += stride) {
    uint4 v = *(const uint4*)(o + base);
    const unsigned int* u = (const unsigned int*)&v;
#pragma unroll
    for (int w = 0; w < 4; w++) {
      float f0 = b2f((unsigned short)(u[w] & 0xffff));
      float f1 = b2f((unsigned short)(u[w] >> 16));
      s1[2 * w] += f0; s2[2 * w] += f0 * f0;
      s1[2 * w + 1] += f1; s2[2 * w + 1] += f1 * f1;
    }
  }
  __shared__ float L1[2048], L2[2048];
#pragma unroll
  for (int j = 0; j < 8; j++) {
    L1[threadIdx.x * 8 + j] = s1[j];
    L2[threadIdx.x * 8 + j] = s2[j];
  }
  __syncthreads();
  int c = threadIdx.x;
  if (c < FO) {
    float a1 = 0.f, a2 = 0.f;
    for (int i = c; i < 2048; i += FO) { a1 += L1[i]; a2 += L2[i]; }
    atomicAdd(&gsum[c], a1);
    atomicAdd(&gsq[c], a2);
  }
}

template <int FO>
__global__ __launch_bounds__(256) void k_bn_stats_f32(const float* __restrict__ o,
                                                      float* __restrict__ gsum, float* __restrict__ gsq) {
  constexpr int TOTAL = N_NODES * FO;
  float s1[4], s2[4];
#pragma unroll
  for (int j = 0; j < 4; j++) { s1[j] = 0.f; s2[j] = 0.f; }
  const int stride = gridDim.x * 1024;
  for (int base = blockIdx.x * 1024 + threadIdx.x * 4; base < TOTAL; base += stride) {
    float4 v = *(const float4*)(o + base);
    s1[0] += v.x; s2[0] += v.x * v.x;
    s1[1] += v.y; s2[1] += v.y * v.y;
    s1[2] += v.z; s2[2] += v.z * v.z;
    s1[3] += v.w; s2[3] += v.w * v.w;
  }
  __shared__ float L1[1024], L2[1024];
#pragma unroll
  for (int j = 0; j < 4; j++) {
    L1[threadIdx.x * 4 + j] = s1[j];
    L2[threadIdx.x * 4 + j] = s2[j];
  }
  __syncthreads();
  int c = threadIdx.x;
  if (c < FO) {
    float a1 = 0.f, a2 = 0.f;
    for (int i = c; i < 1024; i += FO) { a1 += L1[i]; a2 += L2[i]; }
    atomicAdd(&gsum[c], a1);
    atomicAdd(&gsq[c], a2);
  }
}

__global__ void k_bn_fin(const float* bnsum, const float* bnsq, float* bnmean, float* bnrs, int FO) {
  int c = threadIdx.x;
  if (c < FO) {
    float mean = bnsum[c] / (float)N_NODES;
    float var = bnsq[c] / (float)N_NODES - mean * mean;
    bnmean[c] = mean;
    bnrs[c] = rsqrtf(var + 1e-5f);
  }
}

// ---------------- BN+ELU (vectorized) ----------------
template <int FO>
__global__ __launch_bounds__(256) void k_bn_elu_bf(const unsigned short* __restrict__ o,
                                                   const float* __restrict__ mean, const float* __restrict__ rs,
                                                   const float* __restrict__ gamma, const float* __restrict__ beta,
                                                   unsigned short* __restrict__ h) {
  constexpr int TOTAL = N_NODES * FO;
  int base = (blockIdx.x * blockDim.x + threadIdx.x) * 8;
  if (base >= TOTAL) return;
  int c0 = base % FO;
  uint4 v = *(const uint4*)(o + base);
  const unsigned int* u = (const unsigned int*)&v;
  unsigned int outw[4];
#pragma unroll
  for (int w = 0; w < 4; w++) {
    int c = c0 + 2 * w;
    float f0 = b2f((unsigned short)(u[w] & 0xffff));
    float f1 = b2f((unsigned short)(u[w] >> 16));
    float y0 = gamma[c] * (f0 - mean[c]) * rs[c] + beta[c];
    float y1 = gamma[c + 1] * (f1 - mean[c + 1]) * rs[c + 1] + beta[c + 1];
    y0 = y0 > 0.f ? y0 : expm1f(y0);
    y1 = y1 > 0.f ? y1 : expm1f(y1);
    outw[w] = pk2(y0, y1);
  }
  *(uint4*)(h + base) = *(uint4*)outw;
}

template <int FO>
__global__ __launch_bounds__(256) void k_bn_elu_f32(const float* __restrict__ o,
                                                    const float* __restrict__ mean, const float* __restrict__ rs,
                                                    const float* __restrict__ gamma, const float* __restrict__ beta,
                                                    unsigned short* __restrict__ h, float* __restrict__ bnout) {
  constexpr int TOTAL = N_NODES * FO;
  int base = (blockIdx.x * blockDim.x + threadIdx.x) * 4;
  if (base >= TOTAL) return;
  int c = base % FO;
  float4 v = *(const float4*)(o + base);
  float y0 = gamma[c] * (v.x - mean[c]) * rs[c] + beta[c];
  float y1 = gamma[c + 1] * (v.y - mean[c + 1]) * rs[c + 1] + beta[c + 1];
  float y2 = gamma[c + 2] * (v.z - mean[c + 2]) * rs[c + 2] + beta[c + 2];
  float y3 = gamma[c + 3] * (v.w - mean[c + 3]) * rs[c + 3] + beta[c + 3];
  if (bnout) *(float4*)(bnout + base) = make_float4(y0, y1, y2, y3);
  unsigned int o0 = pk2(y0 > 0.f ? y0 : expm1f(y0), y1 > 0.f ? y1 : expm1f(y1));
  unsigned int o1 = pk2(y2 > 0.f ? y2 : expm1f(y2), y3 > 0.f ? y3 : expm1f(y3));
  *(uint2*)(h + base) = make_uint2(o0, o1);
}

// ---------------- misc ----------------
__global__ void k_bcomb(const float* __restrict__ bpost, const float* __restrict__ Wlin,
                        const float* __restrict__ blin, float* __restrict__ bcomb, int FO) {
  int j = threadIdx.x;
  if (j < FO) {
    float acc = blin[j];
    for (int k = 0; k < FO; k++) acc += bpost[k] * Wlin[k * FO + j];
    bcomb[j] = acc;
  }
}

__global__ void k_add(const unsigned short* __restrict__ a, const unsigned short* __restrict__ b,
                      unsigned short* __restrict__ c) {
  int idx = blockIdx.x * blockDim.x + threadIdx.x;
  if (idx < N_NODES * 128) c[idx] = f2b(b2f(a[idx]) + b2f(b[idx]));
}

__global__ void k_logits(const unsigned short* __restrict__ h4, const float* __restrict__ Wc,
                         const float* __restrict__ bc, float* __restrict__ out) {
  int n = blockIdx.x * blockDim.x + threadIdx.x;
  if (n < N_NODES) {
    float acc0 = bc[0], acc1 = bc[1];
    const unsigned short* hr = h4 + (size_t)n * 64;
    for (int k = 0; k < 64; k++) {
      float v = b2f(hr[k]);
      acc0 += v * Wc[k * 2 + 0];
      acc1 += v * Wc[k * 2 + 1];
    }
    out[n * 2 + 0] = acc0;
    out[n * 2 + 1] = acc1;
  }
}

// ---------------- driver ----------------
struct WS {
  int *ptr, *col, *cnt, *degall, *scansums;
  float *scal, *a_arr, *c_arr, *bnsum, *bnsq, *bnmean, *bnrs, *bcomb, *biasPre;
  unsigned short *wcombT, *wpreT;
  unsigned short *xb, *h1, *h2, *h3, *ts, *aggx;
  size_t agg_elems;
};

template <int F, typename To>
static void run_layer(const unsigned short* xin, To* o_ptr, float* bnout, unsigned short* hout,
                      const float* Wpre, const float* bpre, const float* Wpost, const float* bpost,
                      const float* Wlin, const float* blin, const float* gamma, const float* beta,
                      int FO, const WS& ws, hipStream_t stream) {
  const int N = N_NODES;
  const int K13 = 13 * F;
  // weight prep (wcombT written transposed-bf16 directly)
  {
    dim3 g((FO + 127) / 128, (K13 + 127) / 128);
    k_wcombT<<<g, 256, 0, stream>>>(Wpost, Wlin, ws.wcombT, K13, FO, FO);
    k_bcomb<<<1, 256, 0, stream>>>(bpost, Wlin, blin, ws.bcomb, FO);
    k_tcast_pre<<<(2 * F * F + 255) / 256, 256, 0, stream>>>(Wpre, ws.wpreT, F);
    k_biaspre<<<1, 512, 0, stream>>>(bpre, ws.biasPre, F);
  }
  // fused pre-GEMM: ts = xin @ [W1 | W2] + [bpre | 0]
  {
    dim3 g(2 * F / 128, (N + 127) / 128);
    k_mm<unsigned short><<<g, 256, 0, stream>>>(xin, F, ws.wpreT, ws.biasPre, ws.ts, 0, N, 2 * F);
  }
  // chunked: edge aggregation (4F stats) -> virtual-13F post GEMM
  int NB = (int)(ws.agg_elems / (size_t)(4 * F));
  NB &= ~127;
  if (NB > N) NB = N;
  if (NB < 128) NB = 128;
  for (int c0 = 0; c0 < N; c0 += NB) {
    int nc = (N - c0 < NB) ? (N - c0) : NB;
    k_edge_agg<F><<<(nc + 3) / 4, 256, 0, stream>>>(ws.ts, ws.ptr, ws.col, ws.aggx, c0, nc);
    if (FO == 64) {
      dim3 g(1, (nc + 63) / 64);
      k_mmP<64, F, To><<<g, 256, 0, stream>>>(xin, ws.aggx, ws.a_arr, ws.c_arr, ws.wcombT,
                                              ws.bcomb, o_ptr, c0, nc, NB, FO);
    } else {
      dim3 g(FO / 128, (nc + 63) / 64);
      k_mmP<128, F, To><<<g, 256, 0, stream>>>(xin, ws.aggx, ws.a_arr, ws.c_arr, ws.wcombT,
                                               ws.bcomb, o_ptr, c0, nc, NB, FO);
    }
  }
  // BN + ELU
  hipMemsetAsync(ws.bnsum, 0, 512 * sizeof(float), stream);  // bnsum+bnsq contiguous
  constexpr bool is_bf = (sizeof(To) == 2);
  if constexpr (is_bf) {
    int gs = imin((N * FO) / 2048 + 1, 1024);
    if (FO == 128)
      k_bn_stats_bf<128><<<gs, 256, 0, stream>>>((const unsigned short*)o_ptr, ws.bnsum, ws.bnsq);
    else
      k_bn_stats_bf<256><<<gs, 256, 0, stream>>>((const unsigned short*)o_ptr, ws.bnsum, ws.bnsq);
  } else {
    int gs = imin((N * FO) / 1024 + 1, 1024);
    k_bn_stats_f32<64><<<gs, 256, 0, stream>>>((const float*)o_ptr, ws.bnsum, ws.bnsq);
  }
  k_bn_fin<<<1, 256, 0, stream>>>(ws.bnsum, ws.bnsq, ws.bnmean, ws.bnrs, FO);
  int total = N_NODES * FO;
  if constexpr (is_bf) {
    int ge = (total / 8 + 255) / 256;
    if (FO == 128)
      k_bn_elu_bf<128><<<ge, 256, 0, stream>>>((const unsigned short*)o_ptr, ws.bnmean, ws.bnrs, gamma, beta, hout);
    else
      k_bn_elu_bf<256><<<ge, 256, 0, stream>>>((const unsigned short*)o_ptr, ws.bnmean, ws.bnrs, gamma, beta, hout);
  } else {
    int ge = (total / 4 + 255) / 256;
    k_bn_elu_f32<64><<<ge, 256, 0, stream>>>((const float*)o_ptr, ws.bnmean, ws.bnrs, gamma, beta, hout, bnout);
  }
}

extern "C" void kernel_launch(void* const* d_in, const int* in_sizes, int n_in,
                              void* d_out, int out_size, void* d_ws, size_t ws_size,
                              hipStream_t stream) {
  const int N = N_NODES, E = N_EDGES;
  const float* x = (const float*)d_in[0];
  const int* ei = (const int*)d_in[1];
  const int* src = ei;
  const int* dst = ei + E;
  const float *Wpre[4], *bpre[4], *Wpost[4], *bpost[4], *Wlin[4], *blin[4], *gamma[4], *beta[4];
  for (int i = 0; i < 4; i++) {
    const int b = 2 + i * 8;
    Wpre[i] = (const float*)d_in[b + 0];
    bpre[i] = (const float*)d_in[b + 1];
    Wpost[i] = (const float*)d_in[b + 2];
    bpost[i] = (const float*)d_in[b + 3];
    Wlin[i] = (const float*)d_in[b + 4];
    blin[i] = (const float*)d_in[b + 5];
    gamma[i] = (const float*)d_in[b + 6];
    beta[i] = (const float*)d_in[b + 7];
  }
  const float* Wc = (const float*)d_in[34];
  const float* bcv = (const float*)d_in[35];

  // ----- workspace layout (~119 MB fixed + adaptive aggx) -----
  char* w = (char*)d_ws;
  size_t off = 0;
  auto alloc = [&](size_t bytes) -> void* {
    void* p = (void*)(w + off);
    off = (off + bytes + 255) & ~(size_t)255;
    return p;
  };
  WS ws;
  ws.ptr = (int*)alloc((N + 1) * sizeof(int));
  ws.col = (int*)alloc((size_t)E * sizeof(int));
  ws.cnt = (int*)alloc((size_t)N * sizeof(int));
  ws.degall = (int*)alloc((size_t)N * sizeof(int));
  ws.scansums = (int*)alloc((SCAN_NB + 1) * sizeof(int));
  ws.scal = (float*)alloc(16 * sizeof(float));
  ws.a_arr = (float*)alloc((size_t)N * sizeof(float));
  ws.c_arr = (float*)alloc((size_t)N * sizeof(float));
  ws.bnsum = (float*)alloc(256 * sizeof(float));
  ws.bnsq = (float*)alloc(256 * sizeof(float));
  ws.bnmean = (float*)alloc(256 * sizeof(float));
  ws.bnrs = (float*)alloc(256 * sizeof(float));
  ws.bcomb = (float*)alloc(256 * sizeof(float));
  ws.biasPre = (float*)alloc(512 * sizeof(float));
  ws.wcombT = (unsigned short*)alloc((size_t)256 * 3328 * sizeof(unsigned short));
  ws.wpreT = (unsigned short*)alloc((size_t)512 * 256 * sizeof(unsigned short));
  ws.xb = (unsigned short*)alloc((size_t)N * 128 * sizeof(unsigned short));
  ws.h1 = (unsigned short*)alloc((size_t)N * 128 * sizeof(unsigned short));
  ws.h2 = (unsigned short*)alloc((size_t)N * 256 * sizeof(unsigned short));
  ws.h3 = (unsigned short*)alloc((size_t)N * 128 * sizeof(unsigned short));
  ws.ts = (unsigned short*)alloc((size_t)N * 512 * sizeof(unsigned short));
  size_t rem = (ws_size > off) ? (ws_size - off) : 0;
  ws.agg_elems = rem / sizeof(unsigned short);
  ws.aggx = (unsigned short*)(w + off);
  unsigned short* h4 = ws.xb;  // alias: x dead after layer 1; h4 is [N,64]

  float* outp = (float*)d_out;
  float* logits = outp;              // [N,2]
  float* p4 = outp + (size_t)N * 2;  // [N,64]
  float* b4 = p4 + (size_t)N * 64;   // [N,64]
  unsigned short* o_scratch = (unsigned short*)p4;  // pre-BN scratch, overwritten by layer 4

  // ----- degree / CSR / scalars -----
  hipMemsetAsync(ws.cnt, 0, N * sizeof(int), stream);
  hipMemsetAsync(ws.degall, 0, N * sizeof(int), stream);
  hipMemsetAsync(ws.scal, 0, 16 * sizeof(float), stream);
  k_count<<<(E + 255) / 256, 256, 0, stream>>>(src, dst, ws.cnt, ws.degall);
  k_scan1<<<SCAN_NB, 1024, 0, stream>>>(ws.cnt, ws.ptr, ws.scansums);
  k_scan2<<<1, 64, 0, stream>>>(ws.scansums);
  k_scan3<<<SCAN_NB, 1024, 0, stream>>>(ws.ptr, ws.scansums);
  hipMemsetAsync(ws.cnt, 0, N * sizeof(int), stream);
  k_fill<<<(E + 255) / 256, 256, 0, stream>>>(src, dst, ws.ptr, ws.cnt, ws.col);
  k_avglog<<<64, 256, 0, stream>>>(ws.degall, ws.scal);
  k_avg_fin<<<1, 1, 0, stream>>>(ws.scal);
  k_scalars<<<(N + 255) / 256, 256, 0, stream>>>(ws.ptr, ws.scal, ws.a_arr, ws.c_arr);
  k_cast<<<(N * 128 + 255) / 256, 256, 0, stream>>>(x, ws.xb, N * 128);

  run_layer<128, unsigned short>(ws.xb, o_scratch, nullptr, ws.h1,
                                 Wpre[0], bpre[0], Wpost[0], bpost[0], Wlin[0], blin[0], gamma[0], beta[0],
                                 128, ws, stream);
  run_layer<128, unsigned short>(ws.h1, o_scratch, nullptr, ws.h2,
                                 Wpre[1], bpre[1], Wpost[1], bpost[1], Wlin[1], blin[1], gamma[1], beta[1],
                                 256, ws, stream);
  run_layer<256, unsigned short>(ws.h2, o_scratch, nullptr, ws.h3,
                                 Wpre[2], bpre[2], Wpost[2], bpost[2], Wlin[2], blin[2], gamma[2], beta[2],
                                 128, ws, stream);
  k_add<<<((N * 128) + 255) / 256, 256, 0, stream>>>(ws.h1, ws.h3, ws.h3);  // x4 = h1 + h3 in place
  run_layer<128, float>(ws.h3, p4, b4, h4,
                        Wpre[3], bpre[3], Wpost[3], bpost[3], Wlin[3], blin[3], gamma[3], beta[3],
                        64, ws, stream);
  k_logits<<<(N + 255) / 256, 256, 0, stream>>>(h4, Wc, bcv, logits);
  (void)in_sizes; (void)n_in; (void)out_size; (void)ws_size;
}

// Round 14
// 1161.868 us; speedup vs baseline: 1.9441x; 1.0270x over previous
//
#include <hip/hip_runtime.h>
#include <math.h>

#define N_NODES 50000
#define N_EDGES 500000
#define SCAN_NB ((N_NODES + 1023) / 1024)

using bf16x8 = __attribute__((ext_vector_type(8))) short;
using f32x4  = __attribute__((ext_vector_type(4))) float;

// ---------- bf16 helpers ----------
__device__ inline float b2f(unsigned short u) {
  union { unsigned int i; float f; } v; v.i = ((unsigned int)u) << 16; return v.f;
}
__device__ inline unsigned short f2b(float f) {
  union { float f; unsigned int i; } v; v.f = f;
  unsigned int x = v.i;
  return (unsigned short)((x + 0x7fffu + ((x >> 16) & 1u)) >> 16);
}
__device__ inline unsigned int pk2(float a, float b) {
  return (unsigned int)f2b(a) | ((unsigned int)f2b(b) << 16);
}
__device__ inline void stv(unsigned short* p, float v) { *p = f2b(v); }
__device__ inline void stv(float* p, float v) { *p = v; }
__device__ inline float ldf(unsigned short u) { return b2f(u); }
__device__ inline float ldf(float f) { return f; }
__host__ __device__ inline int imin(int a, int b) { return a < b ? a : b; }

// direct global->LDS DMA, 16B per lane; lds base is wave-uniform, lane offset = lane*16
__device__ inline void gload16(const unsigned short* g, unsigned short* l) {
  __builtin_amdgcn_global_load_lds((const __attribute__((address_space(1))) unsigned int*)g,
                                   (__attribute__((address_space(3))) unsigned int*)l, 16, 0, 0);
}

// ---------------- degree / CSR ----------------
__global__ void k_count(const int* __restrict__ src, const int* __restrict__ dst,
                        int* __restrict__ cnt, int* __restrict__ degall) {
  int e = blockIdx.x * blockDim.x + threadIdx.x;
  if (e < N_EDGES) {
    atomicAdd(&cnt[dst[e]], 1);
    atomicAdd(&degall[src[e]], 1);
    atomicAdd(&degall[dst[e]], 1);
  }
}

// 3-phase parallel exclusive scan over cnt[N_NODES] -> ptr (+ ptr[N]=total)
__global__ __launch_bounds__(1024) void k_scan1(const int* __restrict__ cnt, int* __restrict__ ptr,
                                                int* __restrict__ sums) {
  __shared__ int buf[1024];
  int i = blockIdx.x * 1024 + threadIdx.x;
  int v = (i < N_NODES) ? cnt[i] : 0;
  buf[threadIdx.x] = v;
  __syncthreads();
  for (int off = 1; off < 1024; off <<= 1) {
    int tv = (threadIdx.x >= off) ? buf[threadIdx.x - off] : 0;
    __syncthreads();
    buf[threadIdx.x] += tv;
    __syncthreads();
  }
  if (i < N_NODES) ptr[i] = buf[threadIdx.x] - v;  // block-local exclusive
  if (threadIdx.x == 1023) sums[blockIdx.x] = buf[1023];
}

__global__ void k_scan2(int* __restrict__ sums) {
  if (threadIdx.x == 0) {
    int acc = 0;
    for (int b = 0; b < SCAN_NB; b++) {
      int t = sums[b];
      sums[b] = acc;
      acc += t;
    }
    sums[SCAN_NB] = acc;
  }
}

__global__ __launch_bounds__(1024) void k_scan3(int* __restrict__ ptr, const int* __restrict__ sums) {
  int i = blockIdx.x * 1024 + threadIdx.x;
  if (i < N_NODES) ptr[i] += sums[blockIdx.x];
  if (blockIdx.x == 0 && threadIdx.x == 0) ptr[N_NODES] = sums[SCAN_NB];
}

__global__ void k_fill(const int* __restrict__ src, const int* __restrict__ dst,
                       const int* __restrict__ ptr, int* __restrict__ cnt, int* __restrict__ col) {
  int e = blockIdx.x * blockDim.x + threadIdx.x;
  if (e < N_EDGES) {
    int d = dst[e];
    int pos = atomicAdd(&cnt[d], 1);
    col[ptr[d] + pos] = src[e];
  }
}

__global__ void k_avglog(const int* __restrict__ degall, float* __restrict__ scal) {
  __shared__ float L[256];
  float s = 0.f;
  for (int n = blockIdx.x * blockDim.x + threadIdx.x; n < N_NODES; n += gridDim.x * blockDim.x)
    s += logf((float)degall[n] + 1.0f);
  L[threadIdx.x] = s;
  __syncthreads();
  for (int o = 128; o > 0; o >>= 1) {
    if (threadIdx.x < o) L[threadIdx.x] += L[threadIdx.x + o];
    __syncthreads();
  }
  if (threadIdx.x == 0) atomicAdd(&scal[0], L[0]);
}

__global__ void k_avg_fin(float* scal) {
  float avg = scal[0] / (float)N_NODES;
  scal[1] = avg;
  scal[2] = 1.0f / avg;
}

__global__ void k_scalars(const int* __restrict__ ptr, const float* __restrict__ scal,
                          float* __restrict__ a_arr, float* __restrict__ c_arr) {
  int n = blockIdx.x * blockDim.x + threadIdx.x;
  if (n < N_NODES) {
    int d = ptr[n + 1] - ptr[n];
    float degc = fmaxf((float)d, 1.f);
    float logd = logf(degc + 1.f);
    a_arr[n] = logd * scal[2];
    c_arr[n] = scal[1] / logd;
  }
}

__global__ void k_cast(const float* __restrict__ x, unsigned short* __restrict__ xb, int total) {
  int i = blockIdx.x * blockDim.x + threadIdx.x;
  if (i < total) xb[i] = f2b(x[i]);
}

// pre-weights: BT_pre[j][k] = j<F ? Wpre[k][j] : Wpre[F+k][j-F]   (j<2F, k<F)
__global__ void k_tcast_pre(const float* __restrict__ Wpre, unsigned short* __restrict__ out, int F) {
  int i = blockIdx.x * blockDim.x + threadIdx.x;
  if (i < 2 * F * F) {
    int j = i / F, k = i % F;
    float v = (j < F) ? Wpre[(size_t)k * F + j] : Wpre[(size_t)(F + k) * F + (j - F)];
    out[i] = f2b(v);
  }
}

__global__ void k_biaspre(const float* __restrict__ bpre, float* __restrict__ biasPre, int F) {
  int j = threadIdx.x;
  if (j < 2 * F) biasPre[j] = (j < F) ? bpre[j] : 0.f;
}

// ---------------- weight GEMM: CT[c][r] = bf16( (Wpost@Wlin)[r][c] ) ----------------
__global__ __launch_bounds__(256) void k_wcombT(const float* __restrict__ A, const float* __restrict__ B,
                                                unsigned short* __restrict__ CT, int M, int Ncol, int K) {
  __shared__ float As[16][136];
  __shared__ float Bs[16][128];
  int tid = threadIdx.x;
  int row0 = blockIdx.y * 128, col0 = blockIdx.x * 128;
  int am = tid >> 1, ah = (tid & 1) * 8;
  int ty = tid >> 4, tx = tid & 15;
  float acc[8][8];
#pragma unroll
  for (int i = 0; i < 8; i++)
#pragma unroll
    for (int j = 0; j < 8; j++) acc[i][j] = 0.f;
  int arow = row0 + am;
  bool av = arow < M;
  const float* Ar = A + (size_t)arow * K;
  for (int k0 = 0; k0 < K; k0 += 16) {
    float4 a0 = make_float4(0, 0, 0, 0), a1 = make_float4(0, 0, 0, 0);
    if (av) {
      a0 = *(const float4*)(Ar + k0 + ah);
      a1 = *(const float4*)(Ar + k0 + ah + 4);
    }
    As[ah + 0][am] = a0.x; As[ah + 1][am] = a0.y; As[ah + 2][am] = a0.z; As[ah + 3][am] = a0.w;
    As[ah + 4][am] = a1.x; As[ah + 5][am] = a1.y; As[ah + 6][am] = a1.z; As[ah + 7][am] = a1.w;
#pragma unroll
    for (int i = 0; i < 2; i++) {
      int q = tid * 2 + i;
      int kk = q >> 5, j4 = (q & 31) * 4;
      int bc = col0 + j4;
      float4 b = make_float4(0, 0, 0, 0);
      if (bc < Ncol && (k0 + kk) < K) b = *(const float4*)(B + (size_t)(k0 + kk) * Ncol + bc);
      *(float4*)(&Bs[kk][j4]) = b;
    }
    __syncthreads();
#pragma unroll
    for (int kk = 0; kk < 16; kk++) {
      float av8[8], bv8[8];
#pragma unroll
      for (int i = 0; i < 8; i++) av8[i] = As[kk][ty * 8 + i];
#pragma unroll
      for (int j = 0; j < 8; j++) bv8[j] = Bs[kk][tx * 8 + j];
#pragma unroll
      for (int i = 0; i < 8; i++)
#pragma unroll
        for (int j = 0; j < 8; j++) acc[i][j] = fmaf(av8[i], bv8[j], acc[i][j]);
    }
    __syncthreads();
  }
#pragma unroll
  for (int i = 0; i < 8; i++) {
    int r = row0 + ty * 8 + i;
    if (r < M) {
#pragma unroll
      for (int j = 0; j < 8; j++) {
        int c = col0 + tx * 8 + j;
        if (c < Ncol) CT[(size_t)c * M + r] = f2b(acc[i][j]);
      }
    }
  }
}

// ---------------- m97-style MFMA GEMM (pre-GEMM): 128x128 tile, BK=32 ----------------
template <typename To>
__global__ __launch_bounds__(256) void k_mm(
    const unsigned short* __restrict__ A, int K,
    const unsigned short* __restrict__ BT,
    const float* __restrict__ bias,
    To* __restrict__ C, int n0, int M, int Ncol) {
  __shared__ unsigned short lds[2][2][4096];
  const int tid = threadIdx.x;
  const int lane = tid & 63;
  const int wid = tid >> 6;
  const int wr = wid >> 1, wc = wid & 1;
  const int row0 = blockIdx.y * 128;
  const int col0 = blockIdx.x * 128;
  const int l15 = lane & 15, lq = lane >> 4;
  const int srow = wid * 32 + (lane >> 2);
  const int scol = (lane & 3) * 8;
  const unsigned short* gA0 = A + (size_t)imin(row0 + srow, N_NODES - 1) * K + scol;
  const unsigned short* gA1 = A + (size_t)imin(row0 + srow + 16, N_NODES - 1) * K + scol;
  const unsigned short* gB0 = BT + (size_t)(col0 + srow) * K + scol;
  const unsigned short* gB1 = BT + (size_t)(col0 + srow + 16) * K + scol;

  f32x4 acc[4][4];
#pragma unroll
  for (int m = 0; m < 4; m++)
#pragma unroll
    for (int n = 0; n < 4; n++) acc[m][n] = (f32x4){0.f, 0.f, 0.f, 0.f};

  auto stage = [&](int buf, int k0) {
    gload16(gA0 + k0, &lds[buf][0][wid * 1024]);
    gload16(gA1 + k0, &lds[buf][0][wid * 1024 + 512]);
    gload16(gB0 + k0, &lds[buf][1][wid * 1024]);
    gload16(gB1 + k0, &lds[buf][1][wid * 1024 + 512]);
  };

  const int nk = K / 32;
  stage(0, 0);
  __syncthreads();
  for (int t = 0; t < nk; ++t) {
    const int cur = t & 1;
    if (t + 1 < nk) stage(cur ^ 1, (t + 1) * 32);
    bf16x8 a[4], b[4];
#pragma unroll
    for (int m = 0; m < 4; m++)
      a[m] = *(const bf16x8*)&lds[cur][0][(wr * 64 + m * 16 + l15) * 32 + lq * 8];
#pragma unroll
    for (int n = 0; n < 4; n++)
      b[n] = *(const bf16x8*)&lds[cur][1][(wc * 64 + n * 16 + l15) * 32 + lq * 8];
#pragma unroll
    for (int m = 0; m < 4; m++)
#pragma unroll
      for (int n = 0; n < 4; n++)
        acc[m][n] = __builtin_amdgcn_mfma_f32_16x16x32_bf16(a[m], b[n], acc[m][n], 0, 0, 0);
    __syncthreads();
  }
#pragma unroll
  for (int n = 0; n < 4; n++) {
    int col = col0 + wc * 64 + n * 16 + l15;
    float bv = bias ? bias[col] : 0.f;
#pragma unroll
    for (int m = 0; m < 4; m++) {
#pragma unroll
      for (int j = 0; j < 4; j++) {
        int r = row0 + wr * 64 + m * 16 + lq * 4 + j;
        if (r < M) stv(&C[(size_t)(n0 + r) * Ncol + col], acc[m][n][j] + bv);
      }
    }
  }
}

// ---------------- post-GEMM: virtual 13F A, CHUNK-MAJOR region walk ----------------
// Steps: s<SX -> x-region (acc0). Then per G-chunk tg: 3 consecutive steps (regions 0/1/2)
// staging the SAME A chunk (L2-hot on repeats) vs B slices W2/W3/W4 -> acc0/1/2.
// Epilogue: o = acc0 + an*acc1 + cn*acc2 + bias. 64xNTILE tile, BK=64, XOR-swizzled LDS.
template <int NTILE, int F, typename To>
__global__ __launch_bounds__(256, 2) void k_mmP(
    const unsigned short* __restrict__ X,
    const unsigned short* __restrict__ G,
    const float* __restrict__ a_arr, const float* __restrict__ c_arr,
    const unsigned short* __restrict__ BT,
    const float* __restrict__ bias,
    To* __restrict__ C, int n0, int M, int Mbuf, int Ncol) {
  constexpr int K13 = 13 * F;
  constexpr int F4 = 4 * F;
  constexpr int SX = F / 64;       // x-phase steps
  constexpr int NG = F4 / 64;      // G chunks
  constexpr int NS = SX + 3 * NG;  // total steps (= K13/64)
  constexpr int CB = NTILE / 32;
  constexpr int NF = NTILE / 32;
  __shared__ unsigned short lds[2][(64 + NTILE) * 64];
  const int tid = threadIdx.x;
  const int lane = tid & 63;
  const int wid = tid >> 6;
  const int wr = wid >> 1, wc = wid & 1;
  const int row0 = blockIdx.y * 64;
  const int col0 = blockIdx.x * NTILE;
  const int l15 = lane & 15, lq = lane >> 4;
  const int lr8 = lane >> 3;
  const int lc8 = lane & 7;

  f32x4 acc0[2][NF], acc1[2][NF], acc2[2][NF];
#pragma unroll
  for (int m = 0; m < 2; m++)
#pragma unroll
    for (int n = 0; n < NF; n++) {
      acc0[m][n] = (f32x4){0.f, 0.f, 0.f, 0.f};
      acc1[m][n] = (f32x4){0.f, 0.f, 0.f, 0.f};
      acc2[m][n] = (f32x4){0.f, 0.f, 0.f, 0.f};
    }

  auto stage = [&](int buf, int s) {
    unsigned short* Ar = &lds[buf][0];
    unsigned short* Br = &lds[buf][64 * 64];
    int koff;           // B k-offset in [0, K13)
    int akoff;          // A k-offset within its source
    bool isx = (s < SX);
    int tg = 0;
    if (isx) {
      koff = s * 64;
      akoff = s * 64;
    } else {
      int q = s - SX;
      tg = q / 3;
      int reg = q - 3 * tg;
      koff = F + reg * F4 + tg * 64;
      akoff = tg * 64;
    }
#pragma unroll
    for (int c = 0; c < 2; c++) {
      int r = (wid * 2 + c) * 8 + lr8;
      int gc = (lc8 ^ (r & 7)) * 8;
      const unsigned short* src;
      if (isx)
        src = X + (size_t)imin(n0 + row0 + r, N_NODES - 1) * F + akoff + gc;
      else
        src = G + (size_t)imin(row0 + r, Mbuf - 1) * F4 + akoff + gc;
      gload16(src, Ar + (wid * 2 + c) * 512);
    }
#pragma unroll
    for (int c = 0; c < CB; c++) {
      int r = (wid * CB + c) * 8 + lr8;
      int gc = (lc8 ^ (r & 7)) * 8;
      gload16(BT + (size_t)(col0 + r) * K13 + koff + gc, Br + (wid * CB + c) * 512);
    }
  };

  stage(0, 0);
  __syncthreads();
  for (int s = 0; s < NS; ++s) {
    const int cur = s & 1;
    if (s + 1 < NS) stage(cur ^ 1, s + 1);
    const unsigned short* Ar = &lds[cur][0];
    const unsigned short* Br = &lds[cur][64 * 64];
    bf16x8 a[2][2], b[2][NF];
#pragma unroll
    for (int ks = 0; ks < 2; ks++) {
#pragma unroll
      for (int m = 0; m < 2; m++) {
        int r = wr * 32 + m * 16 + l15;
        a[ks][m] = *(const bf16x8*)&Ar[r * 64 + ((lq + ks * 4) ^ (r & 7)) * 8];
      }
#pragma unroll
      for (int n = 0; n < NF; n++) {
        int r = wc * (NTILE / 2) + n * 16 + l15;
        b[ks][n] = *(const bf16x8*)&Br[r * 64 + ((lq + ks * 4) ^ (r & 7)) * 8];
      }
    }
    const int reg = (s < SX) ? 0 : (s - SX) % 3;
    if (reg == 0) {
#pragma unroll
      for (int ks = 0; ks < 2; ks++)
#pragma unroll
        for (int m = 0; m < 2; m++)
#pragma unroll
          for (int n = 0; n < NF; n++)
            acc0[m][n] = __builtin_amdgcn_mfma_f32_16x16x32_bf16(a[ks][m], b[ks][n], acc0[m][n], 0, 0, 0);
    } else if (reg == 1) {
#pragma unroll
      for (int ks = 0; ks < 2; ks++)
#pragma unroll
        for (int m = 0; m < 2; m++)
#pragma unroll
          for (int n = 0; n < NF; n++)
            acc1[m][n] = __builtin_amdgcn_mfma_f32_16x16x32_bf16(a[ks][m], b[ks][n], acc1[m][n], 0, 0, 0);
    } else {
#pragma unroll
      for (int ks = 0; ks < 2; ks++)
#pragma unroll
        for (int m = 0; m < 2; m++)
#pragma unroll
          for (int n = 0; n < NF; n++)
            acc2[m][n] = __builtin_amdgcn_mfma_f32_16x16x32_bf16(a[ks][m], b[ks][n], acc2[m][n], 0, 0, 0);
    }
    __syncthreads();
  }
  // epilogue: per-row an/cn combine + bias
#pragma unroll
  for (int m = 0; m < 2; m++) {
    f32x4 anv, cnv;
#pragma unroll
    for (int j = 0; j < 4; j++) {
      int g = imin(n0 + row0 + wr * 32 + m * 16 + lq * 4 + j, N_NODES - 1);
      anv[j] = a_arr[g];
      cnv[j] = c_arr[g];
    }
#pragma unroll
    for (int n = 0; n < NF; n++) {
      f32x4 v = acc0[m][n] + anv * acc1[m][n] + cnv * acc2[m][n];
      int col = col0 + wc * (NTILE / 2) + n * 16 + l15;
      float bv = bias[col];
#pragma unroll
      for (int j = 0; j < 4; j++) {
        int r = row0 + wr * 32 + m * 16 + lq * 4 + j;
        if (r < M) stv(&C[(size_t)(n0 + r) * Ncol + col], v[j] + bv);
      }
    }
  }
}

// ---------------- edge aggregation (vectorized): writes 4F rows [mean | min | max | std] ----------------
template <int F>
__global__ __launch_bounds__(256) void k_edge_agg(
    const unsigned short* __restrict__ ts,
    const int* __restrict__ ptr, const int* __restrict__ col,
    unsigned short* __restrict__ aggc, int n0, int nchunk) {
  constexpr int VU = F / 128;
  int idx = (blockIdx.x * blockDim.x + threadIdx.x) >> 6;
  int lane = threadIdx.x & 63;
  if (idx >= nchunk) return;
  int n = n0 + idx;
  if (n >= N_NODES) return;
  float S1[2 * VU], S2[2 * VU], mn[2 * VU], mx[2 * VU];
#pragma unroll
  for (int u = 0; u < 2 * VU; u++) {
    S1[u] = 0.f; S2[u] = 0.f; mn[u] = 3.4e38f; mx[u] = -3.4e38f;
  }
  int e0 = ptr[n], e1 = ptr[n + 1];
  for (int e = e0; e < e1; ++e) {
    int sidx = col[e];
    const unsigned int* sr = (const unsigned int*)(ts + (size_t)sidx * 2 * F + F);
#pragma unroll
    for (int u = 0; u < VU; u++) {
      unsigned int v = sr[lane + 64 * u];
      float f0 = b2f((unsigned short)(v & 0xffff));
      float f1 = b2f((unsigned short)(v >> 16));
      S1[2 * u] += f0; S2[2 * u] += f0 * f0;
      mn[2 * u] = fminf(mn[2 * u], f0); mx[2 * u] = fmaxf(mx[2 * u], f0);
      S1[2 * u + 1] += f1; S2[2 * u + 1] += f1 * f1;
      mn[2 * u + 1] = fminf(mn[2 * u + 1], f1); mx[2 * u + 1] = fmaxf(mx[2 * u + 1], f1);
    }
  }
  int d = e1 - e0;
  const unsigned int* tr = (const unsigned int*)(ts + (size_t)n * 2 * F);
  unsigned int* ob = (unsigned int*)(aggc + (size_t)idx * 4 * F);
  constexpr int UB = 64 * VU;
#pragma unroll
  for (int u = 0; u < VU; u++) {
    int ui = lane + 64 * u;
    float mean0, mean1, lo0, lo1, hi0, hi1, sd0, sd1;
    if (d > 0) {
      float inv = 1.f / (float)d;
      unsigned int tv = tr[ui];
      float t0 = b2f((unsigned short)(tv & 0xffff));
      float t1 = b2f((unsigned short)(tv >> 16));
      float ms0 = S1[2 * u] * inv, ms1 = S1[2 * u + 1] * inv;
      sd0 = sqrtf(fmaxf(S2[2 * u] * inv - ms0 * ms0, 0.f) + 1e-5f);
      sd1 = sqrtf(fmaxf(S2[2 * u + 1] * inv - ms1 * ms1, 0.f) + 1e-5f);
      mean0 = t0 + ms0; mean1 = t1 + ms1;
      lo0 = t0 + mn[2 * u]; lo1 = t1 + mn[2 * u + 1];
      hi0 = t0 + mx[2 * u]; hi1 = t1 + mx[2 * u + 1];
    } else {
      mean0 = mean1 = lo0 = lo1 = hi0 = hi1 = 0.f;
      sd0 = sd1 = sqrtf(1e-5f);
    }
    unsigned int* o1 = ob + ui;
    o1[0] = pk2(mean0, mean1);
    o1[UB] = pk2(lo0, lo1);
    o1[2 * UB] = pk2(hi0, hi1);
    o1[3 * UB] = pk2(sd0, sd1);
  }
}

// ---------------- BN stats ----------------
template <int FO>
__global__ __launch_bounds__(256) void k_bn_stats_bf(const unsigned short* __restrict__ o,
                                                     float* __restrict__ gsum, float* __restrict__ gsq) {
  constexpr int TOTAL = N_NODES * FO;
  float s1[8], s2[8];
#pragma unroll
  for (int j = 0; j < 8; j++) { s1[j] = 0.f; s2[j] = 0.f; }
  const int stride = gridDim.x * 2048;
  for (int base = blockIdx.x * 2048 + threadIdx.x * 8; base < TOTAL; base += stride) {
    uint4 v = *(const uint4*)(o + base);
    const unsigned int* u = (const unsigned int*)&v;
#pragma unroll
    for (int w = 0; w < 4; w++) {
      float f0 = b2f((unsigned short)(u[w] & 0xffff));
      float f1 = b2f((unsigned short)(u[w] >> 16));
      s1[2 * w] += f0; s2[2 * w] += f0 * f0;
      s1[2 * w + 1] += f1; s2[2 * w + 1] += f1 * f1;
    }
  }
  __shared__ float L1[2048], L2[2048];
#pragma unroll
  for (int j = 0; j < 8; j++) {
    L1[threadIdx.x * 8 + j] = s1[j];
    L2[threadIdx.x * 8 + j] = s2[j];
  }
  __syncthreads();
  int c = threadIdx.x;
  if (c < FO) {
    float a1 = 0.f, a2 = 0.f;
    for (int i = c; i < 2048; i += FO) { a1 += L1[i]; a2 += L2[i]; }
    atomicAdd(&gsum[c], a1);
    atomicAdd(&gsq[c], a2);
  }
}

template <int FO>
__global__ __launch_bounds__(256) void k_bn_stats_f32(const float* __restrict__ o,
                                                      float* __restrict__ gsum, float* __restrict__ gsq) {
  constexpr int TOTAL = N_NODES * FO;
  float s1[4], s2[4];
#pragma unroll
  for (int j = 0; j < 4; j++) { s1[j] = 0.f; s2[j] = 0.f; }
  const int stride = gridDim.x * 1024;
  for (int base = blockIdx.x * 1024 + threadIdx.x * 4; base < TOTAL; base += stride) {
    float4 v = *(const float4*)(o + base);
    s1[0] += v.x; s2[0] += v.x * v.x;
    s1[1] += v.y; s2[1] += v.y * v.y;
    s1[2] += v.z; s2[2] += v.z * v.z;
    s1[3] += v.w; s2[3] += v.w * v.w;
  }
  __shared__ float L1[1024], L2[1024];
#pragma unroll
  for (int j = 0; j < 4; j++) {
    L1[threadIdx.x * 4 + j] = s1[j];
    L2[threadIdx.x * 4 + j] = s2[j];
  }
  __syncthreads();
  int c = threadIdx.x;
  if (c < FO) {
    float a1 = 0.f, a2 = 0.f;
    for (int i = c; i < 1024; i += FO) { a1 += L1[i]; a2 += L2[i]; }
    atomicAdd(&gsum[c], a1);
    atomicAdd(&gsq[c], a2);
  }
}

__global__ void k_bn_fin(const float* bnsum, const float* bnsq, float* bnmean, float* bnrs, int FO) {
  int c = threadIdx.x;
  if (c < FO) {
    float mean = bnsum[c] / (float)N_NODES;
    float var = bnsq[c] / (float)N_NODES - mean * mean;
    bnmean[c] = mean;
    bnrs[c] = rsqrtf(var + 1e-5f);
  }
}

// ---------------- BN+ELU (vectorized) ----------------
template <int FO>
__global__ __launch_bounds__(256) void k_bn_elu_bf(const unsigned short* __restrict__ o,
                                                   const float* __restrict__ mean, const float* __restrict__ rs,
                                                   const float* __restrict__ gamma, const float* __restrict__ beta,
                                                   unsigned short* __restrict__ h) {
  constexpr int TOTAL = N_NODES * FO;
  int base = (blockIdx.x * blockDim.x + threadIdx.x) * 8;
  if (base >= TOTAL) return;
  int c0 = base % FO;
  uint4 v = *(const uint4*)(o + base);
  const unsigned int* u = (const unsigned int*)&v;
  unsigned int outw[4];
#pragma unroll
  for (int w = 0; w < 4; w++) {
    int c = c0 + 2 * w;
    float f0 = b2f((unsigned short)(u[w] & 0xffff));
    float f1 = b2f((unsigned short)(u[w] >> 16));
    float y0 = gamma[c] * (f0 - mean[c]) * rs[c] + beta[c];
    float y1 = gamma[c + 1] * (f1 - mean[c + 1]) * rs[c + 1] + beta[c + 1];
    y0 = y0 > 0.f ? y0 : expm1f(y0);
    y1 = y1 > 0.f ? y1 : expm1f(y1);
    outw[w] = pk2(y0, y1);
  }
  *(uint4*)(h + base) = *(uint4*)outw;
}

template <int FO>
__global__ __launch_bounds__(256) void k_bn_elu_f32(const float* __restrict__ o,
                                                    const float* __restrict__ mean, const float* __restrict__ rs,
                                                    const float* __restrict__ gamma, const float* __restrict__ beta,
                                                    unsigned short* __restrict__ h, float* __restrict__ bnout) {
  constexpr int TOTAL = N_NODES * FO;
  int base = (blockIdx.x * blockDim.x + threadIdx.x) * 4;
  if (base >= TOTAL) return;
  int c = base % FO;
  float4 v = *(const float4*)(o + base);
  float y0 = gamma[c] * (v.x - mean[c]) * rs[c] + beta[c];
  float y1 = gamma[c + 1] * (v.y - mean[c + 1]) * rs[c + 1] + beta[c + 1];
  float y2 = gamma[c + 2] * (v.z - mean[c + 2]) * rs[c + 2] + beta[c + 2];
  float y3 = gamma[c + 3] * (v.w - mean[c + 3]) * rs[c + 3] + beta[c + 3];
  if (bnout) *(float4*)(bnout + base) = make_float4(y0, y1, y2, y3);
  unsigned int o0 = pk2(y0 > 0.f ? y0 : expm1f(y0), y1 > 0.f ? y1 : expm1f(y1));
  unsigned int o1 = pk2(y2 > 0.f ? y2 : expm1f(y2), y3 > 0.f ? y3 : expm1f(y3));
  *(uint2*)(h + base) = make_uint2(o0, o1);
}

// ---------------- misc ----------------
__global__ void k_bcomb(const float* __restrict__ bpost, const float* __restrict__ Wlin,
                        const float* __restrict__ blin, float* __restrict__ bcomb, int FO) {
  int j = threadIdx.x;
  if (j < FO) {
    float acc = blin[j];
    for (int k = 0; k < FO; k++) acc += bpost[k] * Wlin[k * FO + j];
    bcomb[j] = acc;
  }
}

__global__ void k_add(const unsigned short* __restrict__ a, const unsigned short* __restrict__ b,
                      unsigned short* __restrict__ c) {
  int idx = blockIdx.x * blockDim.x + threadIdx.x;
  if (idx < N_NODES * 128) c[idx] = f2b(b2f(a[idx]) + b2f(b[idx]));
}

__global__ void k_logits(const unsigned short* __restrict__ h4, const float* __restrict__ Wc,
                         const float* __restrict__ bc, float* __restrict__ out) {
  int n = blockIdx.x * blockDim.x + threadIdx.x;
  if (n < N_NODES) {
    float acc0 = bc[0], acc1 = bc[1];
    const unsigned short* hr = h4 + (size_t)n * 64;
    for (int k = 0; k < 64; k++) {
      float v = b2f(hr[k]);
      acc0 += v * Wc[k * 2 + 0];
      acc1 += v * Wc[k * 2 + 1];
    }
    out[n * 2 + 0] = acc0;
    out[n * 2 + 1] = acc1;
  }
}

// ---------------- driver ----------------
struct WS {
  int *ptr, *col, *cnt, *degall, *scansums;
  float *scal, *a_arr, *c_arr, *bnsum, *bnsq, *bnmean, *bnrs, *bcomb, *biasPre;
  unsigned short *wcombT, *wpreT;
  unsigned short *xb, *h1, *h2, *h3, *ts, *aggx;
  size_t agg_elems;
};

template <int F, typename To>
static void run_layer(const unsigned short* xin, To* o_ptr, float* bnout, unsigned short* hout,
                      const float* Wpre, const float* bpre, const float* Wpost, const float* bpost,
                      const float* Wlin, const float* blin, const float* gamma, const float* beta,
                      int FO, const WS& ws, hipStream_t stream) {
  const int N = N_NODES;
  const int K13 = 13 * F;
  // weight prep (wcombT written transposed-bf16 directly)
  {
    dim3 g((FO + 127) / 128, (K13 + 127) / 128);
    k_wcombT<<<g, 256, 0, stream>>>(Wpost, Wlin, ws.wcombT, K13, FO, FO);
    k_bcomb<<<1, 256, 0, stream>>>(bpost, Wlin, blin, ws.bcomb, FO);
    k_tcast_pre<<<(2 * F * F + 255) / 256, 256, 0, stream>>>(Wpre, ws.wpreT, F);
    k_biaspre<<<1, 512, 0, stream>>>(bpre, ws.biasPre, F);
  }
  // fused pre-GEMM: ts = xin @ [W1 | W2] + [bpre | 0]
  {
    dim3 g(2 * F / 128, (N + 127) / 128);
    k_mm<unsigned short><<<g, 256, 0, stream>>>(xin, F, ws.wpreT, ws.biasPre, ws.ts, 0, N, 2 * F);
  }
  // chunked: edge aggregation (4F stats) -> chunk-major virtual-13F post GEMM
  int NB = (int)(ws.agg_elems / (size_t)(4 * F));
  NB &= ~127;
  if (NB > N) NB = N;
  if (NB < 128) NB = 128;
  for (int c0 = 0; c0 < N; c0 += NB) {
    int nc = (N - c0 < NB) ? (N - c0) : NB;
    k_edge_agg<F><<<(nc + 3) / 4, 256, 0, stream>>>(ws.ts, ws.ptr, ws.col, ws.aggx, c0, nc);
    if (FO == 64) {
      dim3 g(1, (nc + 63) / 64);
      k_mmP<64, F, To><<<g, 256, 0, stream>>>(xin, ws.aggx, ws.a_arr, ws.c_arr, ws.wcombT,
                                              ws.bcomb, o_ptr, c0, nc, NB, FO);
    } else {
      dim3 g(FO / 128, (nc + 63) / 64);
      k_mmP<128, F, To><<<g, 256, 0, stream>>>(xin, ws.aggx, ws.a_arr, ws.c_arr, ws.wcombT,
                                               ws.bcomb, o_ptr, c0, nc, NB, FO);
    }
  }
  // BN + ELU
  hipMemsetAsync(ws.bnsum, 0, 512 * sizeof(float), stream);  // bnsum+bnsq contiguous
  constexpr bool is_bf = (sizeof(To) == 2);
  if constexpr (is_bf) {
    int gs = imin((N * FO) / 2048 + 1, 1024);
    if (FO == 128)
      k_bn_stats_bf<128><<<gs, 256, 0, stream>>>((const unsigned short*)o_ptr, ws.bnsum, ws.bnsq);
    else
      k_bn_stats_bf<256><<<gs, 256, 0, stream>>>((const unsigned short*)o_ptr, ws.bnsum, ws.bnsq);
  } else {
    int gs = imin((N * FO) / 1024 + 1, 1024);
    k_bn_stats_f32<64><<<gs, 256, 0, stream>>>((const float*)o_ptr, ws.bnsum, ws.bnsq);
  }
  k_bn_fin<<<1, 256, 0, stream>>>(ws.bnsum, ws.bnsq, ws.bnmean, ws.bnrs, FO);
  int total = N_NODES * FO;
  if constexpr (is_bf) {
    int ge = (total / 8 + 255) / 256;
    if (FO == 128)
      k_bn_elu_bf<128><<<ge, 256, 0, stream>>>((const unsigned short*)o_ptr, ws.bnmean, ws.bnrs, gamma, beta, hout);
    else
      k_bn_elu_bf<256><<<ge, 256, 0, stream>>>((const unsigned short*)o_ptr, ws.bnmean, ws.bnrs, gamma, beta, hout);
  } else {
    int ge = (total / 4 + 255) / 256;
    k_bn_elu_f32<64><<<ge, 256, 0, stream>>>((const float*)o_ptr, ws.bnmean, ws.bnrs, gamma, beta, hout, bnout);
  }
}

extern "C" void kernel_launch(void* const* d_in, const int* in_sizes, int n_in,
                              void* d_out, int out_size, void* d_ws, size_t ws_size,
                              hipStream_t stream) {
  const int N = N_NODES, E = N_EDGES;
  const float* x = (const float*)d_in[0];
  const int* ei = (const int*)d_in[1];
  const int* src = ei;
  const int* dst = ei + E;
  const float *Wpre[4], *bpre[4], *Wpost[4], *bpost[4], *Wlin[4], *blin[4], *gamma[4], *beta[4];
  for (int i = 0; i < 4; i++) {
    const int b = 2 + i * 8;
    Wpre[i] = (const float*)d_in[b + 0];
    bpre[i] = (const float*)d_in[b + 1];
    Wpost[i] = (const float*)d_in[b + 2];
    bpost[i] = (const float*)d_in[b + 3];
    Wlin[i] = (const float*)d_in[b + 4];
    blin[i] = (const float*)d_in[b + 5];
    gamma[i] = (const float*)d_in[b + 6];
    beta[i] = (const float*)d_in[b + 7];
  }
  const float* Wc = (const float*)d_in[34];
  const float* bcv = (const float*)d_in[35];

  // ----- workspace layout (~119 MB fixed + adaptive aggx) -----
  char* w = (char*)d_ws;
  size_t off = 0;
  auto alloc = [&](size_t bytes) -> void* {
    void* p = (void*)(w + off);
    off = (off + bytes + 255) & ~(size_t)255;
    return p;
  };
  WS ws;
  ws.ptr = (int*)alloc((N + 1) * sizeof(int));
  ws.col = (int*)alloc((size_t)E * sizeof(int));
  ws.cnt = (int*)alloc((size_t)N * sizeof(int));
  ws.degall = (int*)alloc((size_t)N * sizeof(int));
  ws.scansums = (int*)alloc((SCAN_NB + 1) * sizeof(int));
  ws.scal = (float*)alloc(16 * sizeof(float));
  ws.a_arr = (float*)alloc((size_t)N * sizeof(float));
  ws.c_arr = (float*)alloc((size_t)N * sizeof(float));
  ws.bnsum = (float*)alloc(256 * sizeof(float));
  ws.bnsq = (float*)alloc(256 * sizeof(float));
  ws.bnmean = (float*)alloc(256 * sizeof(float));
  ws.bnrs = (float*)alloc(256 * sizeof(float));
  ws.bcomb = (float*)alloc(256 * sizeof(float));
  ws.biasPre = (float*)alloc(512 * sizeof(float));
  ws.wcombT = (unsigned short*)alloc((size_t)256 * 3328 * sizeof(unsigned short));
  ws.wpreT = (unsigned short*)alloc((size_t)512 * 256 * sizeof(unsigned short));
  ws.xb = (unsigned short*)alloc((size_t)N * 128 * sizeof(unsigned short));
  ws.h1 = (unsigned short*)alloc((size_t)N * 128 * sizeof(unsigned short));
  ws.h2 = (unsigned short*)alloc((size_t)N * 256 * sizeof(unsigned short));
  ws.h3 = (unsigned short*)alloc((size_t)N * 128 * sizeof(unsigned short));
  ws.ts = (unsigned short*)alloc((size_t)N * 512 * sizeof(unsigned short));
  size_t rem = (ws_size > off) ? (ws_size - off) : 0;
  ws.agg_elems = rem / sizeof(unsigned short);
  ws.aggx = (unsigned short*)(w + off);
  unsigned short* h4 = ws.xb;  // alias: x dead after layer 1; h4 is [N,64]

  float* outp = (float*)d_out;
  float* logits = outp;              // [N,2]
  float* p4 = outp + (size_t)N * 2;  // [N,64]
  float* b4 = p4 + (size_t)N * 64;   // [N,64]
  unsigned short* o_scratch = (unsigned short*)p4;  // pre-BN scratch, overwritten by layer 4

  // ----- degree / CSR / scalars -----
  hipMemsetAsync(ws.cnt, 0, N * sizeof(int), stream);
  hipMemsetAsync(ws.degall, 0, N * sizeof(int), stream);
  hipMemsetAsync(ws.scal, 0, 16 * sizeof(float), stream);
  k_count<<<(E + 255) / 256, 256, 0, stream>>>(src, dst, ws.cnt, ws.degall);
  k_scan1<<<SCAN_NB, 1024, 0, stream>>>(ws.cnt, ws.ptr, ws.scansums);
  k_scan2<<<1, 64, 0, stream>>>(ws.scansums);
  k_scan3<<<SCAN_NB, 1024, 0, stream>>>(ws.ptr, ws.scansums);
  hipMemsetAsync(ws.cnt, 0, N * sizeof(int), stream);
  k_fill<<<(E + 255) / 256, 256, 0, stream>>>(src, dst, ws.ptr, ws.cnt, ws.col);
  k_avglog<<<64, 256, 0, stream>>>(ws.degall, ws.scal);
  k_avg_fin<<<1, 1, 0, stream>>>(ws.scal);
  k_scalars<<<(N + 255) / 256, 256, 0, stream>>>(ws.ptr, ws.scal, ws.a_arr, ws.c_arr);
  k_cast<<<(N * 128 + 255) / 256, 256, 0, stream>>>(x, ws.xb, N * 128);

  run_layer<128, unsigned short>(ws.xb, o_scratch, nullptr, ws.h1,
                                 Wpre[0], bpre[0], Wpost[0], bpost[0], Wlin[0], blin[0], gamma[0], beta[0],
                                 128, ws, stream);
  run_layer<128, unsigned short>(ws.h1, o_scratch, nullptr, ws.h2,
                                 Wpre[1], bpre[1], Wpost[1], bpost[1], Wlin[1], blin[1], gamma[1], beta[1],
                                 256, ws, stream);
  run_layer<256, unsigned short>(ws.h2, o_scratch, nullptr, ws.h3,
                                 Wpre[2], bpre[2], Wpost[2], bpost[2], Wlin[2], blin[2], gamma[2], beta[2],
                                 128, ws, stream);
  k_add<<<((N * 128) + 255) / 256, 256, 0, stream>>>(ws.h1, ws.h3, ws.h3);  // x4 = h1 + h3 in place
  run_layer<128, float>(ws.h3, p4, b4, h4,
                        Wpre[3], bpre[3], Wpost[3], bpost[3], Wlin[3], blin[3], gamma[3], beta[3],
                        64, ws, stream);
  k_logits<<<(N + 255) / 256, 256, 0, stream>>>(h4, Wc, bcv, logits);
  (void)in_sizes; (void)n_in; (void)out_size; (void)ws_size;
}